// Round 1
// baseline (819.826 us; speedup 1.0000x reference)
//
#include <hip/hip_runtime.h>

#define NUSER 30000
#define NITEM 50000
#define NN    80000
#define NE    1200000
#define DD    64
#define FEAT  512
#define HIDN  256

#define BM 128
#define BN 64
#define BK 32

// ---------------- GEMM: C[M,N] = A[M,K] * B[N,K]^T + bias, optional leaky ----------------
template<int ACT>
__global__ __launch_bounds__(256) void gemm_nt(const float* __restrict__ A,
                                               const float* __restrict__ B,
                                               const float* __restrict__ bias,
                                               float* __restrict__ C,
                                               int M, int N, int K){
  __shared__ float As[BK][BM];
  __shared__ float Bs[BK][BN];
  const int m0 = blockIdx.y * BM;
  const int n0 = blockIdx.x * BN;
  const int tid = threadIdx.x;
  const int tx = tid & 15;        // 16 cols of 4
  const int ty = tid >> 4;        // 16 rows of 8
  float acc[8][4] = {};

  for (int k0 = 0; k0 < K; k0 += BK){
    // A tile: BM*BK = 4096 floats = 1024 float4, 4 per thread
    #pragma unroll
    for (int s = 0; s < 4; s++){
      int q = tid + 256 * s;
      int row = q >> 3;          // 8 float4 per 32-float row
      int kq  = q & 7;
      float4 v = make_float4(0.f, 0.f, 0.f, 0.f);
      int gr = m0 + row;
      if (gr < M) v = *reinterpret_cast<const float4*>(&A[(size_t)gr * K + k0 + kq * 4]);
      As[kq*4+0][row] = v.x; As[kq*4+1][row] = v.y;
      As[kq*4+2][row] = v.z; As[kq*4+3][row] = v.w;
    }
    // B tile: BN*BK = 2048 floats = 512 float4, 2 per thread (N multiple of 64)
    #pragma unroll
    for (int s = 0; s < 2; s++){
      int q = tid + 256 * s;
      int row = q >> 3;
      int kq  = q & 7;
      float4 v = *reinterpret_cast<const float4*>(&B[(size_t)(n0 + row) * K + k0 + kq * 4]);
      Bs[kq*4+0][row] = v.x; Bs[kq*4+1][row] = v.y;
      Bs[kq*4+2][row] = v.z; Bs[kq*4+3][row] = v.w;
    }
    __syncthreads();
    #pragma unroll
    for (int kk = 0; kk < BK; kk++){
      const float4 a0 = *reinterpret_cast<const float4*>(&As[kk][ty*8]);
      const float4 a1 = *reinterpret_cast<const float4*>(&As[kk][ty*8+4]);
      const float4 b0 = *reinterpret_cast<const float4*>(&Bs[kk][tx*4]);
      const float a[8] = {a0.x,a0.y,a0.z,a0.w,a1.x,a1.y,a1.z,a1.w};
      const float b[4] = {b0.x,b0.y,b0.z,b0.w};
      #pragma unroll
      for (int i = 0; i < 8; i++)
        #pragma unroll
        for (int j = 0; j < 4; j++)
          acc[i][j] = fmaf(a[i], b[j], acc[i][j]);
    }
    __syncthreads();
  }

  #pragma unroll
  for (int i = 0; i < 8; i++){
    int gr = m0 + ty*8 + i;
    if (gr >= M) continue;
    int gc = n0 + tx*4;
    float4 r;
    r.x = acc[i][0] + bias[gc+0];
    r.y = acc[i][1] + bias[gc+1];
    r.z = acc[i][2] + bias[gc+2];
    r.w = acc[i][3] + bias[gc+3];
    if (ACT){
      r.x = r.x > 0.f ? r.x : 0.01f*r.x;
      r.y = r.y > 0.f ? r.y : 0.01f*r.y;
      r.z = r.z > 0.f ? r.z : 0.01f*r.z;
      r.w = r.w > 0.f ? r.w : 0.01f*r.w;
    }
    *reinterpret_cast<float4*>(&C[(size_t)gr * N + gc]) = r;
  }
}

// ---------------- graph-norm helpers ----------------
__global__ void deg_kernel(const int* __restrict__ ei, int* __restrict__ counts){
  for (int e = blockIdx.x * blockDim.x + threadIdx.x; e < NE; e += gridDim.x * blockDim.x)
    atomicAdd(&counts[ei[NE + e]], 1);
}

__global__ void dinv_kernel(const int* __restrict__ counts, float* __restrict__ dinv){
  int i = blockIdx.x * blockDim.x + threadIdx.x;
  if (i < NN) dinv[i] = rsqrtf((float)(counts[i] + 1));   // +1 self-loop, deg>=1 always
}

__global__ __launch_bounds__(1024) void scan_kernel(const int* __restrict__ counts,
                                                    int* __restrict__ indptr,
                                                    int* __restrict__ cursor, int n){
  __shared__ int wsum[16];
  const int tid  = threadIdx.x;
  const int lane = tid & 63;
  const int wid  = tid >> 6;
  int running = 0;
  for (int base = 0; base < n; base += 1024){
    int idx = base + tid;
    int v = (idx < n) ? counts[idx] : 0;
    int incl = v;
    #pragma unroll
    for (int o = 1; o < 64; o <<= 1){
      int u = __shfl_up(incl, o);
      if (lane >= o) incl += u;
    }
    if (lane == 63) wsum[wid] = incl;
    __syncthreads();
    int woff = 0, total = 0;
    #pragma unroll
    for (int w2 = 0; w2 < 16; w2++){
      int s = wsum[w2];
      if (w2 < wid) woff += s;
      total += s;
    }
    int excl = running + woff + (incl - v);
    if (idx < n){ indptr[idx] = excl; cursor[idx] = excl; }
    running += total;
    __syncthreads();
  }
  if (tid == 0) indptr[n] = running;
}

__global__ void scatter_kernel(const int* __restrict__ ei, int* __restrict__ cursor,
                               int* __restrict__ csr){
  for (int e = blockIdx.x * blockDim.x + threadIdx.x; e < NE; e += gridDim.x * blockDim.x){
    int s = ei[e];
    int d = ei[NE + e];
    int pos = atomicAdd(&cursor[d], 1);
    csr[pos] = s;
  }
}

// ---------------- normalize rows of x ----------------
__global__ __launch_bounds__(256) void normalize_kernel(float* __restrict__ x){
  int node = blockIdx.x * 4 + (threadIdx.x >> 6);
  if (node >= NN) return;
  int lane = threadIdx.x & 63;
  float v = x[(size_t)node * DD + lane];
  float ss = v * v;
  #pragma unroll
  for (int o = 1; o < 64; o <<= 1) ss += __shfl_xor(ss, o);
  float nrm = sqrtf(ss);
  x[(size_t)node * DD + lane] = v / fmaxf(nrm, 1e-12f);
}

// ---------------- hlin = in @ conv_w^T  (64x64 weight in LDS) ----------------
__global__ __launch_bounds__(256) void lin_kernel(const float* __restrict__ in,
                                                  const float* __restrict__ w,
                                                  float* __restrict__ out){
  __shared__ float W[DD][DD + 1];
  for (int q = threadIdx.x; q < DD * DD; q += 256) W[q >> 6][q & 63] = w[q];
  __syncthreads();
  int node = blockIdx.x * 4 + (threadIdx.x >> 6);
  if (node >= NN) return;
  int lane = threadIdx.x & 63;
  const float* r = in + (size_t)node * DD;
  float acc = 0.f;
  #pragma unroll
  for (int d = 0; d < DD; d++) acc = fmaf(r[d], W[lane][d], acc);
  out[(size_t)node * DD + lane] = acc;
}

// ---------------- per-node gather aggregation (one wave per node) ----------------
template<int FINAL>
__global__ __launch_bounds__(256) void agg_kernel(const float* __restrict__ hlin,
                                                  const float* __restrict__ dinv,
                                                  const int* __restrict__ indptr,
                                                  const int* __restrict__ csr,
                                                  const float* __restrict__ bias,
                                                  const float* __restrict__ x,
                                                  const float* __restrict__ h,
                                                  float* __restrict__ out){
  int node = blockIdx.x * 4 + (threadIdx.x >> 6);
  if (node >= NN) return;
  int lane = threadIdx.x & 63;
  float di = dinv[node];
  float acc = di * hlin[(size_t)node * DD + lane];   // self-loop (x di later -> di^2)
  int e0 = indptr[node], e1 = indptr[node + 1];
  for (int k = e0; k < e1; k++){
    int j = csr[k];
    acc = fmaf(dinv[j], hlin[(size_t)j * DD + lane], acc);
  }
  float r = fmaf(di, acc, bias[lane]);
  if (FINAL) r += x[(size_t)node * DD + lane] + h[(size_t)node * DD + lane];
  out[(size_t)node * DD + lane] = r;
}

extern "C" void kernel_launch(void* const* d_in, const int* in_sizes, int n_in,
                              void* d_out, int out_size, void* d_ws, size_t ws_size,
                              hipStream_t stream){
  const int*   ei    = (const int*)  d_in[0];
  const float* feats = (const float*)d_in[1];
  const float* pref  = (const float*)d_in[2];
  const float* w1    = (const float*)d_in[3];
  const float* b1    = (const float*)d_in[4];
  const float* w2    = (const float*)d_in[5];
  const float* b2    = (const float*)d_in[6];
  const float* cw    = (const float*)d_in[7];
  const float* cb    = (const float*)d_in[8];
  float* out = (float*)d_out;

  // workspace layout (floats unless noted):
  //   x      : NN*DD                     (20.5 MB)
  //   bigbuf : NITEM*HIDN = 12.8M floats (51.2 MB) -- GEMM1 hidden, later reused:
  //            hlin = bigbuf[0 .. NN*DD), hbuf = bigbuf[NN*DD .. 2*NN*DD)
  //   dinv   : NN
  //   counts : NN ints | indptr : NN+1 ints | cursor : NN ints | csr : NE ints
  float* ws     = (float*)d_ws;
  float* x      = ws;
  float* bigbuf = x + (size_t)NN * DD;
  float* hidden = bigbuf;
  float* hlin   = bigbuf;
  float* hbuf   = bigbuf + (size_t)NN * DD;
  float* dinv   = bigbuf + (size_t)NITEM * HIDN;
  int*   counts = (int*)(dinv + NN);
  int*   indptr = counts + NN;
  int*   cursor = indptr + NN + 1;
  int*   csr    = cursor + NN;

  hipMemsetAsync(counts, 0, NN * sizeof(int), stream);

  // MLP: hidden = leaky(features @ w1^T + b1); temp = hidden @ w2^T + b2 -> x[NUSER..]
  gemm_nt<1><<<dim3(HIDN / BN, (NITEM + BM - 1) / BM), 256, 0, stream>>>(
      feats, w1, b1, hidden, NITEM, HIDN, FEAT);
  gemm_nt<0><<<dim3(DD / BN, (NITEM + BM - 1) / BM), 256, 0, stream>>>(
      hidden, w2, b2, x + (size_t)NUSER * DD, NITEM, DD, HIDN);
  hipMemcpyAsync(x, pref, (size_t)NUSER * DD * sizeof(float),
                 hipMemcpyDeviceToDevice, stream);
  normalize_kernel<<<NN / 4, 256, 0, stream>>>(x);

  // gcn_norm + CSR build
  deg_kernel<<<2048, 256, 0, stream>>>(ei, counts);
  dinv_kernel<<<(NN + 255) / 256, 256, 0, stream>>>(counts, dinv);
  scan_kernel<<<1, 1024, 0, stream>>>(counts, indptr, cursor, NN);
  scatter_kernel<<<2048, 256, 0, stream>>>(ei, cursor, csr);

  // conv1: h = agg(x @ cw^T) + cb
  lin_kernel<<<NN / 4, 256, 0, stream>>>(x, cw, hlin);
  agg_kernel<0><<<NN / 4, 256, 0, stream>>>(hlin, dinv, indptr, csr, cb,
                                            nullptr, nullptr, hbuf);
  // conv2 + residual: out = x + h + (agg(h @ cw^T) + cb)
  lin_kernel<<<NN / 4, 256, 0, stream>>>(hbuf, cw, hlin);
  agg_kernel<1><<<NN / 4, 256, 0, stream>>>(hlin, dinv, indptr, csr, cb,
                                            x, hbuf, out);

  // output 1: preference passthrough
  hipMemcpyAsync(out + (size_t)NN * DD, pref, (size_t)NUSER * DD * sizeof(float),
                 hipMemcpyDeviceToDevice, stream);
}

// Round 2
// 599.329 us; speedup vs baseline: 1.3679x; 1.3679x over previous
//
#include <hip/hip_runtime.h>

#define NUSER 30000
#define NITEM 50000
#define NN    80000
#define NE    1200000
#define DD    64
#define FEAT  512
#define HIDN  256
#define MPAD  50048           // NITEM rounded up to 128

#define NB    79              // ceil(NN/1024) scan blocks

using s16x8 = __attribute__((ext_vector_type(8))) short;
using f32x4 = __attribute__((ext_vector_type(4))) float;

__device__ __forceinline__ unsigned short f2bf(float f){
  unsigned int u = __float_as_uint(f);
  unsigned int r = (u + 0x7fffu + ((u >> 16) & 1u)) >> 16;
  return (unsigned short)r;
}

__device__ __forceinline__ void gload_lds16(const void* g, void* l){
  __builtin_amdgcn_global_load_lds(
      (const __attribute__((address_space(1))) unsigned int*)g,
      (__attribute__((address_space(3))) unsigned int*)l, 16, 0, 0);
}

// ---------------- fp32 -> bf16 convert (quad-vectorized, zero-pads tail rows) ----------------
__global__ __launch_bounds__(256) void cvt_bf16(const float* __restrict__ in,
                                                unsigned short* __restrict__ out,
                                                long nq_in, long nq_tot){
  for (long q = (long)blockIdx.x * blockDim.x + threadIdx.x; q < nq_tot;
       q += (long)gridDim.x * blockDim.x){
    float4 v = (q < nq_in) ? ((const float4*)in)[q] : make_float4(0.f, 0.f, 0.f, 0.f);
    ushort4 o;
    o.x = f2bf(v.x); o.y = f2bf(v.y); o.z = f2bf(v.z); o.w = f2bf(v.w);
    ((ushort4*)out)[q] = o;
  }
}

// ---------------- MFMA GEMM: C[M,N] = A[Mpad,K]_bf16 @ B[N,K]_bf16^T + bias ----------------
// m97 structure: BM=128, BK=32, 4 waves (2x2), global_load_lds width 16, 2-barrier K-loop.
template<int BN, int ACT, int OUT_BF16>
__global__ __launch_bounds__(256) void gemm_mfma(const short* __restrict__ Ag,
                                                 const short* __restrict__ Bg,
                                                 const float* __restrict__ bias,
                                                 void* __restrict__ Cout,
                                                 int M, int K, int ldc){
  constexpr int BM = 128;
  constexpr int BK = 32;
  constexpr int NFRAG = BN / 32;          // per-wave 16-col fragments
  __shared__ __align__(16) short As[BM * BK];
  __shared__ __align__(16) short Bs[BN * BK];

  const int tid  = threadIdx.x;
  const int wid  = tid >> 6;
  const int lane = tid & 63;
  const int wr   = wid >> 1;              // wave row (0..1), 64 rows each
  const int wc   = wid & 1;               // wave col (0..1), BN/2 cols each
  const int m0   = blockIdx.y * BM;
  const int n0   = blockIdx.x * BN;

  f32x4 acc[4][NFRAG] = {};

  for (int k0 = 0; k0 < K; k0 += BK){
    // stage A: BM*BK*2B = 8192B = 512 x 16B chunks, 2 issues of 256 threads
    #pragma unroll
    for (int s = 0; s < 2; s++){
      int q = s * 256 + tid;
      int row = q >> 2, kc = q & 3;                 // 4 chunks per 32-elem row
      const short* src = Ag + (size_t)(m0 + row) * K + k0 + kc * 8;
      gload_lds16(src, &As[(size_t)(s * 256 + wid * 64) * 8]);
    }
    // stage B: BN*BK*2B, BN/64 issues
    #pragma unroll
    for (int s = 0; s < BN / 64; s++){
      int q = s * 256 + tid;
      int row = q >> 2, kc = q & 3;
      const short* src = Bg + (size_t)(n0 + row) * K + k0 + kc * 8;
      gload_lds16(src, &Bs[(size_t)(s * 256 + wid * 64) * 8]);
    }
    __syncthreads();   // drains vmcnt

    s16x8 af[4], bf[NFRAG];
    #pragma unroll
    for (int m = 0; m < 4; m++)
      af[m] = *(const s16x8*)&As[(wr * 64 + m * 16 + (lane & 15)) * BK + (lane >> 4) * 8];
    #pragma unroll
    for (int n = 0; n < NFRAG; n++)
      bf[n] = *(const s16x8*)&Bs[(wc * (BN / 2) + n * 16 + (lane & 15)) * BK + (lane >> 4) * 8];
    #pragma unroll
    for (int m = 0; m < 4; m++)
      #pragma unroll
      for (int n = 0; n < NFRAG; n++)
        acc[m][n] = __builtin_amdgcn_mfma_f32_16x16x32_bf16(af[m], bf[n], acc[m][n], 0, 0, 0);
    __syncthreads();
  }

  // epilogue: C/D layout col=lane&15, row=(lane>>4)*4+r  [m89/m91-verified]
  #pragma unroll
  for (int m = 0; m < 4; m++){
    int row_base = m0 + wr * 64 + m * 16 + (lane >> 4) * 4;
    #pragma unroll
    for (int n = 0; n < NFRAG; n++){
      int col = n0 + wc * (BN / 2) + n * 16 + (lane & 15);
      float bi = bias[col];
      #pragma unroll
      for (int r = 0; r < 4; r++){
        int row = row_base + r;
        if (row >= M) continue;
        float v = acc[m][n][r] + bi;
        if (ACT) v = v > 0.f ? v : 0.01f * v;
        if (OUT_BF16) ((unsigned short*)Cout)[(size_t)row * ldc + col] = f2bf(v);
        else          ((float*)Cout)[(size_t)row * ldc + col] = v;
      }
    }
  }
}

// ---------------- graph-norm helpers ----------------
__global__ void deg_kernel(const int* __restrict__ ei, int* __restrict__ counts){
  for (int e = blockIdx.x * blockDim.x + threadIdx.x; e < NE; e += gridDim.x * blockDim.x)
    atomicAdd(&counts[ei[NE + e]], 1);
}

__global__ void dinv_kernel(const int* __restrict__ counts, float* __restrict__ dinv){
  int i = blockIdx.x * blockDim.x + threadIdx.x;
  if (i < NN) dinv[i] = rsqrtf((float)(counts[i] + 1));   // +1 self-loop
}

// hierarchical scan: per-block sums -> scan of block sums -> apply
__global__ __launch_bounds__(256) void scan_part(const int* __restrict__ counts,
                                                 int* __restrict__ bsum){
  __shared__ int ws4[4];
  int b = blockIdx.x, base = b * 1024;
  int v = 0;
  #pragma unroll
  for (int s = 0; s < 4; s++){
    int idx = base + s * 256 + threadIdx.x;
    if (idx < NN) v += counts[idx];
  }
  int lane = threadIdx.x & 63, w = threadIdx.x >> 6;
  #pragma unroll
  for (int o = 1; o < 64; o <<= 1) v += __shfl_xor(v, o);
  if (lane == 0) ws4[w] = v;
  __syncthreads();
  if (threadIdx.x == 0) bsum[b] = ws4[0] + ws4[1] + ws4[2] + ws4[3];
}

__global__ __launch_bounds__(128) void scan_tops(const int* __restrict__ bsum,
                                                 int* __restrict__ boff,
                                                 int* __restrict__ indptr){
  __shared__ int tot0;
  int tid = threadIdx.x;
  int v = (tid < NB) ? bsum[tid] : 0;
  int lane = tid & 63, w = tid >> 6;
  int incl = v;
  #pragma unroll
  for (int o = 1; o < 64; o <<= 1){ int u = __shfl_up(incl, o); if (lane >= o) incl += u; }
  if (w == 0 && lane == 63) tot0 = incl;
  __syncthreads();
  int excl = incl - v + (w ? tot0 : 0);
  if (tid < NB) boff[tid] = excl;
  if (tid == 127) indptr[NN] = tot0 + incl;
}

__global__ __launch_bounds__(1024) void scan_apply(const int* __restrict__ counts,
                                                   const int* __restrict__ boff,
                                                   int* __restrict__ indptr,
                                                   int* __restrict__ cursor){
  __shared__ int wsum[16];
  int b = blockIdx.x, tid = threadIdx.x;
  int idx = b * 1024 + tid;
  int v = (idx < NN) ? counts[idx] : 0;
  int lane = tid & 63, w = tid >> 6;
  int incl = v;
  #pragma unroll
  for (int o = 1; o < 64; o <<= 1){ int u = __shfl_up(incl, o); if (lane >= o) incl += u; }
  if (lane == 63) wsum[w] = incl;
  __syncthreads();
  int woff = 0;
  #pragma unroll
  for (int k = 0; k < 16; k++) if (k < w) woff += wsum[k];
  int excl = boff[b] + woff + incl - v;
  if (idx < NN){ indptr[idx] = excl; cursor[idx] = excl; }
}

__global__ void scatter_kernel(const int* __restrict__ ei, int* __restrict__ cursor,
                               int* __restrict__ csr){
  for (int e = blockIdx.x * blockDim.x + threadIdx.x; e < NE; e += gridDim.x * blockDim.x){
    int s = ei[e];
    int d = ei[NE + e];
    int pos = atomicAdd(&cursor[d], 1);
    csr[pos] = s;
  }
}

// ---------------- normalize rows of x ----------------
__global__ __launch_bounds__(256) void normalize_kernel(float* __restrict__ x){
  int node = blockIdx.x * 4 + (threadIdx.x >> 6);
  if (node >= NN) return;
  int lane = threadIdx.x & 63;
  float v = x[(size_t)node * DD + lane];
  float ss = v * v;
  #pragma unroll
  for (int o = 1; o < 64; o <<= 1) ss += __shfl_xor(ss, o);
  float nrm = sqrtf(ss);
  x[(size_t)node * DD + lane] = v / fmaxf(nrm, 1e-12f);
}

// ---------------- hlin = in @ conv_w^T ----------------
__global__ __launch_bounds__(256) void lin_kernel(const float* __restrict__ in,
                                                  const float* __restrict__ w,
                                                  float* __restrict__ out){
  __shared__ float W[DD][DD + 1];
  for (int q = threadIdx.x; q < DD * DD; q += 256) W[q >> 6][q & 63] = w[q];
  __syncthreads();
  int node = blockIdx.x * 4 + (threadIdx.x >> 6);
  if (node >= NN) return;
  int lane = threadIdx.x & 63;
  const float* r = in + (size_t)node * DD;
  float acc = 0.f;
  #pragma unroll
  for (int d = 0; d < DD; d++) acc = fmaf(r[d], W[lane][d], acc);
  out[(size_t)node * DD + lane] = acc;
}

// ---------------- per-node gather aggregation (one wave per node) ----------------
template<int FINAL>
__global__ __launch_bounds__(256) void agg_kernel(const float* __restrict__ hlin,
                                                  const float* __restrict__ dinv,
                                                  const int* __restrict__ indptr,
                                                  const int* __restrict__ csr,
                                                  const float* __restrict__ bias,
                                                  const float* __restrict__ x,
                                                  const float* __restrict__ h,
                                                  float* __restrict__ out){
  int node = blockIdx.x * 4 + (threadIdx.x >> 6);
  if (node >= NN) return;
  int lane = threadIdx.x & 63;
  float di = dinv[node];
  float acc = di * hlin[(size_t)node * DD + lane];   // self-loop
  int e0 = indptr[node], e1 = indptr[node + 1];
  for (int k = e0; k < e1; k++){
    int j = csr[k];
    acc = fmaf(dinv[j], hlin[(size_t)j * DD + lane], acc);
  }
  float r = fmaf(di, acc, bias[lane]);
  if (FINAL) r += x[(size_t)node * DD + lane] + h[(size_t)node * DD + lane];
  out[(size_t)node * DD + lane] = r;
}

extern "C" void kernel_launch(void* const* d_in, const int* in_sizes, int n_in,
                              void* d_out, int out_size, void* d_ws, size_t ws_size,
                              hipStream_t stream){
  const int*   ei    = (const int*)  d_in[0];
  const float* feats = (const float*)d_in[1];
  const float* pref  = (const float*)d_in[2];
  const float* w1    = (const float*)d_in[3];
  const float* b1    = (const float*)d_in[4];
  const float* w2    = (const float*)d_in[5];
  const float* b2    = (const float*)d_in[6];
  const float* cw    = (const float*)d_in[7];
  const float* cb    = (const float*)d_in[8];
  float* out = (float*)d_out;

  // ---- workspace layout (byte offsets), with lifetime-based overlap ----
  // [0, 51.25MB)  feats_bf16 [MPAD*512]          (dead after GEMM1)
  //   overlaid after GEMM1/2 by:
  //   [0, 20.48MB)      x [NN*DD] f32
  //   [20.48, 40.96MB)  hbuf [NN*DD] f32
  //   [40.96, ~47MB)    graph ints: dinv|counts|indptr|cursor|csr|bsum|boff
  // [51.25, 76.87MB) hidden_bf16 [MPAD*256]      (dead after GEMM2)
  //   overlaid after GEMM2 by hlin [NN*DD] f32
  // [76.87, 77.17MB) w1_bf16, w2_bf16
  char* wsb = (char*)d_ws;
  short* featsb  = (short*)wsb;
  float* x       = (float*)wsb;
  float* hbuf    = (float*)(wsb + (size_t)NN * DD * 4);
  char*  graphb  = wsb + (size_t)NN * DD * 8;
  float* dinv    = (float*)graphb;
  int*   counts  = (int*)(dinv + NN);
  int*   indptr  = counts + NN;
  int*   cursor  = indptr + NN + 1;
  int*   csr     = cursor + NN;
  int*   bsum    = csr + NE;
  int*   boff    = bsum + NB + 1;
  char*  hidb_c  = wsb + (size_t)MPAD * FEAT * 2;
  short* hiddenb = (short*)hidb_c;
  float* hlin    = (float*)hidb_c;
  short* w1b     = (short*)(wsb + (size_t)MPAD * FEAT * 2 + (size_t)MPAD * HIDN * 2);
  short* w2b     = w1b + (size_t)HIDN * FEAT;

  // ---- convert weights + features to bf16 ----
  cvt_bf16<<<128, 256, 0, stream>>>(w1, (unsigned short*)w1b,
                                    (long)HIDN * FEAT / 4, (long)HIDN * FEAT / 4);
  cvt_bf16<<<16, 256, 0, stream>>>(w2, (unsigned short*)w2b,
                                   (long)DD * HIDN / 4, (long)DD * HIDN / 4);
  cvt_bf16<<<2048, 256, 0, stream>>>(feats, (unsigned short*)featsb,
                                     (long)NITEM * FEAT / 4, (long)MPAD * FEAT / 4);

  // ---- MLP: hidden = leaky(feats @ w1^T + b1) ; temp = hidden @ w2^T + b2 ----
  gemm_mfma<128, 1, 1><<<dim3(HIDN / 128, MPAD / 128), 256, 0, stream>>>(
      featsb, w1b, b1, hiddenb, NITEM, FEAT, HIDN);
  gemm_mfma<64, 0, 0><<<dim3(1, MPAD / 128), 256, 0, stream>>>(
      hiddenb, w2b, b2, x + (size_t)NUSER * DD, NITEM, HIDN, DD);

  hipMemcpyAsync(x, pref, (size_t)NUSER * DD * sizeof(float),
                 hipMemcpyDeviceToDevice, stream);
  normalize_kernel<<<NN / 4, 256, 0, stream>>>(x);

  // ---- gcn_norm + CSR build (buffers overlap feats_bf16: must run after GEMM1) ----
  hipMemsetAsync(counts, 0, NN * sizeof(int), stream);
  deg_kernel<<<2048, 256, 0, stream>>>(ei, counts);
  dinv_kernel<<<(NN + 255) / 256, 256, 0, stream>>>(counts, dinv);
  scan_part<<<NB, 256, 0, stream>>>(counts, bsum);
  scan_tops<<<1, 128, 0, stream>>>(bsum, boff, indptr);
  scan_apply<<<NB, 1024, 0, stream>>>(counts, boff, indptr, cursor);
  scatter_kernel<<<2048, 256, 0, stream>>>(ei, cursor, csr);

  // ---- conv1: hbuf = agg(x @ cw^T) + cb ----
  lin_kernel<<<NN / 4, 256, 0, stream>>>(x, cw, hlin);
  agg_kernel<0><<<NN / 4, 256, 0, stream>>>(hlin, dinv, indptr, csr, cb,
                                            nullptr, nullptr, hbuf);
  // ---- conv2 + residual: out = x + hbuf + (agg(hbuf @ cw^T) + cb) ----
  lin_kernel<<<NN / 4, 256, 0, stream>>>(hbuf, cw, hlin);
  agg_kernel<1><<<NN / 4, 256, 0, stream>>>(hlin, dinv, indptr, csr, cb,
                                            x, hbuf, out);

  // ---- output 1: preference passthrough ----
  hipMemcpyAsync(out + (size_t)NN * DD, pref, (size_t)NUSER * DD * sizeof(float),
                 hipMemcpyDeviceToDevice, stream);
}

// Round 3
// 441.295 us; speedup vs baseline: 1.8578x; 1.3581x over previous
//
#include <hip/hip_runtime.h>

#define NUSER 30000
#define NITEM 50000
#define NN    80000
#define NE    1200000
#define DD    64
#define FEAT  512
#define HIDN  256
#define MPAD  50048           // NITEM rounded up to 128
#define NB    79              // ceil(NN/1024) scan blocks
#define CSRCAP (NE + 4 * NN)  // padded CSR capacity

using s16x8 = __attribute__((ext_vector_type(8))) short;
using f32x4 = __attribute__((ext_vector_type(4))) float;

__device__ __forceinline__ unsigned short f2bf(float f){
  unsigned int u = __float_as_uint(f);
  unsigned int r = (u + 0x7fffu + ((u >> 16) & 1u)) >> 16;
  return (unsigned short)r;
}

__device__ __forceinline__ void gload_lds16(const void* g, void* l){
  __builtin_amdgcn_global_load_lds(
      (const __attribute__((address_space(1))) unsigned int*)g,
      (__attribute__((address_space(3))) unsigned int*)l, 16, 0, 0);
}

// ---------------- fp32 -> bf16 convert: w1 | w2 | feats(+pad) in one launch ----------------
#define QW1 ((long)HIDN * FEAT / 4)
#define QW2 ((long)DD * HIDN / 4)
#define QFI ((long)NITEM * FEAT / 4)
#define QFT ((long)MPAD * FEAT / 4)
__global__ __launch_bounds__(256) void cvt_all(const float* __restrict__ w1,
                                               const float* __restrict__ w2,
                                               const float* __restrict__ feats,
                                               unsigned short* __restrict__ w1b,
                                               unsigned short* __restrict__ w2b,
                                               unsigned short* __restrict__ featsb){
  const long ntot = QW1 + QW2 + QFT;
  for (long q = (long)blockIdx.x * blockDim.x + threadIdx.x; q < ntot;
       q += (long)gridDim.x * blockDim.x){
    const float4* src; ushort4* dst; long i;
    if (q < QW1){ src = (const float4*)w1; dst = (ushort4*)w1b; i = q; }
    else if (q < QW1 + QW2){ src = (const float4*)w2; dst = (ushort4*)w2b; i = q - QW1; }
    else { src = (const float4*)feats; dst = (ushort4*)featsb; i = q - QW1 - QW2; }
    float4 v = make_float4(0.f, 0.f, 0.f, 0.f);
    if (dst != (ushort4*)featsb || i < QFI) v = src[i];
    ushort4 o;
    o.x = f2bf(v.x); o.y = f2bf(v.y); o.z = f2bf(v.z); o.w = f2bf(v.w);
    dst[i] = o;
  }
}

// ---------------- MFMA GEMM: C[M,N] = A[Mpad,K]_bf16 @ B[N,K]_bf16^T + bias ----------------
template<int BN, int ACT, int OUT_BF16>
__global__ __launch_bounds__(256) void gemm_mfma(const short* __restrict__ Ag,
                                                 const short* __restrict__ Bg,
                                                 const float* __restrict__ bias,
                                                 void* __restrict__ Cout,
                                                 int M, int K, int ldc){
  constexpr int BM = 128;
  constexpr int BK = 32;
  constexpr int NFRAG = BN / 32;
  __shared__ __align__(16) short As[BM * BK];
  __shared__ __align__(16) short Bs[BN * BK];

  const int tid  = threadIdx.x;
  const int wid  = tid >> 6;
  const int lane = tid & 63;
  const int wr   = wid >> 1;
  const int wc   = wid & 1;
  const int m0   = blockIdx.y * BM;
  const int n0   = blockIdx.x * BN;

  f32x4 acc[4][NFRAG] = {};

  for (int k0 = 0; k0 < K; k0 += BK){
    #pragma unroll
    for (int s = 0; s < 2; s++){
      int q = s * 256 + tid;
      int row = q >> 2, kc = q & 3;
      const short* src = Ag + (size_t)(m0 + row) * K + k0 + kc * 8;
      gload_lds16(src, &As[(size_t)(s * 256 + wid * 64) * 8]);
    }
    #pragma unroll
    for (int s = 0; s < BN / 64; s++){
      int q = s * 256 + tid;
      int row = q >> 2, kc = q & 3;
      const short* src = Bg + (size_t)(n0 + row) * K + k0 + kc * 8;
      gload_lds16(src, &Bs[(size_t)(s * 256 + wid * 64) * 8]);
    }
    __syncthreads();

    s16x8 af[4], bf[NFRAG];
    #pragma unroll
    for (int m = 0; m < 4; m++)
      af[m] = *(const s16x8*)&As[(wr * 64 + m * 16 + (lane & 15)) * BK + (lane >> 4) * 8];
    #pragma unroll
    for (int n = 0; n < NFRAG; n++)
      bf[n] = *(const s16x8*)&Bs[(wc * (BN / 2) + n * 16 + (lane & 15)) * BK + (lane >> 4) * 8];
    #pragma unroll
    for (int m = 0; m < 4; m++)
      #pragma unroll
      for (int n = 0; n < NFRAG; n++)
        acc[m][n] = __builtin_amdgcn_mfma_f32_16x16x32_bf16(af[m], bf[n], acc[m][n], 0, 0, 0);
    __syncthreads();
  }

  #pragma unroll
  for (int m = 0; m < 4; m++){
    int row_base = m0 + wr * 64 + m * 16 + (lane >> 4) * 4;
    #pragma unroll
    for (int n = 0; n < NFRAG; n++){
      int col = n0 + wc * (BN / 2) + n * 16 + (lane & 15);
      float bi = bias[col];
      #pragma unroll
      for (int r = 0; r < 4; r++){
        int row = row_base + r;
        if (row >= M) continue;
        float v = acc[m][n][r] + bi;
        if (ACT) v = v > 0.f ? v : 0.01f * v;
        if (OUT_BF16) ((unsigned short*)Cout)[(size_t)row * ldc + col] = f2bf(v);
        else          ((float*)Cout)[(size_t)row * ldc + col] = v;
      }
    }
  }
}

// ---------------- graph-norm helpers ----------------
__global__ void deg_kernel(const int* __restrict__ ei, int* __restrict__ counts){
  for (int e = blockIdx.x * blockDim.x + threadIdx.x; e < NE; e += gridDim.x * blockDim.x)
    atomicAdd(&counts[ei[NE + e]], 1);
}

// dinv = rsqrt(deg+1); pcnt = ceil((deg+1+1self)/4)*4  (padded adjacency incl. self)
__global__ void dinv_kernel(const int* __restrict__ counts, float* __restrict__ dinv,
                            int* __restrict__ pcnt){
  int i = blockIdx.x * blockDim.x + threadIdx.x;
  if (i < NN){
    int d = counts[i];
    dinv[i] = rsqrtf((float)(d + 1));
    pcnt[i] = (d + 1 + 3) & ~3;
  }
}

// hierarchical scan over pcnt
__global__ __launch_bounds__(256) void scan_part(const int* __restrict__ pcnt,
                                                 int* __restrict__ bsum){
  __shared__ int ws4[4];
  int b = blockIdx.x, base = b * 1024;
  int v = 0;
  #pragma unroll
  for (int s = 0; s < 4; s++){
    int idx = base + s * 256 + threadIdx.x;
    if (idx < NN) v += pcnt[idx];
  }
  int lane = threadIdx.x & 63, w = threadIdx.x >> 6;
  #pragma unroll
  for (int o = 1; o < 64; o <<= 1) v += __shfl_xor(v, o);
  if (lane == 0) ws4[w] = v;
  __syncthreads();
  if (threadIdx.x == 0) bsum[b] = ws4[0] + ws4[1] + ws4[2] + ws4[3];
}

__global__ __launch_bounds__(128) void scan_tops(const int* __restrict__ bsum,
                                                 int* __restrict__ boff,
                                                 int* __restrict__ indptr){
  __shared__ int tot0;
  int tid = threadIdx.x;
  int v = (tid < NB) ? bsum[tid] : 0;
  int lane = tid & 63, w = tid >> 6;
  int incl = v;
  #pragma unroll
  for (int o = 1; o < 64; o <<= 1){ int u = __shfl_up(incl, o); if (lane >= o) incl += u; }
  if (w == 0 && lane == 63) tot0 = incl;
  __syncthreads();
  int excl = incl - v + (w ? tot0 : 0);
  if (tid < NB) boff[tid] = excl;
  if (tid == 127) indptr[NN] = tot0 + incl;
}

__global__ __launch_bounds__(1024) void scan_apply(const int* __restrict__ pcnt,
                                                   const int* __restrict__ boff,
                                                   int* __restrict__ indptr,
                                                   int* __restrict__ cursor){
  __shared__ int wsum[16];
  int b = blockIdx.x, tid = threadIdx.x;
  int idx = b * 1024 + tid;
  int v = (idx < NN) ? pcnt[idx] : 0;
  int lane = tid & 63, w = tid >> 6;
  int incl = v;
  #pragma unroll
  for (int o = 1; o < 64; o <<= 1){ int u = __shfl_up(incl, o); if (lane >= o) incl += u; }
  if (lane == 63) wsum[w] = incl;
  __syncthreads();
  int woff = 0;
  #pragma unroll
  for (int k = 0; k < 16; k++) if (k < w) woff += wsum[k];
  int excl = boff[b] + woff + incl - v;
  if (idx < NN){ indptr[idx] = excl; cursor[idx] = excl; }
}

__global__ void scatter_kernel(const int* __restrict__ ei, int* __restrict__ cursor,
                               int* __restrict__ csr){
  for (int e = blockIdx.x * blockDim.x + threadIdx.x; e < NE; e += gridDim.x * blockDim.x){
    int s = ei[e];
    int d = ei[NE + e];
    int pos = atomicAdd(&cursor[d], 1);
    csr[pos] = s;
  }
}

// append self-edge, fill pad slots with zero-row index NN
__global__ void selfpad_kernel(const int* __restrict__ cursor,
                               const int* __restrict__ indptr,
                               int* __restrict__ csr){
  int i = blockIdx.x * blockDim.x + threadIdx.x;
  if (i >= NN) return;
  int p = cursor[i];           // == indptr[i] + deg after scatter
  int e1 = indptr[i + 1];
  csr[p] = i;                  // self-loop
  for (int q = p + 1; q < e1; q++) csr[q] = NN;   // pad -> zero row
}

// ---------------- fused: (optional normalize) + hs = dinv * (row @ W^T) ----------------
// NORM=1: src row = pref (users) / x (items, from gemm2), normalized, written back to x.
template<int NORM>
__global__ __launch_bounds__(256) void norm_lin(const float* __restrict__ pref,
                                                float* __restrict__ x,
                                                const float* __restrict__ srcb,
                                                const float* __restrict__ w,
                                                const float* __restrict__ dinv,
                                                float* __restrict__ hs){
  __shared__ float W[DD][DD + 1];
  for (int q = threadIdx.x; q < DD * DD; q += 256) W[q >> 6][q & 63] = w[q];
  __syncthreads();
  int node = blockIdx.x * 4 + (threadIdx.x >> 6);
  if (node >= NN) return;
  int lane = threadIdx.x & 63;
  float v;
  if (NORM){
    v = (node < NUSER) ? pref[(size_t)node * DD + lane] : x[(size_t)node * DD + lane];
    float ss = v * v;
    #pragma unroll
    for (int o = 1; o < 64; o <<= 1) ss += __shfl_xor(ss, o);
    v = v / fmaxf(sqrtf(ss), 1e-12f);
    x[(size_t)node * DD + lane] = v;
  } else {
    v = srcb[(size_t)node * DD + lane];
  }
  // broadcast row via LDS-free path: each lane needs full row -> use shuffles? cheaper: LDS row
  __shared__ float rowbuf[4][DD];
  int wv = threadIdx.x >> 6;
  rowbuf[wv][lane] = v;
  __syncthreads();   // waves independent rows; syncthreads ok (all waves reach)
  float acc = 0.f;
  #pragma unroll
  for (int d = 0; d < DD; d++) acc = fmaf(rowbuf[wv][d], W[lane][d], acc);
  hs[(size_t)node * DD + lane] = dinv[node] * acc;
}

// ---------------- gather aggregation: 4 edges in flight, 16 lanes x float4 per row ----------------
// out = dinv[node] * sum(hs[j]) + bias   (+ x + h residual when FINAL)
template<int FINAL>
__global__ __launch_bounds__(256) void agg_kernel(const float* __restrict__ hs,
                                                  const float* __restrict__ dinv,
                                                  const int* __restrict__ indptr,
                                                  const int* __restrict__ csr,
                                                  const float* __restrict__ bias,
                                                  const float* __restrict__ x,
                                                  const float* __restrict__ h,
                                                  float* __restrict__ out,
                                                  const float* __restrict__ pref,
                                                  float* __restrict__ out2){
  int b = blockIdx.x;
  if (FINAL && b >= NN / 4){
    // tail: copy preference rows to out2 (second tuple output)
    long q = (long)(b - NN / 4) * 256 + threadIdx.x;
    if (q < (long)NUSER * DD / 4)
      ((float4*)out2)[q] = ((const float4*)pref)[q];
    return;
  }
  int node = b * 4 + (threadIdx.x >> 6);
  int lane = threadIdx.x & 63;
  int g  = lane >> 4;          // edge group 0..3
  int sl = lane & 15;          // 16 lanes x float4 = one 64-float row
  int e0 = indptr[node];
  int nit = (indptr[node + 1] - e0) >> 2;
  float ax = 0.f, ay = 0.f, az = 0.f, aw = 0.f;
  int k = e0 + g;
  for (int i = 0; i < nit; i++){
    int j = csr[k];
    k += 4;
    float4 v = *(const float4*)&hs[(size_t)j * DD + sl * 4];
    ax += v.x; ay += v.y; az += v.z; aw += v.w;
  }
  // combine the 4 edge groups
  #pragma unroll
  for (int off = 16; off < 64; off <<= 1){
    ax += __shfl_xor(ax, off);
    ay += __shfl_xor(ay, off);
    az += __shfl_xor(az, off);
    aw += __shfl_xor(aw, off);
  }
  if (g == 0){
    float di = dinv[node];
    const float4 bi = *(const float4*)&bias[sl * 4];
    float4 r;
    r.x = fmaf(di, ax, bi.x);
    r.y = fmaf(di, ay, bi.y);
    r.z = fmaf(di, az, bi.z);
    r.w = fmaf(di, aw, bi.w);
    if (FINAL){
      const float4 xv = *(const float4*)&x[(size_t)node * DD + sl * 4];
      const float4 hv = *(const float4*)&h[(size_t)node * DD + sl * 4];
      r.x += xv.x + hv.x; r.y += xv.y + hv.y;
      r.z += xv.z + hv.z; r.w += xv.w + hv.w;
    }
    *(float4*)&out[(size_t)node * DD + sl * 4] = r;
  }
}

extern "C" void kernel_launch(void* const* d_in, const int* in_sizes, int n_in,
                              void* d_out, int out_size, void* d_ws, size_t ws_size,
                              hipStream_t stream){
  const int*   ei    = (const int*)  d_in[0];
  const float* feats = (const float*)d_in[1];
  const float* pref  = (const float*)d_in[2];
  const float* w1    = (const float*)d_in[3];
  const float* b1    = (const float*)d_in[4];
  const float* w2    = (const float*)d_in[5];
  const float* b2    = (const float*)d_in[6];
  const float* cw    = (const float*)d_in[7];
  const float* cb    = (const float*)d_in[8];
  float* out = (float*)d_out;

  // ---- workspace layout (lifetime-overlapped) ----
  // [0, 51.25MB)  feats_bf16 [MPAD*512]  (dead after GEMM1) overlaid by:
  //    x [NN*64] f32 | hbuf [NN*64] f32 | graph ints (dinv,counts,pcnt,indptr,cursor,bsum,boff,csr)
  // [51.25, 76.9MB) hidden_bf16 [MPAD*256] (dead after GEMM2) overlaid by hs [(NN+1)*64] f32
  // [76.9MB, ...)  w1_bf16, w2_bf16
  char* wsb = (char*)d_ws;
  short* featsb  = (short*)wsb;
  float* x       = (float*)wsb;
  float* hbuf    = (float*)(wsb + (size_t)NN * DD * 4);
  char*  graphb  = wsb + (size_t)NN * DD * 8;
  float* dinv    = (float*)graphb;
  int*   counts  = (int*)(dinv + NN);
  int*   pcnt    = counts + NN;
  int*   indptr  = pcnt + NN;
  int*   cursor  = indptr + NN + 1;
  int*   bsum    = cursor + NN;
  int*   boff    = bsum + NB + 1;
  int*   csr     = boff + NB + 1;
  char*  hidb_c  = wsb + (size_t)MPAD * FEAT * 2;
  short* hiddenb = (short*)hidb_c;
  float* hs      = (float*)hidb_c;
  short* w1b     = (short*)(wsb + (size_t)MPAD * FEAT * 2 + (size_t)(MPAD + 64) * HIDN * 2);
  short* w2b     = w1b + (size_t)HIDN * FEAT;

  // ---- bf16 conversions (one launch) ----
  cvt_all<<<2048, 256, 0, stream>>>(w1, w2, feats, (unsigned short*)w1b,
                                    (unsigned short*)w2b, (unsigned short*)featsb);

  // ---- MLP ----
  gemm_mfma<128, 1, 1><<<dim3(HIDN / 128, MPAD / 128), 256, 0, stream>>>(
      featsb, w1b, b1, hiddenb, NITEM, FEAT, HIDN);
  gemm_mfma<64, 0, 0><<<dim3(1, MPAD / 128), 256, 0, stream>>>(
      hiddenb, w2b, b2, x + (size_t)NUSER * DD, NITEM, HIDN, DD);
  // zero row NN of hs (pad target) -- after gemm2 (hs overlays hiddenb)
  hipMemsetAsync(hs + (size_t)NN * DD, 0, DD * sizeof(float), stream);

  // ---- gcn_norm + padded CSR (region overlays featsb: after GEMM1) ----
  hipMemsetAsync(counts, 0, NN * sizeof(int), stream);
  deg_kernel<<<2048, 256, 0, stream>>>(ei, counts);
  dinv_kernel<<<(NN + 255) / 256, 256, 0, stream>>>(counts, dinv, pcnt);
  scan_part<<<NB, 256, 0, stream>>>(pcnt, bsum);
  scan_tops<<<1, 128, 0, stream>>>(bsum, boff, indptr);
  scan_apply<<<NB, 1024, 0, stream>>>(pcnt, boff, indptr, cursor);
  scatter_kernel<<<2048, 256, 0, stream>>>(ei, cursor, csr);
  selfpad_kernel<<<(NN + 255) / 256, 256, 0, stream>>>(cursor, indptr, csr);

  // ---- x = normalize(concat(pref, temp)); hs = dinv * (x @ cw^T) ----
  norm_lin<1><<<NN / 4, 256, 0, stream>>>(pref, x, nullptr, cw, dinv, hs);
  // ---- conv1: hbuf = dinv * sum(hs[j]) + cb ----
  agg_kernel<0><<<NN / 4, 256, 0, stream>>>(hs, dinv, indptr, csr, cb,
                                            nullptr, nullptr, hbuf, nullptr, nullptr);
  // ---- conv2 input: hs = dinv * (hbuf @ cw^T) ----
  norm_lin<0><<<NN / 4, 256, 0, stream>>>(nullptr, nullptr, hbuf, cw, dinv, hs);
  // ---- conv2 + residual + pref tail copy ----
  agg_kernel<1><<<NN / 4 + (NUSER * DD / 4 + 255) / 256, 256, 0, stream>>>(
      hs, dinv, indptr, csr, cb, x, hbuf, out, pref, out + (size_t)NN * DD);
}

// Round 4
// 323.975 us; speedup vs baseline: 2.5305x; 1.3621x over previous
//
#include <hip/hip_runtime.h>

#define NUSER 30000
#define NITEM 50000
#define NN    80000
#define NE    1200000
#define DD    64
#define FEAT  512
#define HIDN  256
#define MPAD  50048           // NITEM rounded up to 128
#define CSRCAP (NE + 4 * NN)  // padded CSR capacity

#define NBUCK  625            // dst >> 7 ; 625*128 == 80000 exactly
#define NCHUNK 256            // edge chunks for histogram/binscat
#define CHSZ   ((NE + NCHUNK - 1) / NCHUNK)   // 4688
#define NHIST  (NBUCK * NCHUNK)               // 160000
#define NPART  ((NHIST + 1023) / 1024)        // 157

using s16x8 = __attribute__((ext_vector_type(8))) short;
using f32x4 = __attribute__((ext_vector_type(4))) float;

__device__ __forceinline__ unsigned short f2bf(float f){
  unsigned int u = __float_as_uint(f);
  unsigned int r = (u + 0x7fffu + ((u >> 16) & 1u)) >> 16;
  return (unsigned short)r;
}

__device__ __forceinline__ void gload_lds16(const void* g, void* l){
  __builtin_amdgcn_global_load_lds(
      (const __attribute__((address_space(1))) unsigned int*)g,
      (__attribute__((address_space(3))) unsigned int*)l, 16, 0, 0);
}

// ---------------- fp32 -> bf16 convert: w1 | w2 | feats(+pad) in one launch ----------------
#define QW1 ((long)HIDN * FEAT / 4)
#define QW2 ((long)DD * HIDN / 4)
#define QFI ((long)NITEM * FEAT / 4)
#define QFT ((long)MPAD * FEAT / 4)
__global__ __launch_bounds__(256) void cvt_all(const float* __restrict__ w1,
                                               const float* __restrict__ w2,
                                               const float* __restrict__ feats,
                                               unsigned short* __restrict__ w1b,
                                               unsigned short* __restrict__ w2b,
                                               unsigned short* __restrict__ featsb){
  const long ntot = QW1 + QW2 + QFT;
  for (long q = (long)blockIdx.x * blockDim.x + threadIdx.x; q < ntot;
       q += (long)gridDim.x * blockDim.x){
    const float4* src; ushort4* dst; long i;
    if (q < QW1){ src = (const float4*)w1; dst = (ushort4*)w1b; i = q; }
    else if (q < QW1 + QW2){ src = (const float4*)w2; dst = (ushort4*)w2b; i = q - QW1; }
    else { src = (const float4*)feats; dst = (ushort4*)featsb; i = q - QW1 - QW2; }
    float4 v = make_float4(0.f, 0.f, 0.f, 0.f);
    if (dst != (ushort4*)featsb || i < QFI) v = src[i];
    ushort4 o;
    o.x = f2bf(v.x); o.y = f2bf(v.y); o.z = f2bf(v.z); o.w = f2bf(v.w);
    dst[i] = o;
  }
}

// ---------------- MFMA GEMM: C[M,N] = A[Mpad,K]_bf16 @ B[N,K]_bf16^T + bias ----------------
template<int BN, int ACT, int OUT_BF16>
__global__ __launch_bounds__(256) void gemm_mfma(const short* __restrict__ Ag,
                                                 const short* __restrict__ Bg,
                                                 const float* __restrict__ bias,
                                                 void* __restrict__ Cout,
                                                 int M, int K, int ldc){
  constexpr int BM = 128;
  constexpr int BK = 32;
  constexpr int NFRAG = BN / 32;
  __shared__ __align__(16) short As[BM * BK];
  __shared__ __align__(16) short Bs[BN * BK];

  const int tid  = threadIdx.x;
  const int wid  = tid >> 6;
  const int lane = tid & 63;
  const int wr   = wid >> 1;
  const int wc   = wid & 1;
  const int m0   = blockIdx.y * BM;
  const int n0   = blockIdx.x * BN;

  f32x4 acc[4][NFRAG] = {};

  for (int k0 = 0; k0 < K; k0 += BK){
    #pragma unroll
    for (int s = 0; s < 2; s++){
      int q = s * 256 + tid;
      int row = q >> 2, kc = q & 3;
      const short* src = Ag + (size_t)(m0 + row) * K + k0 + kc * 8;
      gload_lds16(src, &As[(size_t)(s * 256 + wid * 64) * 8]);
    }
    #pragma unroll
    for (int s = 0; s < BN / 64; s++){
      int q = s * 256 + tid;
      int row = q >> 2, kc = q & 3;
      const short* src = Bg + (size_t)(n0 + row) * K + k0 + kc * 8;
      gload_lds16(src, &Bs[(size_t)(s * 256 + wid * 64) * 8]);
    }
    __syncthreads();

    s16x8 af[4], bf[NFRAG];
    #pragma unroll
    for (int m = 0; m < 4; m++)
      af[m] = *(const s16x8*)&As[(wr * 64 + m * 16 + (lane & 15)) * BK + (lane >> 4) * 8];
    #pragma unroll
    for (int n = 0; n < NFRAG; n++)
      bf[n] = *(const s16x8*)&Bs[(wc * (BN / 2) + n * 16 + (lane & 15)) * BK + (lane >> 4) * 8];
    #pragma unroll
    for (int m = 0; m < 4; m++)
      #pragma unroll
      for (int n = 0; n < NFRAG; n++)
        acc[m][n] = __builtin_amdgcn_mfma_f32_16x16x32_bf16(af[m], bf[n], acc[m][n], 0, 0, 0);
    __syncthreads();
  }

  #pragma unroll
  for (int m = 0; m < 4; m++){
    int row_base = m0 + wr * 64 + m * 16 + (lane >> 4) * 4;
    #pragma unroll
    for (int n = 0; n < NFRAG; n++){
      int col = n0 + wc * (BN / 2) + n * 16 + (lane & 15);
      float bi = bias[col];
      #pragma unroll
      for (int r = 0; r < 4; r++){
        int row = row_base + r;
        if (row >= M) continue;
        float v = acc[m][n][r] + bi;
        if (ACT) v = v > 0.f ? v : 0.01f * v;
        if (OUT_BF16) ((unsigned short*)Cout)[(size_t)row * ldc + col] = f2bf(v);
        else          ((float*)Cout)[(size_t)row * ldc + col] = v;
      }
    }
  }
}

// ================= atomic-free CSR build =================
// Phase A: per-chunk LDS histogram over 625 dst-buckets; exclusive global cells.
__global__ __launch_bounds__(256) void histo_kernel(const int* __restrict__ ei,
                                                    int* __restrict__ hist){
  __shared__ int h[NBUCK];
  const int tid = threadIdx.x, c = blockIdx.x;
  for (int i = tid; i < NBUCK; i += 256) h[i] = 0;
  __syncthreads();
  int e0 = c * CHSZ, e1 = min(e0 + CHSZ, NE);
  for (int e = e0 + tid; e < e1; e += 256)
    atomicAdd(&h[ei[NE + e] >> 7], 1);
  __syncthreads();
  for (int i = tid; i < NBUCK; i += 256) hist[i * NCHUNK + c] = h[i];
}

// generic hierarchical exclusive scan: part -> mid -> apply
__global__ __launch_bounds__(256) void scan_part(const int* __restrict__ a, int n,
                                                 int* __restrict__ bsum){
  __shared__ int ws4[4];
  int b = blockIdx.x, base = b * 1024;
  int v = 0;
  #pragma unroll
  for (int s = 0; s < 4; s++){
    int idx = base + s * 256 + threadIdx.x;
    if (idx < n) v += a[idx];
  }
  int lane = threadIdx.x & 63, w = threadIdx.x >> 6;
  #pragma unroll
  for (int o = 1; o < 64; o <<= 1) v += __shfl_xor(v, o);
  if (lane == 0) ws4[w] = v;
  __syncthreads();
  if (threadIdx.x == 0) bsum[b] = ws4[0] + ws4[1] + ws4[2] + ws4[3];
}

// exclusive scan of np (<=1024) values in one block; optional grand total out
__global__ __launch_bounds__(1024) void scan_mid(const int* __restrict__ a, int np,
                                                 int* __restrict__ excl_out,
                                                 int* __restrict__ total_out){
  __shared__ int wsum[16];
  int tid = threadIdx.x;
  int v = (tid < np) ? a[tid] : 0;
  int lane = tid & 63, w = tid >> 6;
  int incl = v;
  #pragma unroll
  for (int o = 1; o < 64; o <<= 1){ int u = __shfl_up(incl, o); if (lane >= o) incl += u; }
  if (lane == 63) wsum[w] = incl;
  __syncthreads();
  int woff = 0;
  #pragma unroll
  for (int k = 0; k < 16; k++) if (k < w) woff += wsum[k];
  if (tid < np) excl_out[tid] = woff + incl - v;
  if (total_out && tid == 1023) *total_out = woff + incl;
}

__global__ __launch_bounds__(1024) void scan_apply(const int* __restrict__ a,
                                                   const int* __restrict__ boff,
                                                   int* __restrict__ sc, int n){
  __shared__ int wsum[16];
  int b = blockIdx.x, tid = threadIdx.x;
  int idx = b * 1024 + tid;
  int v = (idx < n) ? a[idx] : 0;
  int lane = tid & 63, w = tid >> 6;
  int incl = v;
  #pragma unroll
  for (int o = 1; o < 64; o <<= 1){ int u = __shfl_up(incl, o); if (lane >= o) incl += u; }
  if (lane == 63) wsum[w] = incl;
  __syncthreads();
  int woff = 0;
  #pragma unroll
  for (int k = 0; k < 16; k++) if (k < w) woff += wsum[k];
  if (idx < n) sc[idx] = boff[b] + woff + incl - v;
}

// Phase C: binned scatter of packed (dst&127)<<17 | src, LDS cursors, no global atomics.
__global__ __launch_bounds__(256) void binscat_kernel(const int* __restrict__ ei,
                                                      const int* __restrict__ sc,
                                                      int* __restrict__ pairsv){
  __shared__ int cur[NBUCK];
  const int tid = threadIdx.x, c = blockIdx.x;
  for (int i = tid; i < NBUCK; i += 256) cur[i] = sc[i * NCHUNK + c];
  __syncthreads();
  int e0 = c * CHSZ, e1 = min(e0 + CHSZ, NE);
  for (int e = e0 + tid; e < e1; e += 256){
    int s = ei[e];
    int d = ei[NE + e];
    int pos = atomicAdd(&cur[d >> 7], 1);
    pairsv[pos] = ((d & 127) << 17) | s;
  }
}

// Phase D1: per-bucket per-node degree count + LDS scan of padded counts.
__global__ __launch_bounds__(256) void bucket_count(const int* __restrict__ pairsv,
                                                    const int* __restrict__ sc,
                                                    int* __restrict__ lofs,
                                                    float* __restrict__ dinv,
                                                    int* __restrict__ btot){
  __shared__ int cnt[128];
  __shared__ int wtot;
  const int tid = threadIdx.x, b = blockIdx.x;
  if (tid < 128) cnt[tid] = 0;
  __syncthreads();
  int e0 = sc[b * NCHUNK];
  int e1 = (b == NBUCK - 1) ? NE : sc[(b + 1) * NCHUNK];
  for (int e = e0 + tid; e < e1; e += 256)
    atomicAdd(&cnt[(pairsv[e] >> 17) & 127], 1);
  __syncthreads();
  int lane = tid & 63;
  int incl = 0, pc = 0;
  if (tid < 128){
    pc = (cnt[tid] + 4) & ~3;        // deg + 1 self, padded to x4
    incl = pc;
    #pragma unroll
    for (int o = 1; o < 64; o <<= 1){ int u = __shfl_up(incl, o); if (lane >= o) incl += u; }
  }
  if (tid == 63) wtot = incl;
  __syncthreads();
  if (tid < 128){
    int excl = incl - pc + (tid >= 64 ? wtot : 0);
    int node = b * 128 + tid;
    lofs[node] = excl;
    dinv[node] = rsqrtf((float)(cnt[tid] + 1));
    if (tid == 127) btot[b] = excl + pc;
  }
}

// Phase D2: fill CSR (edges + self + pads) + indptr, all writes bucket-local.
__global__ __launch_bounds__(256) void bucket_fill(const int* __restrict__ pairsv,
                                                   const int* __restrict__ sc,
                                                   const int* __restrict__ lofs,
                                                   const int* __restrict__ bbase,
                                                   int* __restrict__ csr,
                                                   int* __restrict__ indptr){
  __shared__ int cur[128], l0[128];
  const int tid = threadIdx.x, b = blockIdx.x;
  const int base = bbase[b];
  if (tid < 128){
    int v = lofs[b * 128 + tid];
    cur[tid] = v; l0[tid] = v;
  }
  __syncthreads();
  int e0 = sc[b * NCHUNK];
  int e1 = (b == NBUCK - 1) ? NE : sc[(b + 1) * NCHUNK];
  for (int e = e0 + tid; e < e1; e += 256){
    int v = pairsv[e];
    int li = (v >> 17) & 127;
    int p = atomicAdd(&cur[li], 1);
    csr[base + p] = v & 0x1FFFF;
  }
  __syncthreads();
  if (tid < 128){
    int node = b * 128 + tid;
    int c = cur[tid];                 // l0 + deg
    int l = l0[tid];
    int end = l + ((c - l + 4) & ~3); // l + padded count
    csr[base + c] = node;             // self-loop
    for (int q = c + 1; q < end; q++) csr[base + q] = NN;   // pads -> zero row
    indptr[node] = base + l;
  }
}

// ---------------- fused: (optional normalize) + hs = dinv * (row @ W^T) ----------------
template<int NORM>
__global__ __launch_bounds__(256) void norm_lin(const float* __restrict__ pref,
                                                float* __restrict__ x,
                                                const float* __restrict__ srcb,
                                                const float* __restrict__ w,
                                                const float* __restrict__ dinv,
                                                float* __restrict__ hs){
  __shared__ float W[DD][DD + 1];
  for (int q = threadIdx.x; q < DD * DD; q += 256) W[q >> 6][q & 63] = w[q];
  __syncthreads();
  int node = blockIdx.x * 4 + (threadIdx.x >> 6);
  if (node >= NN) return;
  int lane = threadIdx.x & 63;
  float v;
  if (NORM){
    v = (node < NUSER) ? pref[(size_t)node * DD + lane] : x[(size_t)node * DD + lane];
    float ss = v * v;
    #pragma unroll
    for (int o = 1; o < 64; o <<= 1) ss += __shfl_xor(ss, o);
    v = v / fmaxf(sqrtf(ss), 1e-12f);
    x[(size_t)node * DD + lane] = v;
  } else {
    v = srcb[(size_t)node * DD + lane];
  }
  __shared__ float rowbuf[4][DD];
  int wv = threadIdx.x >> 6;
  rowbuf[wv][lane] = v;
  __syncthreads();
  float acc = 0.f;
  #pragma unroll
  for (int d = 0; d < DD; d++) acc = fmaf(rowbuf[wv][d], W[lane][d], acc);
  hs[(size_t)node * DD + lane] = dinv[node] * acc;
}

// ---------------- gather aggregation: 4 edges in flight, 16 lanes x float4 per row ----------------
template<int FINAL>
__global__ __launch_bounds__(256) void agg_kernel(const float* __restrict__ hs,
                                                  const float* __restrict__ dinv,
                                                  const int* __restrict__ indptr,
                                                  const int* __restrict__ csr,
                                                  const float* __restrict__ bias,
                                                  const float* __restrict__ x,
                                                  const float* __restrict__ h,
                                                  float* __restrict__ out,
                                                  const float* __restrict__ pref,
                                                  float* __restrict__ out2){
  int b = blockIdx.x;
  if (FINAL && b >= NN / 4){
    long q = (long)(b - NN / 4) * 256 + threadIdx.x;
    if (q < (long)NUSER * DD / 4)
      ((float4*)out2)[q] = ((const float4*)pref)[q];
    return;
  }
  int node = b * 4 + (threadIdx.x >> 6);
  int lane = threadIdx.x & 63;
  int g  = lane >> 4;
  int sl = lane & 15;
  int e0 = indptr[node];
  int nit = (indptr[node + 1] - e0) >> 2;
  float ax = 0.f, ay = 0.f, az = 0.f, aw = 0.f;
  int k = e0 + g;
  for (int i = 0; i < nit; i++){
    int j = csr[k];
    k += 4;
    float4 v = *(const float4*)&hs[(size_t)j * DD + sl * 4];
    ax += v.x; ay += v.y; az += v.z; aw += v.w;
  }
  #pragma unroll
  for (int off = 16; off < 64; off <<= 1){
    ax += __shfl_xor(ax, off);
    ay += __shfl_xor(ay, off);
    az += __shfl_xor(az, off);
    aw += __shfl_xor(aw, off);
  }
  if (g == 0){
    float di = dinv[node];
    const float4 bi = *(const float4*)&bias[sl * 4];
    float4 r;
    r.x = fmaf(di, ax, bi.x);
    r.y = fmaf(di, ay, bi.y);
    r.z = fmaf(di, az, bi.z);
    r.w = fmaf(di, aw, bi.w);
    if (FINAL){
      const float4 xv = *(const float4*)&x[(size_t)node * DD + sl * 4];
      const float4 hv = *(const float4*)&h[(size_t)node * DD + sl * 4];
      r.x += xv.x + hv.x; r.y += xv.y + hv.y;
      r.z += xv.z + hv.z; r.w += xv.w + hv.w;
    }
    *(float4*)&out[(size_t)node * DD + sl * 4] = r;
  }
}

extern "C" void kernel_launch(void* const* d_in, const int* in_sizes, int n_in,
                              void* d_out, int out_size, void* d_ws, size_t ws_size,
                              hipStream_t stream){
  const int*   ei    = (const int*)  d_in[0];
  const float* feats = (const float*)d_in[1];
  const float* pref  = (const float*)d_in[2];
  const float* w1    = (const float*)d_in[3];
  const float* b1    = (const float*)d_in[4];
  const float* w2    = (const float*)d_in[5];
  const float* b2    = (const float*)d_in[6];
  const float* cw    = (const float*)d_in[7];
  const float* cb    = (const float*)d_in[8];
  float* out = (float*)d_out;

  // ---- workspace layout (lifetime-overlapped) ----
  // W1 [0, 51.25MB) featsb (dead after GEMM1), overlaid by:
  //    x    [0, 20.48MB)
  //    hbuf [20.48, 40.96MB)  -- during CSR build hosts scratch: pairsv|hist|sc|bsum|boff|btot|bbase
  //    [40.96, 51.25MB) live graph: csr|indptr|dinv|lofs
  // W2 [51.25, 76.9MB) hiddenb (dead after GEMM2), overlaid by hs [(NN+1) rows]
  // [76.9MB, ...) w1b, w2b
  char* wsb = (char*)d_ws;
  short* featsb  = (short*)wsb;
  float* x       = (float*)wsb;
  float* hbuf    = (float*)(wsb + (size_t)NN * DD * 4);
  // build scratch (inside hbuf region, dead before agg writes hbuf)
  int*   pairsv  = (int*)hbuf;
  int*   hist    = pairsv + NE;
  int*   sc      = hist + NHIST;
  int*   bsum    = sc + NHIST;
  int*   boff    = bsum + NPART;
  int*   btot    = boff + NPART;
  int*   bbase   = btot + NBUCK;
  // live graph region
  char*  graphb  = wsb + (size_t)NN * DD * 8;
  int*   csr     = (int*)graphb;
  int*   indptr  = csr + CSRCAP;
  float* dinv    = (float*)(indptr + NN + 1);
  int*   lofs    = (int*)(dinv + NN);
  // W2
  char*  hidb_c  = wsb + (size_t)MPAD * FEAT * 2;
  short* hiddenb = (short*)hidb_c;
  float* hs      = (float*)hidb_c;
  short* w1b     = (short*)(wsb + (size_t)MPAD * FEAT * 2 + (size_t)(MPAD + 64) * HIDN * 2);
  short* w2b     = w1b + (size_t)HIDN * FEAT;

  // ---- bf16 conversions ----
  cvt_all<<<2048, 256, 0, stream>>>(w1, w2, feats, (unsigned short*)w1b,
                                    (unsigned short*)w2b, (unsigned short*)featsb);

  // ---- MLP ----
  gemm_mfma<128, 1, 1><<<dim3(HIDN / 128, MPAD / 128), 256, 0, stream>>>(
      featsb, w1b, b1, hiddenb, NITEM, FEAT, HIDN);
  gemm_mfma<64, 0, 0><<<dim3(1, MPAD / 128), 256, 0, stream>>>(
      hiddenb, w2b, b2, x + (size_t)NUSER * DD, NITEM, HIDN, DD);
  hipMemsetAsync(hs + (size_t)NN * DD, 0, DD * sizeof(float), stream);  // zero pad-row

  // ---- atomic-free CSR build (regions overlay featsb: after GEMM1) ----
  histo_kernel<<<NCHUNK, 256, 0, stream>>>(ei, hist);
  scan_part<<<NPART, 256, 0, stream>>>(hist, NHIST, bsum);
  scan_mid<<<1, 1024, 0, stream>>>(bsum, NPART, boff, nullptr);
  scan_apply<<<NPART, 1024, 0, stream>>>(hist, boff, sc, NHIST);
  binscat_kernel<<<NCHUNK, 256, 0, stream>>>(ei, sc, pairsv);
  bucket_count<<<NBUCK, 256, 0, stream>>>(pairsv, sc, lofs, dinv, btot);
  scan_mid<<<1, 1024, 0, stream>>>(btot, NBUCK, bbase, indptr + NN);
  bucket_fill<<<NBUCK, 256, 0, stream>>>(pairsv, sc, lofs, bbase, csr, indptr);

  // ---- x = normalize(concat(pref, temp)); hs = dinv * (x @ cw^T) ----
  norm_lin<1><<<NN / 4, 256, 0, stream>>>(pref, x, nullptr, cw, dinv, hs);
  // ---- conv1 ----
  agg_kernel<0><<<NN / 4, 256, 0, stream>>>(hs, dinv, indptr, csr, cb,
                                            nullptr, nullptr, hbuf, nullptr, nullptr);
  // ---- conv2 input ----
  norm_lin<0><<<NN / 4, 256, 0, stream>>>(nullptr, nullptr, hbuf, cw, dinv, hs);
  // ---- conv2 + residual + pref tail copy ----
  agg_kernel<1><<<NN / 4 + (NUSER * DD / 4 + 255) / 256, 256, 0, stream>>>(
      hs, dinv, indptr, csr, cb, x, hbuf, out, pref, out + (size_t)NN * DD);
}

// Round 5
// 294.436 us; speedup vs baseline: 2.7844x; 1.1003x over previous
//
#include <hip/hip_runtime.h>

#define NUSER 30000
#define NITEM 50000
#define NN    80000
#define NE    1200000
#define DD    64
#define FEAT  512
#define HIDN  256
#define MPAD  50048           // NITEM rounded up to 128
#define CSRCAP (NE + 8 * NN)  // padded CSR capacity (pad-to-8)

#define NBUCK  625            // dst >> 7 ; 625*128 == 80000 exactly
#define NCHUNK 256            // edge chunks for histogram/binscat
#define CHSZ   ((NE + NCHUNK - 1) / NCHUNK)   // 4688
#define NHIST  (NBUCK * NCHUNK)               // 160000
#define NPART  ((NHIST + 1023) / 1024)        // 157

using s16x8 = __attribute__((ext_vector_type(8))) short;
using f32x4 = __attribute__((ext_vector_type(4))) float;

__device__ __forceinline__ unsigned short f2bf(float f){
  unsigned int u = __float_as_uint(f);
  unsigned int r = (u + 0x7fffu + ((u >> 16) & 1u)) >> 16;
  return (unsigned short)r;
}

__device__ __forceinline__ float bf2f(unsigned short s){
  unsigned int u = ((unsigned int)s) << 16;
  return __uint_as_float(u);
}

__device__ __forceinline__ void gload_lds16(const void* g, void* l){
  __builtin_amdgcn_global_load_lds(
      (const __attribute__((address_space(1))) unsigned int*)g,
      (__attribute__((address_space(3))) unsigned int*)l, 16, 0, 0);
}

// ---------------- fp32 -> bf16 convert: w1 | w2 | feats(+pad) in one launch ----------------
#define QW1 ((long)HIDN * FEAT / 4)
#define QW2 ((long)DD * HIDN / 4)
#define QFI ((long)NITEM * FEAT / 4)
#define QFT ((long)MPAD * FEAT / 4)
__global__ __launch_bounds__(256) void cvt_all(const float* __restrict__ w1,
                                               const float* __restrict__ w2,
                                               const float* __restrict__ feats,
                                               unsigned short* __restrict__ w1b,
                                               unsigned short* __restrict__ w2b,
                                               unsigned short* __restrict__ featsb){
  const long ntot = QW1 + QW2 + QFT;
  for (long q = (long)blockIdx.x * blockDim.x + threadIdx.x; q < ntot;
       q += (long)gridDim.x * blockDim.x){
    const float4* src; ushort4* dst; long i;
    if (q < QW1){ src = (const float4*)w1; dst = (ushort4*)w1b; i = q; }
    else if (q < QW1 + QW2){ src = (const float4*)w2; dst = (ushort4*)w2b; i = q - QW1; }
    else { src = (const float4*)feats; dst = (ushort4*)featsb; i = q - QW1 - QW2; }
    float4 v = make_float4(0.f, 0.f, 0.f, 0.f);
    if (dst != (ushort4*)featsb || i < QFI) v = src[i];
    ushort4 o;
    o.x = f2bf(v.x); o.y = f2bf(v.y); o.z = f2bf(v.z); o.w = f2bf(v.w);
    dst[i] = o;
  }
}

// ---------------- MFMA GEMM: C[M,N] = A[Mpad,K]_bf16 @ B[N,K]_bf16^T + bias ----------------
template<int BN, int ACT, int OUT_BF16>
__global__ __launch_bounds__(256) void gemm_mfma(const short* __restrict__ Ag,
                                                 const short* __restrict__ Bg,
                                                 const float* __restrict__ bias,
                                                 void* __restrict__ Cout,
                                                 int M, int K, int ldc){
  constexpr int BM = 128;
  constexpr int BK = 32;
  constexpr int NFRAG = BN / 32;
  __shared__ __align__(16) short As[BM * BK];
  __shared__ __align__(16) short Bs[BN * BK];

  const int tid  = threadIdx.x;
  const int wid  = tid >> 6;
  const int lane = tid & 63;
  const int wr   = wid >> 1;
  const int wc   = wid & 1;
  const int m0   = blockIdx.y * BM;
  const int n0   = blockIdx.x * BN;

  f32x4 acc[4][NFRAG] = {};

  for (int k0 = 0; k0 < K; k0 += BK){
    #pragma unroll
    for (int s = 0; s < 2; s++){
      int q = s * 256 + tid;
      int row = q >> 2, kc = q & 3;
      const short* src = Ag + (size_t)(m0 + row) * K + k0 + kc * 8;
      gload_lds16(src, &As[(size_t)(s * 256 + wid * 64) * 8]);
    }
    #pragma unroll
    for (int s = 0; s < BN / 64; s++){
      int q = s * 256 + tid;
      int row = q >> 2, kc = q & 3;
      const short* src = Bg + (size_t)(n0 + row) * K + k0 + kc * 8;
      gload_lds16(src, &Bs[(size_t)(s * 256 + wid * 64) * 8]);
    }
    __syncthreads();

    s16x8 af[4], bf[NFRAG];
    #pragma unroll
    for (int m = 0; m < 4; m++)
      af[m] = *(const s16x8*)&As[(wr * 64 + m * 16 + (lane & 15)) * BK + (lane >> 4) * 8];
    #pragma unroll
    for (int n = 0; n < NFRAG; n++)
      bf[n] = *(const s16x8*)&Bs[(wc * (BN / 2) + n * 16 + (lane & 15)) * BK + (lane >> 4) * 8];
    #pragma unroll
    for (int m = 0; m < 4; m++)
      #pragma unroll
      for (int n = 0; n < NFRAG; n++)
        acc[m][n] = __builtin_amdgcn_mfma_f32_16x16x32_bf16(af[m], bf[n], acc[m][n], 0, 0, 0);
    __syncthreads();
  }

  #pragma unroll
  for (int m = 0; m < 4; m++){
    int row_base = m0 + wr * 64 + m * 16 + (lane >> 4) * 4;
    #pragma unroll
    for (int n = 0; n < NFRAG; n++){
      int col = n0 + wc * (BN / 2) + n * 16 + (lane & 15);
      float bi = bias[col];
      #pragma unroll
      for (int r = 0; r < 4; r++){
        int row = row_base + r;
        if (row >= M) continue;
        float v = acc[m][n][r] + bi;
        if (ACT) v = v > 0.f ? v : 0.01f * v;
        if (OUT_BF16) ((unsigned short*)Cout)[(size_t)row * ldc + col] = f2bf(v);
        else          ((float*)Cout)[(size_t)row * ldc + col] = v;
      }
    }
  }
}

// ================= atomic-free CSR build =================
__global__ __launch_bounds__(256) void histo_kernel(const int* __restrict__ ei,
                                                    int* __restrict__ hist){
  __shared__ int h[NBUCK];
  const int tid = threadIdx.x, c = blockIdx.x;
  for (int i = tid; i < NBUCK; i += 256) h[i] = 0;
  __syncthreads();
  int e0 = c * CHSZ, e1 = min(e0 + CHSZ, NE);
  for (int e = e0 + tid; e < e1; e += 256)
    atomicAdd(&h[ei[NE + e] >> 7], 1);
  __syncthreads();
  for (int i = tid; i < NBUCK; i += 256) hist[i * NCHUNK + c] = h[i];
}

__global__ __launch_bounds__(256) void scan_part(const int* __restrict__ a, int n,
                                                 int* __restrict__ bsum){
  __shared__ int ws4[4];
  int b = blockIdx.x, base = b * 1024;
  int v = 0;
  #pragma unroll
  for (int s = 0; s < 4; s++){
    int idx = base + s * 256 + threadIdx.x;
    if (idx < n) v += a[idx];
  }
  int lane = threadIdx.x & 63, w = threadIdx.x >> 6;
  #pragma unroll
  for (int o = 1; o < 64; o <<= 1) v += __shfl_xor(v, o);
  if (lane == 0) ws4[w] = v;
  __syncthreads();
  if (threadIdx.x == 0) bsum[b] = ws4[0] + ws4[1] + ws4[2] + ws4[3];
}

__global__ __launch_bounds__(1024) void scan_mid(const int* __restrict__ a, int np,
                                                 int* __restrict__ excl_out,
                                                 int* __restrict__ total_out){
  __shared__ int wsum[16];
  int tid = threadIdx.x;
  int v = (tid < np) ? a[tid] : 0;
  int lane = tid & 63, w = tid >> 6;
  int incl = v;
  #pragma unroll
  for (int o = 1; o < 64; o <<= 1){ int u = __shfl_up(incl, o); if (lane >= o) incl += u; }
  if (lane == 63) wsum[w] = incl;
  __syncthreads();
  int woff = 0;
  #pragma unroll
  for (int k = 0; k < 16; k++) if (k < w) woff += wsum[k];
  if (tid < np) excl_out[tid] = woff + incl - v;
  if (total_out && tid == 1023) *total_out = woff + incl;
}

__global__ __launch_bounds__(1024) void scan_apply(const int* __restrict__ a,
                                                   const int* __restrict__ boff,
                                                   int* __restrict__ sc, int n){
  __shared__ int wsum[16];
  int b = blockIdx.x, tid = threadIdx.x;
  int idx = b * 1024 + tid;
  int v = (idx < n) ? a[idx] : 0;
  int lane = tid & 63, w = tid >> 6;
  int incl = v;
  #pragma unroll
  for (int o = 1; o < 64; o <<= 1){ int u = __shfl_up(incl, o); if (lane >= o) incl += u; }
  if (lane == 63) wsum[w] = incl;
  __syncthreads();
  int woff = 0;
  #pragma unroll
  for (int k = 0; k < 16; k++) if (k < w) woff += wsum[k];
  if (idx < n) sc[idx] = boff[b] + woff + incl - v;
}

__global__ __launch_bounds__(256) void binscat_kernel(const int* __restrict__ ei,
                                                      const int* __restrict__ sc,
                                                      int* __restrict__ pairsv){
  __shared__ int cur[NBUCK];
  const int tid = threadIdx.x, c = blockIdx.x;
  for (int i = tid; i < NBUCK; i += 256) cur[i] = sc[i * NCHUNK + c];
  __syncthreads();
  int e0 = c * CHSZ, e1 = min(e0 + CHSZ, NE);
  for (int e = e0 + tid; e < e1; e += 256){
    int s = ei[e];
    int d = ei[NE + e];
    int pos = atomicAdd(&cur[d >> 7], 1);
    pairsv[pos] = ((d & 127) << 17) | s;
  }
}

// Phase D1: per-bucket per-node degree count + LDS scan of padded counts (pad-to-8).
__global__ __launch_bounds__(256) void bucket_count(const int* __restrict__ pairsv,
                                                    const int* __restrict__ sc,
                                                    int* __restrict__ lofs,
                                                    float* __restrict__ dinv,
                                                    int* __restrict__ btot){
  __shared__ int cnt[128];
  __shared__ int wtot;
  const int tid = threadIdx.x, b = blockIdx.x;
  if (tid < 128) cnt[tid] = 0;
  __syncthreads();
  int e0 = sc[b * NCHUNK];
  int e1 = (b == NBUCK - 1) ? NE : sc[(b + 1) * NCHUNK];
  for (int e = e0 + tid; e < e1; e += 256)
    atomicAdd(&cnt[(pairsv[e] >> 17) & 127], 1);
  __syncthreads();
  int lane = tid & 63;
  int incl = 0, pc = 0;
  if (tid < 128){
    pc = (cnt[tid] + 8) & ~7;        // deg + 1 self, padded to x8
    incl = pc;
    #pragma unroll
    for (int o = 1; o < 64; o <<= 1){ int u = __shfl_up(incl, o); if (lane >= o) incl += u; }
  }
  if (tid == 63) wtot = incl;
  __syncthreads();
  if (tid < 128){
    int excl = incl - pc + (tid >= 64 ? wtot : 0);
    int node = b * 128 + tid;
    lofs[node] = excl;
    dinv[node] = rsqrtf((float)(cnt[tid] + 1));
    if (tid == 127) btot[b] = excl + pc;
  }
}

// Phase D2: fill CSR (edges + self + pads) + indptr, all writes bucket-local.
__global__ __launch_bounds__(256) void bucket_fill(const int* __restrict__ pairsv,
                                                   const int* __restrict__ sc,
                                                   const int* __restrict__ lofs,
                                                   const int* __restrict__ bbase,
                                                   int* __restrict__ csr,
                                                   int* __restrict__ indptr){
  __shared__ int cur[128], l0[128];
  const int tid = threadIdx.x, b = blockIdx.x;
  const int base = bbase[b];
  if (tid < 128){
    int v = lofs[b * 128 + tid];
    cur[tid] = v; l0[tid] = v;
  }
  __syncthreads();
  int e0 = sc[b * NCHUNK];
  int e1 = (b == NBUCK - 1) ? NE : sc[(b + 1) * NCHUNK];
  for (int e = e0 + tid; e < e1; e += 256){
    int v = pairsv[e];
    int li = (v >> 17) & 127;
    int p = atomicAdd(&cur[li], 1);
    csr[base + p] = v & 0x1FFFF;
  }
  __syncthreads();
  if (tid < 128){
    int node = b * 128 + tid;
    int c = cur[tid];                 // l0 + deg
    int l = l0[tid];
    int end = l + ((c - l + 8) & ~7); // l + padded count (pad-to-8)
    csr[base + c] = node;             // self-loop
    for (int q = c + 1; q < end; q++) csr[base + q] = NN;   // pads -> zero row
    indptr[node] = base + l;
  }
}

// ---------------- fused: (optional normalize) + hsb = bf16(dinv * (row @ W^T)) ----------------
template<int NORM>
__global__ __launch_bounds__(256) void norm_lin(const float* __restrict__ pref,
                                                float* __restrict__ x,
                                                const float* __restrict__ srcb,
                                                const float* __restrict__ w,
                                                const float* __restrict__ dinv,
                                                unsigned short* __restrict__ hsb){
  __shared__ float W[DD][DD + 1];
  for (int q = threadIdx.x; q < DD * DD; q += 256) W[q >> 6][q & 63] = w[q];
  __syncthreads();
  int node = blockIdx.x * 4 + (threadIdx.x >> 6);
  if (node >= NN) return;
  int lane = threadIdx.x & 63;
  float v;
  if (NORM){
    v = (node < NUSER) ? pref[(size_t)node * DD + lane] : x[(size_t)node * DD + lane];
    float ss = v * v;
    #pragma unroll
    for (int o = 1; o < 64; o <<= 1) ss += __shfl_xor(ss, o);
    v = v / fmaxf(sqrtf(ss), 1e-12f);
    x[(size_t)node * DD + lane] = v;
  } else {
    v = srcb[(size_t)node * DD + lane];
  }
  __shared__ float rowbuf[4][DD];
  int wv = threadIdx.x >> 6;
  rowbuf[wv][lane] = v;
  __syncthreads();
  float acc = 0.f;
  #pragma unroll
  for (int d = 0; d < DD; d++) acc = fmaf(rowbuf[wv][d], W[lane][d], acc);
  hsb[(size_t)node * DD + lane] = f2bf(dinv[node] * acc);
}

// ---------------- gather aggregation: 8 edges in flight, 8 lanes x s16x8 (bf16 rows) ----------------
// out = dinv[node] * sum(hsb[j]) + bias   (+ x + h residual when FINAL)
template<int FINAL>
__global__ __launch_bounds__(256) void agg_kernel(const unsigned short* __restrict__ hsb,
                                                  const float* __restrict__ dinv,
                                                  const int* __restrict__ indptr,
                                                  const int* __restrict__ csr,
                                                  const float* __restrict__ bias,
                                                  const float* __restrict__ x,
                                                  const float* __restrict__ h,
                                                  float* __restrict__ out,
                                                  const float* __restrict__ pref,
                                                  float* __restrict__ out2){
  int b = blockIdx.x;
  if (FINAL && b >= NN / 4){
    long q = (long)(b - NN / 4) * 256 + threadIdx.x;
    if (q < (long)NUSER * DD / 4)
      ((float4*)out2)[q] = ((const float4*)pref)[q];
    return;
  }
  int node = b * 4 + (threadIdx.x >> 6);
  int lane = threadIdx.x & 63;
  int g  = lane >> 3;          // edge group 0..7
  int sl = lane & 7;           // 8 lanes x 8 bf16 (16B) = one 64-elem row
  int e0 = indptr[node];
  int nit = (indptr[node + 1] - e0) >> 3;
  float a0=0.f,a1=0.f,a2=0.f,a3=0.f,a4=0.f,a5=0.f,a6=0.f,a7=0.f;
  int k = e0 + g;
  for (int i = 0; i < nit; i++){
    int j = csr[k];
    k += 8;
    s16x8 v = *(const s16x8*)&hsb[(size_t)j * DD + sl * 8];
    a0 += bf2f((unsigned short)v[0]);
    a1 += bf2f((unsigned short)v[1]);
    a2 += bf2f((unsigned short)v[2]);
    a3 += bf2f((unsigned short)v[3]);
    a4 += bf2f((unsigned short)v[4]);
    a5 += bf2f((unsigned short)v[5]);
    a6 += bf2f((unsigned short)v[6]);
    a7 += bf2f((unsigned short)v[7]);
  }
  // combine the 8 edge groups (lanes differing in bits 3..5)
  #pragma unroll
  for (int off = 8; off < 64; off <<= 1){
    a0 += __shfl_xor(a0, off);
    a1 += __shfl_xor(a1, off);
    a2 += __shfl_xor(a2, off);
    a3 += __shfl_xor(a3, off);
    a4 += __shfl_xor(a4, off);
    a5 += __shfl_xor(a5, off);
    a6 += __shfl_xor(a6, off);
    a7 += __shfl_xor(a7, off);
  }
  if (g == 0){
    float di = dinv[node];
    size_t rb = (size_t)node * DD + sl * 8;
    const float4 bi0 = *(const float4*)&bias[sl * 8];
    const float4 bi1 = *(const float4*)&bias[sl * 8 + 4];
    float4 r0, r1;
    r0.x = fmaf(di, a0, bi0.x); r0.y = fmaf(di, a1, bi0.y);
    r0.z = fmaf(di, a2, bi0.z); r0.w = fmaf(di, a3, bi0.w);
    r1.x = fmaf(di, a4, bi1.x); r1.y = fmaf(di, a5, bi1.y);
    r1.z = fmaf(di, a6, bi1.z); r1.w = fmaf(di, a7, bi1.w);
    if (FINAL){
      const float4 xv0 = *(const float4*)&x[rb];
      const float4 xv1 = *(const float4*)&x[rb + 4];
      const float4 hv0 = *(const float4*)&h[rb];
      const float4 hv1 = *(const float4*)&h[rb + 4];
      r0.x += xv0.x + hv0.x; r0.y += xv0.y + hv0.y;
      r0.z += xv0.z + hv0.z; r0.w += xv0.w + hv0.w;
      r1.x += xv1.x + hv1.x; r1.y += xv1.y + hv1.y;
      r1.z += xv1.z + hv1.z; r1.w += xv1.w + hv1.w;
    }
    *(float4*)&out[rb] = r0;
    *(float4*)&out[rb + 4] = r1;
  }
}

extern "C" void kernel_launch(void* const* d_in, const int* in_sizes, int n_in,
                              void* d_out, int out_size, void* d_ws, size_t ws_size,
                              hipStream_t stream){
  const int*   ei    = (const int*)  d_in[0];
  const float* feats = (const float*)d_in[1];
  const float* pref  = (const float*)d_in[2];
  const float* w1    = (const float*)d_in[3];
  const float* b1    = (const float*)d_in[4];
  const float* w2    = (const float*)d_in[5];
  const float* b2    = (const float*)d_in[6];
  const float* cw    = (const float*)d_in[7];
  const float* cb    = (const float*)d_in[8];
  float* out = (float*)d_out;

  // ---- workspace layout (lifetime-overlapped) ----
  // W1 [0, 51.25MB) featsb (dead after GEMM1), overlaid by:
  //    x    [0, 20.48MB)
  //    hbuf [20.48, 40.96MB)  -- during CSR build hosts scratch: pairsv|hist|sc|bsum|boff|btot|bbase
  //    [40.96, 51.25MB) live graph: csr (CSRCAP=1.84M) | indptr | dinv | lofs  (~8.3MB, fits)
  // W2 [51.25, 76.9MB) hiddenb (dead after GEMM2), overlaid by hsb bf16 [(NN+1) rows, 10.24MB]
  // [76.9MB, ...) w1b, w2b
  char* wsb = (char*)d_ws;
  short* featsb  = (short*)wsb;
  float* x       = (float*)wsb;
  float* hbuf    = (float*)(wsb + (size_t)NN * DD * 4);
  int*   pairsv  = (int*)hbuf;
  int*   hist    = pairsv + NE;
  int*   sc      = hist + NHIST;
  int*   bsum    = sc + NHIST;
  int*   boff    = bsum + NPART;
  int*   btot    = boff + NPART;
  int*   bbase   = btot + NBUCK;
  char*  graphb  = wsb + (size_t)NN * DD * 8;
  int*   csr     = (int*)graphb;
  int*   indptr  = csr + CSRCAP;
  float* dinv    = (float*)(indptr + NN + 1);
  int*   lofs    = (int*)(dinv + NN);
  char*  hidb_c  = wsb + (size_t)MPAD * FEAT * 2;
  short* hiddenb = (short*)hidb_c;
  unsigned short* hsb = (unsigned short*)hidb_c;
  short* w1b     = (short*)(wsb + (size_t)MPAD * FEAT * 2 + (size_t)(MPAD + 64) * HIDN * 2);
  short* w2b     = w1b + (size_t)HIDN * FEAT;

  // ---- bf16 conversions ----
  cvt_all<<<2048, 256, 0, stream>>>(w1, w2, feats, (unsigned short*)w1b,
                                    (unsigned short*)w2b, (unsigned short*)featsb);

  // ---- MLP ----
  gemm_mfma<128, 1, 1><<<dim3(HIDN / 128, MPAD / 128), 256, 0, stream>>>(
      featsb, w1b, b1, hiddenb, NITEM, FEAT, HIDN);
  gemm_mfma<64, 0, 0><<<dim3(1, MPAD / 128), 256, 0, stream>>>(
      hiddenb, w2b, b2, x + (size_t)NUSER * DD, NITEM, HIDN, DD);
  hipMemsetAsync(hsb + (size_t)NN * DD, 0, DD * sizeof(unsigned short), stream); // zero pad-row

  // ---- atomic-free CSR build (regions overlay featsb: after GEMM1) ----
  histo_kernel<<<NCHUNK, 256, 0, stream>>>(ei, hist);
  scan_part<<<NPART, 256, 0, stream>>>(hist, NHIST, bsum);
  scan_mid<<<1, 1024, 0, stream>>>(bsum, NPART, boff, nullptr);
  scan_apply<<<NPART, 1024, 0, stream>>>(hist, boff, sc, NHIST);
  binscat_kernel<<<NCHUNK, 256, 0, stream>>>(ei, sc, pairsv);
  bucket_count<<<NBUCK, 256, 0, stream>>>(pairsv, sc, lofs, dinv, btot);
  scan_mid<<<1, 1024, 0, stream>>>(btot, NBUCK, bbase, indptr + NN);
  bucket_fill<<<NBUCK, 256, 0, stream>>>(pairsv, sc, lofs, bbase, csr, indptr);

  // ---- x = normalize(concat(pref, temp)); hsb = bf16(dinv * (x @ cw^T)) ----
  norm_lin<1><<<NN / 4, 256, 0, stream>>>(pref, x, nullptr, cw, dinv, hsb);
  // ---- conv1: hbuf = dinv * sum(hsb[j]) + cb ----
  agg_kernel<0><<<NN / 4, 256, 0, stream>>>(hsb, dinv, indptr, csr, cb,
                                            nullptr, nullptr, hbuf, nullptr, nullptr);
  // ---- conv2 input: hsb = bf16(dinv * (hbuf @ cw^T)) ----
  norm_lin<0><<<NN / 4, 256, 0, stream>>>(nullptr, nullptr, hbuf, cw, dinv, hsb);
  // ---- conv2 + residual + pref tail copy ----
  agg_kernel<1><<<NN / 4 + (NUSER * DD / 4 + 255) / 256, 256, 0, stream>>>(
      hsb, dinv, indptr, csr, cb, x, hbuf, out, pref, out + (size_t)NN * DD);
}

// Round 6
// 282.762 us; speedup vs baseline: 2.8993x; 1.0413x over previous
//
#include <hip/hip_runtime.h>

#define NUSER 30000
#define NITEM 50000
#define NN    80000
#define NE    1200000
#define DD    64
#define FEAT  512
#define HIDN  256
#define MPAD  50048           // NITEM rounded up to 128 (grid sizing)
#define CSRCAP (NE + 8 * NN)  // padded CSR capacity (pad-to-8)

#define NBUCK  625            // dst >> 7 ; 625*128 == 80000 exactly
#define NCHUNK 256            // edge chunks for histogram/binscat
#define CHSZ   ((NE + NCHUNK - 1) / NCHUNK)   // 4688
#define NHIST  (NBUCK * NCHUNK)               // 160000
#define NPART  ((NHIST + 1023) / 1024)        // 157

using s16x8 = __attribute__((ext_vector_type(8))) short;
using f32x4 = __attribute__((ext_vector_type(4))) float;

__device__ __forceinline__ unsigned short f2bf(float f){
  unsigned int u = __float_as_uint(f);
  unsigned int r = (u + 0x7fffu + ((u >> 16) & 1u)) >> 16;
  return (unsigned short)r;
}

__device__ __forceinline__ float bf2f(unsigned short s){
  unsigned int u = ((unsigned int)s) << 16;
  return __uint_as_float(u);
}

__device__ __forceinline__ void gload_lds16(const void* g, void* l){
  __builtin_amdgcn_global_load_lds(
      (const __attribute__((address_space(1))) unsigned int*)g,
      (__attribute__((address_space(3))) unsigned int*)l, 16, 0, 0);
}

// ---------------- weights fp32 -> bf16 (tiny) ----------------
__global__ __launch_bounds__(256) void cvt_w(const float* __restrict__ w1,
                                             const float* __restrict__ w2,
                                             unsigned short* __restrict__ w1b,
                                             unsigned short* __restrict__ w2b){
  const int n1 = HIDN * FEAT / 4;   // 32768 float4s
  const int n2 = DD * HIDN / 4;     // 4096
  int q = blockIdx.x * 256 + threadIdx.x;
  if (q < n1){
    float4 v = ((const float4*)w1)[q];
    ushort4 o = { f2bf(v.x), f2bf(v.y), f2bf(v.z), f2bf(v.w) };
    ((ushort4*)w1b)[q] = o;
  } else if (q < n1 + n2){
    int i = q - n1;
    float4 v = ((const float4*)w2)[i];
    ushort4 o = { f2bf(v.x), f2bf(v.y), f2bf(v.z), f2bf(v.w) };
    ((ushort4*)w2b)[i] = o;
  }
}

// ---------------- fused MLP: x[NUSER..] = (leaky(feats@w1^T+b1))@w2^T + b2 ----------------
// BM=64 rows/block, 4 waves (2x2). Phase 1: K=512 MFMA into acc[2][8] (256 hidden cols).
// Hidden tile kept in LDS (bf16, padded stride). Phase 2: K=256 MFMA vs w2 (global frags).
__global__ __launch_bounds__(256) void mlp_fused(const float* __restrict__ feats,
                                                 const short* __restrict__ w1b,
                                                 const short* __restrict__ w2b,
                                                 const float* __restrict__ b1,
                                                 const float* __restrict__ b2,
                                                 float* __restrict__ x){
  constexpr int BM = 64;
  constexpr int BK = 32;
  constexpr int HP = HIDN + 8;          // Hs stride 264 elems (bank spread)
  __shared__ __align__(16) short As[BM * BK];      // 4KB
  __shared__ __align__(16) short Bs[HIDN * BK];    // 16KB
  __shared__ __align__(16) short Hs[BM * HP];      // 33KB

  const int tid  = threadIdx.x;
  const int wid  = tid >> 6;
  const int lane = tid & 63;
  const int wr   = wid >> 1;            // wave row: 32 rows each
  const int wc   = wid & 1;             // wave col: 128 hidden cols each
  const int m0   = blockIdx.x * BM;

  f32x4 acc[2][8] = {};

  for (int k0 = 0; k0 < FEAT; k0 += BK){
    // A: 64x32 f32 -> bf16 LDS (reg-stage + convert); 512 float4 chunks, 2/thread
    #pragma unroll
    for (int s = 0; s < 2; s++){
      int c = s * 256 + tid;
      int row = c >> 3, kc = c & 7;     // 8 float4 per 32-f32 row
      int gr = m0 + row;
      float4 v = make_float4(0.f, 0.f, 0.f, 0.f);
      if (gr < NITEM) v = *(const float4*)&feats[(size_t)gr * FEAT + k0 + kc * 4];
      ushort4 o = { f2bf(v.x), f2bf(v.y), f2bf(v.z), f2bf(v.w) };
      *(ushort4*)&As[row * BK + kc * 4] = o;
    }
    // B: w1 tile 256x32 bf16 via global_load_lds, 4 issues
    #pragma unroll
    for (int s = 0; s < 4; s++){
      int q = s * 256 + tid;
      int row = q >> 2, kc = q & 3;
      const short* src = w1b + (size_t)row * FEAT + k0 + kc * 8;
      gload_lds16(src, &Bs[(size_t)(s * 256 + wid * 64) * 8]);
    }
    __syncthreads();

    s16x8 af[2], bf[8];
    #pragma unroll
    for (int m = 0; m < 2; m++)
      af[m] = *(const s16x8*)&As[(wr * 32 + m * 16 + (lane & 15)) * BK + (lane >> 4) * 8];
    #pragma unroll
    for (int n = 0; n < 8; n++)
      bf[n] = *(const s16x8*)&Bs[(wc * 128 + n * 16 + (lane & 15)) * BK + (lane >> 4) * 8];
    #pragma unroll
    for (int m = 0; m < 2; m++)
      #pragma unroll
      for (int n = 0; n < 8; n++)
        acc[m][n] = __builtin_amdgcn_mfma_f32_16x16x32_bf16(af[m], bf[n], acc[m][n], 0, 0, 0);
    __syncthreads();
  }

  // epilogue 1: bias + leaky -> Hs bf16 (C/D layout col=lane&15, row=(lane>>4)*4+r)
  #pragma unroll
  for (int m = 0; m < 2; m++){
    #pragma unroll
    for (int n = 0; n < 8; n++){
      int col = wc * 128 + n * 16 + (lane & 15);
      float bi = b1[col];
      #pragma unroll
      for (int r = 0; r < 4; r++){
        int row_l = wr * 32 + m * 16 + (lane >> 4) * 4 + r;
        float v = acc[m][n][r] + bi;
        v = v > 0.f ? v : 0.01f * v;
        Hs[row_l * HP + col] = (short)f2bf(v);
      }
    }
  }
  __syncthreads();

  // phase 2: temp = Hs(64x256) @ w2^T(64x256) ; w2 frags straight from global (L2-hot)
  f32x4 acc2[2][2] = {};
  for (int kk = 0; kk < HIDN; kk += BK){
    s16x8 a2[2], bq[2];
    #pragma unroll
    for (int m = 0; m < 2; m++)
      a2[m] = *(const s16x8*)&Hs[(wr * 32 + m * 16 + (lane & 15)) * HP + kk + (lane >> 4) * 8];
    #pragma unroll
    for (int n = 0; n < 2; n++)
      bq[n] = *(const s16x8*)&w2b[(size_t)(wc * 32 + n * 16 + (lane & 15)) * HIDN + kk + (lane >> 4) * 8];
    #pragma unroll
    for (int m = 0; m < 2; m++)
      #pragma unroll
      for (int n = 0; n < 2; n++)
        acc2[m][n] = __builtin_amdgcn_mfma_f32_16x16x32_bf16(a2[m], bq[n], acc2[m][n], 0, 0, 0);
  }

  // epilogue 2: + b2 -> x item rows (f32)
  #pragma unroll
  for (int m = 0; m < 2; m++){
    #pragma unroll
    for (int n = 0; n < 2; n++){
      int col = wc * 32 + n * 16 + (lane & 15);
      float bi = b2[col];
      #pragma unroll
      for (int r = 0; r < 4; r++){
        int row_l = wr * 32 + m * 16 + (lane >> 4) * 4 + r;
        int gr = m0 + row_l;
        if (gr < NITEM)
          x[(size_t)(NUSER + gr) * DD + col] = acc2[m][n][r] + bi;
      }
    }
  }
}

// ================= atomic-free CSR build =================
__global__ __launch_bounds__(256) void histo_kernel(const int* __restrict__ ei,
                                                    int* __restrict__ hist){
  __shared__ int h[NBUCK];
  const int tid = threadIdx.x, c = blockIdx.x;
  for (int i = tid; i < NBUCK; i += 256) h[i] = 0;
  __syncthreads();
  int e0 = c * CHSZ, e1 = min(e0 + CHSZ, NE);
  for (int e = e0 + tid; e < e1; e += 256)
    atomicAdd(&h[ei[NE + e] >> 7], 1);
  __syncthreads();
  for (int i = tid; i < NBUCK; i += 256) hist[i * NCHUNK + c] = h[i];
}

__global__ __launch_bounds__(256) void scan_part(const int* __restrict__ a, int n,
                                                 int* __restrict__ bsum){
  __shared__ int ws4[4];
  int b = blockIdx.x, base = b * 1024;
  int v = 0;
  #pragma unroll
  for (int s = 0; s < 4; s++){
    int idx = base + s * 256 + threadIdx.x;
    if (idx < n) v += a[idx];
  }
  int lane = threadIdx.x & 63, w = threadIdx.x >> 6;
  #pragma unroll
  for (int o = 1; o < 64; o <<= 1) v += __shfl_xor(v, o);
  if (lane == 0) ws4[w] = v;
  __syncthreads();
  if (threadIdx.x == 0) bsum[b] = ws4[0] + ws4[1] + ws4[2] + ws4[3];
}

__global__ __launch_bounds__(1024) void scan_mid(const int* __restrict__ a, int np,
                                                 int* __restrict__ excl_out,
                                                 int* __restrict__ total_out){
  __shared__ int wsum[16];
  int tid = threadIdx.x;
  int v = (tid < np) ? a[tid] : 0;
  int lane = tid & 63, w = tid >> 6;
  int incl = v;
  #pragma unroll
  for (int o = 1; o < 64; o <<= 1){ int u = __shfl_up(incl, o); if (lane >= o) incl += u; }
  if (lane == 63) wsum[w] = incl;
  __syncthreads();
  int woff = 0;
  #pragma unroll
  for (int k = 0; k < 16; k++) if (k < w) woff += wsum[k];
  if (tid < np) excl_out[tid] = woff + incl - v;
  if (total_out && tid == 1023) *total_out = woff + incl;
}

__global__ __launch_bounds__(1024) void scan_apply(const int* __restrict__ a,
                                                   const int* __restrict__ boff,
                                                   int* __restrict__ sc, int n){
  __shared__ int wsum[16];
  int b = blockIdx.x, tid = threadIdx.x;
  int idx = b * 1024 + tid;
  int v = (idx < n) ? a[idx] : 0;
  int lane = tid & 63, w = tid >> 6;
  int incl = v;
  #pragma unroll
  for (int o = 1; o < 64; o <<= 1){ int u = __shfl_up(incl, o); if (lane >= o) incl += u; }
  if (lane == 63) wsum[w] = incl;
  __syncthreads();
  int woff = 0;
  #pragma unroll
  for (int k = 0; k < 16; k++) if (k < w) woff += wsum[k];
  if (idx < n) sc[idx] = boff[b] + woff + incl - v;
}

__global__ __launch_bounds__(256) void binscat_kernel(const int* __restrict__ ei,
                                                      const int* __restrict__ sc,
                                                      int* __restrict__ pairsv){
  __shared__ int cur[NBUCK];
  const int tid = threadIdx.x, c = blockIdx.x;
  for (int i = tid; i < NBUCK; i += 256) cur[i] = sc[i * NCHUNK + c];
  __syncthreads();
  int e0 = c * CHSZ, e1 = min(e0 + CHSZ, NE);
  for (int e = e0 + tid; e < e1; e += 256){
    int s = ei[e];
    int d = ei[NE + e];
    int pos = atomicAdd(&cur[d >> 7], 1);
    pairsv[pos] = ((d & 127) << 17) | s;
  }
}

__global__ __launch_bounds__(256) void bucket_count(const int* __restrict__ pairsv,
                                                    const int* __restrict__ sc,
                                                    int* __restrict__ lofs,
                                                    float* __restrict__ dinv,
                                                    int* __restrict__ btot){
  __shared__ int cnt[128];
  __shared__ int wtot;
  const int tid = threadIdx.x, b = blockIdx.x;
  if (tid < 128) cnt[tid] = 0;
  __syncthreads();
  int e0 = sc[b * NCHUNK];
  int e1 = (b == NBUCK - 1) ? NE : sc[(b + 1) * NCHUNK];
  for (int e = e0 + tid; e < e1; e += 256)
    atomicAdd(&cnt[(pairsv[e] >> 17) & 127], 1);
  __syncthreads();
  int lane = tid & 63;
  int incl = 0, pc = 0;
  if (tid < 128){
    pc = (cnt[tid] + 8) & ~7;        // deg + 1 self, padded to x8
    incl = pc;
    #pragma unroll
    for (int o = 1; o < 64; o <<= 1){ int u = __shfl_up(incl, o); if (lane >= o) incl += u; }
  }
  if (tid == 63) wtot = incl;
  __syncthreads();
  if (tid < 128){
    int excl = incl - pc + (tid >= 64 ? wtot : 0);
    int node = b * 128 + tid;
    lofs[node] = excl;
    dinv[node] = rsqrtf((float)(cnt[tid] + 1));
    if (tid == 127) btot[b] = excl + pc;
  }
}

__global__ __launch_bounds__(256) void bucket_fill(const int* __restrict__ pairsv,
                                                   const int* __restrict__ sc,
                                                   const int* __restrict__ lofs,
                                                   const int* __restrict__ bbase,
                                                   int* __restrict__ csr,
                                                   int* __restrict__ indptr){
  __shared__ int cur[128], l0[128];
  const int tid = threadIdx.x, b = blockIdx.x;
  const int base = bbase[b];
  if (tid < 128){
    int v = lofs[b * 128 + tid];
    cur[tid] = v; l0[tid] = v;
  }
  __syncthreads();
  int e0 = sc[b * NCHUNK];
  int e1 = (b == NBUCK - 1) ? NE : sc[(b + 1) * NCHUNK];
  for (int e = e0 + tid; e < e1; e += 256){
    int v = pairsv[e];
    int li = (v >> 17) & 127;
    int p = atomicAdd(&cur[li], 1);
    csr[base + p] = v & 0x1FFFF;
  }
  __syncthreads();
  if (tid < 128){
    int node = b * 128 + tid;
    int c = cur[tid];                 // l0 + deg
    int l = l0[tid];
    int end = l + ((c - l + 8) & ~7); // l + padded count (pad-to-8)
    csr[base + c] = node;             // self-loop
    for (int q = c + 1; q < end; q++) csr[base + q] = NN;   // pads -> zero row
    indptr[node] = base + l;
  }
}

// ---------------- fused: normalize(concat(pref,temp)) + hsb = bf16(dinv * (row @ W^T)) ----------------
__global__ __launch_bounds__(256) void norm_lin(const float* __restrict__ pref,
                                                float* __restrict__ x,
                                                const float* __restrict__ w,
                                                const float* __restrict__ dinv,
                                                unsigned short* __restrict__ hsb){
  __shared__ float W[DD][DD + 1];
  for (int q = threadIdx.x; q < DD * DD; q += 256) W[q >> 6][q & 63] = w[q];
  __syncthreads();
  int node = blockIdx.x * 4 + (threadIdx.x >> 6);
  int lane = threadIdx.x & 63;
  float v = (node < NUSER) ? pref[(size_t)node * DD + lane] : x[(size_t)node * DD + lane];
  float ss = v * v;
  #pragma unroll
  for (int o = 1; o < 64; o <<= 1) ss += __shfl_xor(ss, o);
  v = v / fmaxf(sqrtf(ss), 1e-12f);
  x[(size_t)node * DD + lane] = v;
  __shared__ float rowbuf[4][DD];
  int wv = threadIdx.x >> 6;
  rowbuf[wv][lane] = v;
  __syncthreads();
  float acc = 0.f;
  #pragma unroll
  for (int d = 0; d < DD; d++) acc = fmaf(rowbuf[wv][d], W[lane][d], acc);
  hsb[(size_t)node * DD + lane] = f2bf(dinv[node] * acc);
}

// ---------------- conv1 agg + fused lin: hbuf = di*sum(hsb_a[j]) + cb ; hsb_b = bf16(di*(hbuf@W^T)) ----------------
__global__ __launch_bounds__(256) void agg_lin(const unsigned short* __restrict__ hsba,
                                               const float* __restrict__ dinv,
                                               const int* __restrict__ indptr,
                                               const int* __restrict__ csr,
                                               const float* __restrict__ cb,
                                               const float* __restrict__ cw,
                                               float* __restrict__ hbuf,
                                               unsigned short* __restrict__ hsbb){
  __shared__ float W[DD][DD + 1];
  __shared__ float rowbuf[4][DD];
  for (int q = threadIdx.x; q < DD * DD; q += 256) W[q >> 6][q & 63] = cw[q];
  int node = blockIdx.x * 4 + (threadIdx.x >> 6);
  int lane = threadIdx.x & 63;
  int wv = threadIdx.x >> 6;
  int g  = lane >> 3;          // edge group 0..7
  int sl = lane & 7;           // 8 lanes x 8 bf16 (16B) = one 64-elem row
  int e0 = indptr[node];
  int nit = (indptr[node + 1] - e0) >> 3;
  float a0=0.f,a1=0.f,a2=0.f,a3=0.f,a4=0.f,a5=0.f,a6=0.f,a7=0.f;
  int k = e0 + g;
  for (int i = 0; i < nit; i++){
    int j = csr[k];
    k += 8;
    s16x8 v = *(const s16x8*)&hsba[(size_t)j * DD + sl * 8];
    a0 += bf2f((unsigned short)v[0]); a1 += bf2f((unsigned short)v[1]);
    a2 += bf2f((unsigned short)v[2]); a3 += bf2f((unsigned short)v[3]);
    a4 += bf2f((unsigned short)v[4]); a5 += bf2f((unsigned short)v[5]);
    a6 += bf2f((unsigned short)v[6]); a7 += bf2f((unsigned short)v[7]);
  }
  #pragma unroll
  for (int off = 8; off < 64; off <<= 1){
    a0 += __shfl_xor(a0, off); a1 += __shfl_xor(a1, off);
    a2 += __shfl_xor(a2, off); a3 += __shfl_xor(a3, off);
    a4 += __shfl_xor(a4, off); a5 += __shfl_xor(a5, off);
    a6 += __shfl_xor(a6, off); a7 += __shfl_xor(a7, off);
  }
  if (g == 0){
    float di = dinv[node];
    size_t rb = (size_t)node * DD + sl * 8;
    const float4 bi0 = *(const float4*)&cb[sl * 8];
    const float4 bi1 = *(const float4*)&cb[sl * 8 + 4];
    float4 r0, r1;
    r0.x = fmaf(di, a0, bi0.x); r0.y = fmaf(di, a1, bi0.y);
    r0.z = fmaf(di, a2, bi0.z); r0.w = fmaf(di, a3, bi0.w);
    r1.x = fmaf(di, a4, bi1.x); r1.y = fmaf(di, a5, bi1.y);
    r1.z = fmaf(di, a6, bi1.z); r1.w = fmaf(di, a7, bi1.w);
    *(float4*)&hbuf[rb] = r0;
    *(float4*)&hbuf[rb + 4] = r1;
    *(float4*)&rowbuf[wv][sl * 8] = r0;
    *(float4*)&rowbuf[wv][sl * 8 + 4] = r1;
  }
  __syncthreads();
  float acc = 0.f;
  #pragma unroll
  for (int d = 0; d < DD; d++) acc = fmaf(rowbuf[wv][d], W[lane][d], acc);
  hsbb[(size_t)node * DD + lane] = f2bf(dinv[node] * acc);
}

// ---------------- final agg: out = x + hbuf + (di*sum(hsb_b[j]) + cb) ; + pref tail copy ----------------
__global__ __launch_bounds__(256) void agg_final(const unsigned short* __restrict__ hsb,
                                                 const float* __restrict__ dinv,
                                                 const int* __restrict__ indptr,
                                                 const int* __restrict__ csr,
                                                 const float* __restrict__ bias,
                                                 const float* __restrict__ x,
                                                 const float* __restrict__ h,
                                                 float* __restrict__ out,
                                                 const float* __restrict__ pref,
                                                 float* __restrict__ out2){
  int b = blockIdx.x;
  if (b >= NN / 4){
    long q = (long)(b - NN / 4) * 256 + threadIdx.x;
    if (q < (long)NUSER * DD / 4)
      ((float4*)out2)[q] = ((const float4*)pref)[q];
    return;
  }
  int node = b * 4 + (threadIdx.x >> 6);
  int lane = threadIdx.x & 63;
  int g  = lane >> 3;
  int sl = lane & 7;
  int e0 = indptr[node];
  int nit = (indptr[node + 1] - e0) >> 3;
  float a0=0.f,a1=0.f,a2=0.f,a3=0.f,a4=0.f,a5=0.f,a6=0.f,a7=0.f;
  int k = e0 + g;
  for (int i = 0; i < nit; i++){
    int j = csr[k];
    k += 8;
    s16x8 v = *(const s16x8*)&hsb[(size_t)j * DD + sl * 8];
    a0 += bf2f((unsigned short)v[0]); a1 += bf2f((unsigned short)v[1]);
    a2 += bf2f((unsigned short)v[2]); a3 += bf2f((unsigned short)v[3]);
    a4 += bf2f((unsigned short)v[4]); a5 += bf2f((unsigned short)v[5]);
    a6 += bf2f((unsigned short)v[6]); a7 += bf2f((unsigned short)v[7]);
  }
  #pragma unroll
  for (int off = 8; off < 64; off <<= 1){
    a0 += __shfl_xor(a0, off); a1 += __shfl_xor(a1, off);
    a2 += __shfl_xor(a2, off); a3 += __shfl_xor(a3, off);
    a4 += __shfl_xor(a4, off); a5 += __shfl_xor(a5, off);
    a6 += __shfl_xor(a6, off); a7 += __shfl_xor(a7, off);
  }
  if (g == 0){
    float di = dinv[node];
    size_t rb = (size_t)node * DD + sl * 8;
    const float4 bi0 = *(const float4*)&bias[sl * 8];
    const float4 bi1 = *(const float4*)&bias[sl * 8 + 4];
    float4 r0, r1;
    r0.x = fmaf(di, a0, bi0.x); r0.y = fmaf(di, a1, bi0.y);
    r0.z = fmaf(di, a2, bi0.z); r0.w = fmaf(di, a3, bi0.w);
    r1.x = fmaf(di, a4, bi1.x); r1.y = fmaf(di, a5, bi1.y);
    r1.z = fmaf(di, a6, bi1.z); r1.w = fmaf(di, a7, bi1.w);
    const float4 xv0 = *(const float4*)&x[rb];
    const float4 xv1 = *(const float4*)&x[rb + 4];
    const float4 hv0 = *(const float4*)&h[rb];
    const float4 hv1 = *(const float4*)&h[rb + 4];
    r0.x += xv0.x + hv0.x; r0.y += xv0.y + hv0.y;
    r0.z += xv0.z + hv0.z; r0.w += xv0.w + hv0.w;
    r1.x += xv1.x + hv1.x; r1.y += xv1.y + hv1.y;
    r1.z += xv1.z + hv1.z; r1.w += xv1.w + hv1.w;
    *(float4*)&out[rb] = r0;
    *(float4*)&out[rb + 4] = r1;
  }
}

extern "C" void kernel_launch(void* const* d_in, const int* in_sizes, int n_in,
                              void* d_out, int out_size, void* d_ws, size_t ws_size,
                              hipStream_t stream){
  const int*   ei    = (const int*)  d_in[0];
  const float* feats = (const float*)d_in[1];
  const float* pref  = (const float*)d_in[2];
  const float* w1    = (const float*)d_in[3];
  const float* b1    = (const float*)d_in[4];
  const float* w2    = (const float*)d_in[5];
  const float* b2    = (const float*)d_in[6];
  const float* cw    = (const float*)d_in[7];
  const float* cb    = (const float*)d_in[8];
  float* out = (float*)d_out;

  // ---- workspace layout (lifetime-overlapped; peak within proven ~77.2MB) ----
  // [0, 20.48MB)      x f32 [NN*64]
  // [20.48, 40.96MB)  hbuf f32 [NN*64]  -- CSR-build scratch overlays it early
  // [40.96, ~49.3MB)  live graph: csr[CSRCAP] | indptr[NN+1] | dinv[NN] | lofs[NN]
  // [51.25, 61.49MB)  hsb_a bf16 [(NN+1)*64]
  // [61.49, 71.73MB)  hsb_b bf16 [(NN+1)*64]
  // [76.91MB, ...)    w1b, w2b bf16
  char* wsb = (char*)d_ws;
  float* x       = (float*)wsb;
  float* hbuf    = (float*)(wsb + (size_t)NN * DD * 4);
  int*   pairsv  = (int*)hbuf;
  int*   hist    = pairsv + NE;
  int*   sc      = hist + NHIST;
  int*   bsum    = sc + NHIST;
  int*   boff    = bsum + NPART;
  int*   btot    = boff + NPART;
  int*   bbase   = btot + NBUCK;
  char*  graphb  = wsb + (size_t)NN * DD * 8;
  int*   csr     = (int*)graphb;
  int*   indptr  = csr + CSRCAP;
  float* dinv    = (float*)(indptr + NN + 1);
  int*   lofs    = (int*)(dinv + NN);
  unsigned short* hsba = (unsigned short*)(wsb + (size_t)MPAD * FEAT * 2);
  unsigned short* hsbb = hsba + (size_t)(NN + 1) * DD;
  short* w1b     = (short*)(wsb + (size_t)MPAD * FEAT * 2 + (size_t)(MPAD + 64) * HIDN * 2);
  short* w2b     = w1b + (size_t)HIDN * FEAT;

  // ---- weights to bf16 + pad-row zeroing ----
  cvt_w<<<(HIDN * FEAT / 4 + DD * HIDN / 4 + 255) / 256, 256, 0, stream>>>(
      w1, w2, (unsigned short*)w1b, (unsigned short*)w2b);
  hipMemsetAsync(hsba + (size_t)NN * DD, 0, DD * sizeof(unsigned short), stream);
  hipMemsetAsync(hsbb + (size_t)NN * DD, 0, DD * sizeof(unsigned short), stream);

  // ---- atomic-free CSR build ----
  histo_kernel<<<NCHUNK, 256, 0, stream>>>(ei, hist);
  scan_part<<<NPART, 256, 0, stream>>>(hist, NHIST, bsum);
  scan_mid<<<1, 1024, 0, stream>>>(bsum, NPART, boff, nullptr);
  scan_apply<<<NPART, 1024, 0, stream>>>(hist, boff, sc, NHIST);
  binscat_kernel<<<NCHUNK, 256, 0, stream>>>(ei, sc, pairsv);
  bucket_count<<<NBUCK, 256, 0, stream>>>(pairsv, sc, lofs, dinv, btot);
  scan_mid<<<1, 1024, 0, stream>>>(btot, NBUCK, bbase, indptr + NN);
  bucket_fill<<<NBUCK, 256, 0, stream>>>(pairsv, sc, lofs, bbase, csr, indptr);

  // ---- fused MLP: feats(f32) -> x item rows ----
  mlp_fused<<<MPAD / 64, 256, 0, stream>>>(feats, w1b, w2b, b1, b2, x);

  // ---- x = normalize(concat(pref, temp)); hsb_a = bf16(dinv * (x @ cw^T)) ----
  norm_lin<<<NN / 4, 256, 0, stream>>>(pref, x, cw, dinv, hsba);
  // ---- conv1 + fused lin: hbuf, hsb_b ----
  agg_lin<<<NN / 4, 256, 0, stream>>>(hsba, dinv, indptr, csr, cb, cw, hbuf, hsbb);
  // ---- conv2 + residual + pref tail copy ----
  agg_final<<<NN / 4 + (NUSER * DD / 4 + 255) / 256, 256, 0, stream>>>(
      hsbb, dinv, indptr, csr, cb, x, hbuf, out, pref, out + (size_t)NN * DD);
}

// Round 7
// 253.826 us; speedup vs baseline: 3.2299x; 1.1140x over previous
//
#include <hip/hip_runtime.h>

#define NUSER 30000
#define NITEM 50000
#define NN    80000
#define NE    1200000
#define DD    64
#define FEAT  512
#define HIDN  256
#define MPAD  50048           // NITEM rounded up to 128 (grid sizing)
#define CSRCAP (NE + 8 * NN)  // padded CSR capacity (pad-to-8)

#define NBUCK  625            // dst >> 7 ; 625*128 == 80000 exactly
#define NCHUNK 256            // edge chunks for histogram/binscat
#define CHSZ   ((NE + NCHUNK - 1) / NCHUNK)   // 4688
#define NHIST  (NBUCK * NCHUNK)               // 160000
#define NPART  ((NHIST + 1023) / 1024)        // 157

using s16x8 = __attribute__((ext_vector_type(8))) short;
using f32x4 = __attribute__((ext_vector_type(4))) float;

__device__ __forceinline__ unsigned short f2bf(float f){
  unsigned int u = __float_as_uint(f);
  unsigned int r = (u + 0x7fffu + ((u >> 16) & 1u)) >> 16;
  return (unsigned short)r;
}

__device__ __forceinline__ float bf2f(unsigned short s){
  unsigned int u = ((unsigned int)s) << 16;
  return __uint_as_float(u);
}

__device__ __forceinline__ void gload_lds16(const void* g, void* l){
  __builtin_amdgcn_global_load_lds(
      (const __attribute__((address_space(1))) unsigned int*)g,
      (__attribute__((address_space(3))) unsigned int*)l, 16, 0, 0);
}

// ---------------- weights fp32 -> bf16: w1 | w2 | cw ----------------
__global__ __launch_bounds__(256) void cvt_w(const float* __restrict__ w1,
                                             const float* __restrict__ w2,
                                             const float* __restrict__ cw,
                                             unsigned short* __restrict__ w1b,
                                             unsigned short* __restrict__ w2b,
                                             unsigned short* __restrict__ cwb){
  const int n1 = HIDN * FEAT / 4;   // 32768
  const int n2 = DD * HIDN / 4;     // 4096
  const int n3 = DD * DD / 4;       // 1024
  int q = blockIdx.x * 256 + threadIdx.x;
  const float4* src; ushort4* dst; int i;
  if (q < n1){ src = (const float4*)w1; dst = (ushort4*)w1b; i = q; }
  else if (q < n1 + n2){ src = (const float4*)w2; dst = (ushort4*)w2b; i = q - n1; }
  else if (q < n1 + n2 + n3){ src = (const float4*)cw; dst = (ushort4*)cwb; i = q - n1 - n2; }
  else return;
  float4 v = src[i];
  ushort4 o = { f2bf(v.x), f2bf(v.y), f2bf(v.z), f2bf(v.w) };
  dst[i] = o;
}

// ---------------- GEMM1: hiddenb = bf16(leaky(feats_f32 @ w1b^T + b1)) ----------------
// 128x128 tile, BK=32, 4 waves (2x2). A staged f32->bf16 in-register (padded stride 40).
__global__ __launch_bounds__(256) void gemm1f(const float* __restrict__ feats,
                                              const short* __restrict__ w1b,
                                              const float* __restrict__ b1,
                                              unsigned short* __restrict__ hiddenb){
  constexpr int BK = 32;
  constexpr int AP = 40;                       // padded A stride (elems)
  __shared__ __align__(16) short As[128 * AP]; // 10KB
  __shared__ __align__(16) short Bs[128 * BK]; // 8KB

  const int tid  = threadIdx.x;
  const int wid  = tid >> 6;
  const int lane = tid & 63;
  const int wr   = wid >> 1;
  const int wc   = wid & 1;
  const int m0   = blockIdx.y * 128;
  const int n0   = blockIdx.x * 128;

  f32x4 acc[4][4] = {};

  for (int k0 = 0; k0 < FEAT; k0 += BK){
    // A: 128 rows x 32 f32 = 1024 float4 chunks, 4/thread; cvt to bf16, padded LDS
    #pragma unroll
    for (int s = 0; s < 4; s++){
      int c = s * 256 + tid;
      int row = c >> 3, kc = c & 7;            // 8 float4 per 32-f32 row
      int gr = m0 + row;
      float4 v = make_float4(0.f, 0.f, 0.f, 0.f);
      if (gr < NITEM) v = *(const float4*)&feats[(size_t)gr * FEAT + k0 + kc * 4];
      ushort4 o = { f2bf(v.x), f2bf(v.y), f2bf(v.z), f2bf(v.w) };
      *(ushort4*)&As[row * AP + kc * 4] = o;
    }
    // B: w1 tile 128x32 bf16 via global_load_lds, 2 issues
    #pragma unroll
    for (int s = 0; s < 2; s++){
      int q = s * 256 + tid;
      int row = q >> 2, kc = q & 3;
      const short* src = w1b + (size_t)(n0 + row) * FEAT + k0 + kc * 8;
      gload_lds16(src, &Bs[(size_t)(s * 256 + wid * 64) * 8]);
    }
    __syncthreads();

    s16x8 af[4], bf[4];
    #pragma unroll
    for (int m = 0; m < 4; m++)
      af[m] = *(const s16x8*)&As[(wr * 64 + m * 16 + (lane & 15)) * AP + (lane >> 4) * 8];
    #pragma unroll
    for (int n = 0; n < 4; n++)
      bf[n] = *(const s16x8*)&Bs[(wc * 64 + n * 16 + (lane & 15)) * BK + (lane >> 4) * 8];
    #pragma unroll
    for (int m = 0; m < 4; m++)
      #pragma unroll
      for (int n = 0; n < 4; n++)
        acc[m][n] = __builtin_amdgcn_mfma_f32_16x16x32_bf16(af[m], bf[n], acc[m][n], 0, 0, 0);
    __syncthreads();
  }

  // epilogue: bias + leaky -> bf16 (C/D: col=lane&15, row=(lane>>4)*4+r)
  #pragma unroll
  for (int m = 0; m < 4; m++){
    int row_base = m0 + wr * 64 + m * 16 + (lane >> 4) * 4;
    #pragma unroll
    for (int n = 0; n < 4; n++){
      int col = n0 + wc * 64 + n * 16 + (lane & 15);
      float bi = b1[col];
      #pragma unroll
      for (int r = 0; r < 4; r++){
        int row = row_base + r;
        if (row >= NITEM) continue;
        float v = acc[m][n][r] + bi;
        v = v > 0.f ? v : 0.01f * v;
        hiddenb[(size_t)row * HIDN + col] = f2bf(v);
      }
    }
  }
}

// ---------------- GEMM2: x items = hiddenb @ w2b^T + b2 (f32 out) ----------------
__global__ __launch_bounds__(256) void gemm2(const short* __restrict__ Ag,
                                             const short* __restrict__ Bg,
                                             const float* __restrict__ bias,
                                             float* __restrict__ Cout){
  constexpr int BK = 32;
  __shared__ __align__(16) short As[128 * BK];
  __shared__ __align__(16) short Bs[64 * BK];

  const int tid  = threadIdx.x;
  const int wid  = tid >> 6;
  const int lane = tid & 63;
  const int wr   = wid >> 1;
  const int wc   = wid & 1;
  const int m0   = blockIdx.y * 128;

  f32x4 acc[4][2] = {};

  for (int k0 = 0; k0 < HIDN; k0 += BK){
    #pragma unroll
    for (int s = 0; s < 2; s++){
      int q = s * 256 + tid;
      int row = q >> 2, kc = q & 3;
      const short* src = Ag + (size_t)(m0 + row) * HIDN + k0 + kc * 8;
      gload_lds16(src, &As[(size_t)(s * 256 + wid * 64) * 8]);
    }
    {
      int q = tid;
      int row = q >> 2, kc = q & 3;
      if (q < 256){
        const short* src = Bg + (size_t)row * HIDN + k0 + kc * 8;
        gload_lds16(src, &Bs[(size_t)(wid * 64) * 8]);
      }
    }
    __syncthreads();

    s16x8 af[4], bf[2];
    #pragma unroll
    for (int m = 0; m < 4; m++)
      af[m] = *(const s16x8*)&As[(wr * 64 + m * 16 + (lane & 15)) * BK + (lane >> 4) * 8];
    #pragma unroll
    for (int n = 0; n < 2; n++)
      bf[n] = *(const s16x8*)&Bs[(wc * 32 + n * 16 + (lane & 15)) * BK + (lane >> 4) * 8];
    #pragma unroll
    for (int m = 0; m < 4; m++)
      #pragma unroll
      for (int n = 0; n < 2; n++)
        acc[m][n] = __builtin_amdgcn_mfma_f32_16x16x32_bf16(af[m], bf[n], acc[m][n], 0, 0, 0);
    __syncthreads();
  }

  #pragma unroll
  for (int m = 0; m < 4; m++){
    int row_base = m0 + wr * 64 + m * 16 + (lane >> 4) * 4;
    #pragma unroll
    for (int n = 0; n < 2; n++){
      int col = wc * 32 + n * 16 + (lane & 15);
      float bi = bias[col];
      #pragma unroll
      for (int r = 0; r < 4; r++){
        int row = row_base + r;
        if (row >= NITEM) continue;
        Cout[(size_t)row * DD + col] = acc[m][n][r] + bi;
      }
    }
  }
}

// ================= atomic-free CSR build =================
__global__ __launch_bounds__(256) void histo_kernel(const int* __restrict__ ei,
                                                    int* __restrict__ hist){
  __shared__ int h[NBUCK];
  const int tid = threadIdx.x, c = blockIdx.x;
  for (int i = tid; i < NBUCK; i += 256) h[i] = 0;
  __syncthreads();
  int e0 = c * CHSZ, e1 = min(e0 + CHSZ, NE);
  for (int e = e0 + tid; e < e1; e += 256)
    atomicAdd(&h[ei[NE + e] >> 7], 1);
  __syncthreads();
  for (int i = tid; i < NBUCK; i += 256) hist[i * NCHUNK + c] = h[i];
}

__global__ __launch_bounds__(256) void scan_part(const int* __restrict__ a, int n,
                                                 int* __restrict__ bsum){
  __shared__ int ws4[4];
  int b = blockIdx.x, base = b * 1024;
  int v = 0;
  #pragma unroll
  for (int s = 0; s < 4; s++){
    int idx = base + s * 256 + threadIdx.x;
    if (idx < n) v += a[idx];
  }
  int lane = threadIdx.x & 63, w = threadIdx.x >> 6;
  #pragma unroll
  for (int o = 1; o < 64; o <<= 1) v += __shfl_xor(v, o);
  if (lane == 0) ws4[w] = v;
  __syncthreads();
  if (threadIdx.x == 0) bsum[b] = ws4[0] + ws4[1] + ws4[2] + ws4[3];
}

__global__ __launch_bounds__(1024) void scan_mid(const int* __restrict__ a, int np,
                                                 int* __restrict__ excl_out,
                                                 int* __restrict__ total_out){
  __shared__ int wsum[16];
  int tid = threadIdx.x;
  int v = (tid < np) ? a[tid] : 0;
  int lane = tid & 63, w = tid >> 6;
  int incl = v;
  #pragma unroll
  for (int o = 1; o < 64; o <<= 1){ int u = __shfl_up(incl, o); if (lane >= o) incl += u; }
  if (lane == 63) wsum[w] = incl;
  __syncthreads();
  int woff = 0;
  #pragma unroll
  for (int k = 0; k < 16; k++) if (k < w) woff += wsum[k];
  if (tid < np) excl_out[tid] = woff + incl - v;
  if (total_out && tid == 1023) *total_out = woff + incl;
}

__global__ __launch_bounds__(1024) void scan_apply(const int* __restrict__ a,
                                                   const int* __restrict__ boff,
                                                   int* __restrict__ sc, int n){
  __shared__ int wsum[16];
  int b = blockIdx.x, tid = threadIdx.x;
  int idx = b * 1024 + tid;
  int v = (idx < n) ? a[idx] : 0;
  int lane = tid & 63, w = tid >> 6;
  int incl = v;
  #pragma unroll
  for (int o = 1; o < 64; o <<= 1){ int u = __shfl_up(incl, o); if (lane >= o) incl += u; }
  if (lane == 63) wsum[w] = incl;
  __syncthreads();
  int woff = 0;
  #pragma unroll
  for (int k = 0; k < 16; k++) if (k < w) woff += wsum[k];
  if (idx < n) sc[idx] = boff[b] + woff + incl - v;
}

__global__ __launch_bounds__(256) void binscat_kernel(const int* __restrict__ ei,
                                                      const int* __restrict__ sc,
                                                      int* __restrict__ pairsv){
  __shared__ int cur[NBUCK];
  const int tid = threadIdx.x, c = blockIdx.x;
  for (int i = tid; i < NBUCK; i += 256) cur[i] = sc[i * NCHUNK + c];
  __syncthreads();
  int e0 = c * CHSZ, e1 = min(e0 + CHSZ, NE);
  for (int e = e0 + tid; e < e1; e += 256){
    int s = ei[e];
    int d = ei[NE + e];
    int pos = atomicAdd(&cur[d >> 7], 1);
    pairsv[pos] = ((d & 127) << 17) | s;
  }
}

__global__ __launch_bounds__(256) void bucket_count(const int* __restrict__ pairsv,
                                                    const int* __restrict__ sc,
                                                    int* __restrict__ lofs,
                                                    float* __restrict__ dinv,
                                                    int* __restrict__ btot){
  __shared__ int cnt[128];
  __shared__ int wtot;
  const int tid = threadIdx.x, b = blockIdx.x;
  if (tid < 128) cnt[tid] = 0;
  __syncthreads();
  int e0 = sc[b * NCHUNK];
  int e1 = (b == NBUCK - 1) ? NE : sc[(b + 1) * NCHUNK];
  for (int e = e0 + tid; e < e1; e += 256)
    atomicAdd(&cnt[(pairsv[e] >> 17) & 127], 1);
  __syncthreads();
  int lane = tid & 63;
  int incl = 0, pc = 0;
  if (tid < 128){
    pc = (cnt[tid] + 8) & ~7;        // deg + 1 self, padded to x8
    incl = pc;
    #pragma unroll
    for (int o = 1; o < 64; o <<= 1){ int u = __shfl_up(incl, o); if (lane >= o) incl += u; }
  }
  if (tid == 63) wtot = incl;
  __syncthreads();
  if (tid < 128){
    int excl = incl - pc + (tid >= 64 ? wtot : 0);
    int node = b * 128 + tid;
    lofs[node] = excl;
    dinv[node] = rsqrtf((float)(cnt[tid] + 1));
    if (tid == 127) btot[b] = excl + pc;
  }
}

__global__ __launch_bounds__(256) void bucket_fill(const int* __restrict__ pairsv,
                                                   const int* __restrict__ sc,
                                                   const int* __restrict__ lofs,
                                                   const int* __restrict__ bbase,
                                                   int* __restrict__ csr,
                                                   int* __restrict__ indptr){
  __shared__ int cur[128], l0[128];
  const int tid = threadIdx.x, b = blockIdx.x;
  const int base = bbase[b];
  if (tid < 128){
    int v = lofs[b * 128 + tid];
    cur[tid] = v; l0[tid] = v;
  }
  __syncthreads();
  int e0 = sc[b * NCHUNK];
  int e1 = (b == NBUCK - 1) ? NE : sc[(b + 1) * NCHUNK];
  for (int e = e0 + tid; e < e1; e += 256){
    int v = pairsv[e];
    int li = (v >> 17) & 127;
    int p = atomicAdd(&cur[li], 1);
    csr[base + p] = v & 0x1FFFF;
  }
  __syncthreads();
  if (tid < 128){
    int node = b * 128 + tid;
    int c = cur[tid];                 // l0 + deg
    int l = l0[tid];
    int end = l + ((c - l + 8) & ~7); // l + padded count (pad-to-8)
    csr[base + c] = node;             // self-loop
    for (int q = c + 1; q < end; q++) csr[base + q] = NN;   // pads -> zero row
    indptr[node] = base + l;
  }
}

// ---------------- normalize rows of x (users from pref, items from gemm2) ----------------
__global__ __launch_bounds__(256) void normalize_k(const float* __restrict__ pref,
                                                   float* __restrict__ x){
  int node = blockIdx.x * 4 + (threadIdx.x >> 6);
  int lane = threadIdx.x & 63;
  float v = (node < NUSER) ? pref[(size_t)node * DD + lane] : x[(size_t)node * DD + lane];
  float ss = v * v;
  #pragma unroll
  for (int o = 1; o < 64; o <<= 1) ss += __shfl_xor(ss, o);
  v = v / fmaxf(sqrtf(ss), 1e-12f);
  x[(size_t)node * DD + lane] = v;
}

// ---------------- lin via MFMA: hsb = bf16(dinv[row] * (src @ cwb^T)) ----------------
// 128 rows/block (grid 625), A f32->bf16 reg-staged (padded stride 72), B frags from global (L2-hot).
__global__ __launch_bounds__(256) void lin_mfma(const float* __restrict__ src,
                                                const short* __restrict__ cwb,
                                                const float* __restrict__ dinv,
                                                unsigned short* __restrict__ hsb){
  constexpr int AP = 72;                        // padded stride (elems)
  __shared__ __align__(16) short As[128 * AP];  // 18KB

  const int tid  = threadIdx.x;
  const int wid  = tid >> 6;
  const int lane = tid & 63;
  const int wr   = wid >> 1;
  const int wc   = wid & 1;
  const int m0   = blockIdx.x * 128;

  // stage A: 128x64 f32 = 2048 float4, 8/thread
  #pragma unroll
  for (int s = 0; s < 8; s++){
    int c = s * 256 + tid;
    int row = c >> 4, kc = c & 15;              // 16 float4 per 64-f32 row
    float4 v = *(const float4*)&src[(size_t)(m0 + row) * DD + kc * 4];
    ushort4 o = { f2bf(v.x), f2bf(v.y), f2bf(v.z), f2bf(v.w) };
    *(ushort4*)&As[row * AP + kc * 4] = o;
  }
  __syncthreads();

  f32x4 acc[4][2] = {};
  #pragma unroll
  for (int kk = 0; kk < DD; kk += 32){
    s16x8 af[4], bf[2];
    #pragma unroll
    for (int m = 0; m < 4; m++)
      af[m] = *(const s16x8*)&As[(wr * 64 + m * 16 + (lane & 15)) * AP + kk + (lane >> 4) * 8];
    #pragma unroll
    for (int n = 0; n < 2; n++)
      bf[n] = *(const s16x8*)&cwb[(size_t)(wc * 32 + n * 16 + (lane & 15)) * DD + kk + (lane >> 4) * 8];
    #pragma unroll
    for (int m = 0; m < 4; m++)
      #pragma unroll
      for (int n = 0; n < 2; n++)
        acc[m][n] = __builtin_amdgcn_mfma_f32_16x16x32_bf16(af[m], bf[n], acc[m][n], 0, 0, 0);
  }

  #pragma unroll
  for (int m = 0; m < 4; m++){
    int row_base = m0 + wr * 64 + m * 16 + (lane >> 4) * 4;
    #pragma unroll
    for (int n = 0; n < 2; n++){
      int col = wc * 32 + n * 16 + (lane & 15);
      #pragma unroll
      for (int r = 0; r < 4; r++){
        int row = row_base + r;
        hsb[(size_t)row * DD + col] = f2bf(dinv[row] * acc[m][n][r]);
      }
    }
  }
}

// ---------------- gather aggregation: 8 edges in flight, 8 lanes x s16x8 (bf16 rows) ----------------
template<int FINAL>
__global__ __launch_bounds__(256) void agg_kernel(const unsigned short* __restrict__ hsb,
                                                  const float* __restrict__ dinv,
                                                  const int* __restrict__ indptr,
                                                  const int* __restrict__ csr,
                                                  const float* __restrict__ bias,
                                                  const float* __restrict__ x,
                                                  const float* __restrict__ h,
                                                  float* __restrict__ out,
                                                  const float* __restrict__ pref,
                                                  float* __restrict__ out2){
  int b = blockIdx.x;
  if (FINAL && b >= NN / 4){
    long q = (long)(b - NN / 4) * 256 + threadIdx.x;
    if (q < (long)NUSER * DD / 4)
      ((float4*)out2)[q] = ((const float4*)pref)[q];
    return;
  }
  int node = b * 4 + (threadIdx.x >> 6);
  int lane = threadIdx.x & 63;
  int g  = lane >> 3;          // edge group 0..7
  int sl = lane & 7;           // 8 lanes x 8 bf16 (16B) = one 64-elem row
  int e0 = indptr[node];
  int nit = (indptr[node + 1] - e0) >> 3;
  float a0=0.f,a1=0.f,a2=0.f,a3=0.f,a4=0.f,a5=0.f,a6=0.f,a7=0.f;
  int k = e0 + g;
  for (int i = 0; i < nit; i++){
    int j = csr[k];
    k += 8;
    s16x8 v = *(const s16x8*)&hsb[(size_t)j * DD + sl * 8];
    a0 += bf2f((unsigned short)v[0]); a1 += bf2f((unsigned short)v[1]);
    a2 += bf2f((unsigned short)v[2]); a3 += bf2f((unsigned short)v[3]);
    a4 += bf2f((unsigned short)v[4]); a5 += bf2f((unsigned short)v[5]);
    a6 += bf2f((unsigned short)v[6]); a7 += bf2f((unsigned short)v[7]);
  }
  #pragma unroll
  for (int off = 8; off < 64; off <<= 1){
    a0 += __shfl_xor(a0, off); a1 += __shfl_xor(a1, off);
    a2 += __shfl_xor(a2, off); a3 += __shfl_xor(a3, off);
    a4 += __shfl_xor(a4, off); a5 += __shfl_xor(a5, off);
    a6 += __shfl_xor(a6, off); a7 += __shfl_xor(a7, off);
  }
  if (g == 0){
    float di = dinv[node];
    size_t rb = (size_t)node * DD + sl * 8;
    const float4 bi0 = *(const float4*)&bias[sl * 8];
    const float4 bi1 = *(const float4*)&bias[sl * 8 + 4];
    float4 r0, r1;
    r0.x = fmaf(di, a0, bi0.x); r0.y = fmaf(di, a1, bi0.y);
    r0.z = fmaf(di, a2, bi0.z); r0.w = fmaf(di, a3, bi0.w);
    r1.x = fmaf(di, a4, bi1.x); r1.y = fmaf(di, a5, bi1.y);
    r1.z = fmaf(di, a6, bi1.z); r1.w = fmaf(di, a7, bi1.w);
    if (FINAL){
      const float4 xv0 = *(const float4*)&x[rb];
      const float4 xv1 = *(const float4*)&x[rb + 4];
      const float4 hv0 = *(const float4*)&h[rb];
      const float4 hv1 = *(const float4*)&h[rb + 4];
      r0.x += xv0.x + hv0.x; r0.y += xv0.y + hv0.y;
      r0.z += xv0.z + hv0.z; r0.w += xv0.w + hv0.w;
      r1.x += xv1.x + hv1.x; r1.y += xv1.y + hv1.y;
      r1.z += xv1.z + hv1.z; r1.w += xv1.w + hv1.w;
    }
    *(float4*)&out[rb] = r0;
    *(float4*)&out[rb + 4] = r1;
  }
}

extern "C" void kernel_launch(void* const* d_in, const int* in_sizes, int n_in,
                              void* d_out, int out_size, void* d_ws, size_t ws_size,
                              hipStream_t stream){
  const int*   ei    = (const int*)  d_in[0];
  const float* feats = (const float*)d_in[1];
  const float* pref  = (const float*)d_in[2];
  const float* w1    = (const float*)d_in[3];
  const float* b1    = (const float*)d_in[4];
  const float* w2    = (const float*)d_in[5];
  const float* b2    = (const float*)d_in[6];
  const float* cw    = (const float*)d_in[7];
  const float* cb    = (const float*)d_in[8];
  float* out = (float*)d_out;

  // ---- workspace layout (lifetime-overlapped; peak ~77.2MB, proven) ----
  // [0, 20.48MB)      x f32 [NN*64]
  // [20.48, 40.96MB)  hbuf f32 [NN*64]  -- CSR-build scratch overlays it early
  // [40.96, ~49.3MB)  live graph: csr[CSRCAP] | indptr[NN+1] | dinv[NN] | lofs[NN]
  // [51.25, 76.9MB)   hiddenb bf16 [MPAD*256] (dead after gemm2), then overlaid by:
  //                   hsb_a [(NN+1)*64] bf16 | hsb_b [(NN+1)*64] bf16
  // [76.9MB, ...)     w1b, w2b, cwb bf16
  char* wsb = (char*)d_ws;
  float* x       = (float*)wsb;
  float* hbuf    = (float*)(wsb + (size_t)NN * DD * 4);
  int*   pairsv  = (int*)hbuf;
  int*   hist    = pairsv + NE;
  int*   sc      = hist + NHIST;
  int*   bsum    = sc + NHIST;
  int*   boff    = bsum + NPART;
  int*   btot    = boff + NPART;
  int*   bbase   = btot + NBUCK;
  char*  graphb  = wsb + (size_t)NN * DD * 8;
  int*   csr     = (int*)graphb;
  int*   indptr  = csr + CSRCAP;
  float* dinv    = (float*)(indptr + NN + 1);
  int*   lofs    = (int*)(dinv + NN);
  unsigned short* hiddenb = (unsigned short*)(wsb + (size_t)MPAD * FEAT * 2);
  unsigned short* hsba = hiddenb;
  unsigned short* hsbb = hsba + (size_t)(NN + 1) * DD;
  short* w1b     = (short*)(wsb + (size_t)MPAD * FEAT * 2 + (size_t)(MPAD + 64) * HIDN * 2);
  short* w2b     = w1b + (size_t)HIDN * FEAT;
  short* cwb     = w2b + (size_t)DD * HIDN;

  // ---- weights to bf16 ----
  cvt_w<<<(HIDN * FEAT / 4 + DD * HIDN / 4 + DD * DD / 4 + 255) / 256, 256, 0, stream>>>(
      w1, w2, cw, (unsigned short*)w1b, (unsigned short*)w2b, (unsigned short*)cwb);

  // ---- atomic-free CSR build ----
  histo_kernel<<<NCHUNK, 256, 0, stream>>>(ei, hist);
  scan_part<<<NPART, 256, 0, stream>>>(hist, NHIST, bsum);
  scan_mid<<<1, 1024, 0, stream>>>(bsum, NPART, boff, nullptr);
  scan_apply<<<NPART, 1024, 0, stream>>>(hist, boff, sc, NHIST);
  binscat_kernel<<<NCHUNK, 256, 0, stream>>>(ei, sc, pairsv);
  bucket_count<<<NBUCK, 256, 0, stream>>>(pairsv, sc, lofs, dinv, btot);
  scan_mid<<<1, 1024, 0, stream>>>(btot, NBUCK, bbase, indptr + NN);
  bucket_fill<<<NBUCK, 256, 0, stream>>>(pairsv, sc, lofs, bbase, csr, indptr);

  // ---- MLP: gemm1 (fused f32->bf16 A staging) + gemm2 ----
  gemm1f<<<dim3(HIDN / 128, MPAD / 128), 256, 0, stream>>>(feats, w1b, b1, hiddenb);
  gemm2<<<dim3(1, MPAD / 128), 256, 0, stream>>>((const short*)hiddenb, w2b, b2,
                                                 x + (size_t)NUSER * DD);
  // pad rows (region overlays hiddenb: after gemm2)
  hipMemsetAsync(hsba + (size_t)NN * DD, 0, DD * sizeof(unsigned short), stream);
  hipMemsetAsync(hsbb + (size_t)NN * DD, 0, DD * sizeof(unsigned short), stream);

  // ---- normalize + conv1 lin ----
  normalize_k<<<NN / 4, 256, 0, stream>>>(pref, x);
  lin_mfma<<<NN / 128, 256, 0, stream>>>(x, cwb, dinv, hsba);
  // ---- conv1 gather ----
  agg_kernel<0><<<NN / 4, 256, 0, stream>>>(hsba, dinv, indptr, csr, cb,
                                            nullptr, nullptr, hbuf, nullptr, nullptr);
  // ---- conv2 lin + gather + residual + pref tail ----
  lin_mfma<<<NN / 128, 256, 0, stream>>>(hbuf, cwb, dinv, hsbb);
  agg_kernel<1><<<NN / 4 + (NUSER * DD / 4 + 255) / 256, 256, 0, stream>>>(
      hsbb, dinv, indptr, csr, cb, x, hbuf, out, pref, out + (size_t)NN * DD);
}

// Round 8
// 234.967 us; speedup vs baseline: 3.4891x; 1.0803x over previous
//
#include <hip/hip_runtime.h>

#define NUSER 30000
#define NITEM 50000
#define NN    80000
#define NE    1200000
#define DD    64
#define FEAT  512
#define HIDN  256
#define MPAD  50048           // NITEM rounded up to 128 (grid sizing)
#define CSRCAP (NE + 8 * NN)  // padded CSR capacity (pad-to-8)

#define NBUCK  625            // dst >> 7 ; 625*128 == 80000 exactly
#define NCHUNK 256            // edge chunks for histogram/binscat
#define CHSZ   ((NE + NCHUNK - 1) / NCHUNK)   // 4688
#define NHIST  (NBUCK * NCHUNK)               // 160000
#define NPART  ((NHIST + 1023) / 1024)        // 157

using s16x8 = __attribute__((ext_vector_type(8))) short;
using f32x4 = __attribute__((ext_vector_type(4))) float;

__device__ __forceinline__ unsigned short f2bf(float f){
  unsigned int u = __float_as_uint(f);
  unsigned int r = (u + 0x7fffu + ((u >> 16) & 1u)) >> 16;
  return (unsigned short)r;
}

__device__ __forceinline__ float bf2f(unsigned short s){
  unsigned int u = ((unsigned int)s) << 16;
  return __uint_as_float(u);
}

__device__ __forceinline__ void gload_lds16(const void* g, void* l){
  __builtin_amdgcn_global_load_lds(
      (const __attribute__((address_space(1))) unsigned int*)g,
      (__attribute__((address_space(3))) unsigned int*)l, 16, 0, 0);
}

// ---------------- fp32 -> bf16 convert: w1 | w2 | cw | feats(+pad) in one launch ----------------
#define QW1 ((long)HIDN * FEAT / 4)
#define QW2 ((long)DD * HIDN / 4)
#define QCW ((long)DD * DD / 4)
#define QFI ((long)NITEM * FEAT / 4)
#define QFT ((long)MPAD * FEAT / 4)
__global__ __launch_bounds__(256) void cvt_all(const float* __restrict__ w1,
                                               const float* __restrict__ w2,
                                               const float* __restrict__ cw,
                                               const float* __restrict__ feats,
                                               unsigned short* __restrict__ w1b,
                                               unsigned short* __restrict__ w2b,
                                               unsigned short* __restrict__ cwb,
                                               unsigned short* __restrict__ featsb){
  const long ntot = QW1 + QW2 + QCW + QFT;
  for (long q = (long)blockIdx.x * blockDim.x + threadIdx.x; q < ntot;
       q += (long)gridDim.x * blockDim.x){
    const float4* src; ushort4* dst; long i; bool ok = true;
    if (q < QW1){ src = (const float4*)w1; dst = (ushort4*)w1b; i = q; }
    else if (q < QW1 + QW2){ src = (const float4*)w2; dst = (ushort4*)w2b; i = q - QW1; }
    else if (q < QW1 + QW2 + QCW){ src = (const float4*)cw; dst = (ushort4*)cwb; i = q - QW1 - QW2; }
    else { src = (const float4*)feats; dst = (ushort4*)featsb; i = q - QW1 - QW2 - QCW; ok = (i < QFI); }
    float4 v = make_float4(0.f, 0.f, 0.f, 0.f);
    if (ok) v = src[i];
    ushort4 o = { f2bf(v.x), f2bf(v.y), f2bf(v.z), f2bf(v.w) };
    dst[i] = o;
  }
}

// ---------------- MFMA GEMM (R2-proven): C[M,N] = A[Mpad,K]_bf16 @ B[N,K]_bf16^T + bias ----------------
// BM=128, BK=32, 4 waves (2x2), A+B via global_load_lds width 16, 2-barrier K-loop.
template<int BN, int ACT, int OUT_BF16>
__global__ __launch_bounds__(256) void gemm_mfma(const short* __restrict__ Ag,
                                                 const short* __restrict__ Bg,
                                                 const float* __restrict__ bias,
                                                 void* __restrict__ Cout,
                                                 int M, int K, int ldc){
  constexpr int BM = 128;
  constexpr int BK = 32;
  constexpr int NFRAG = BN / 32;
  __shared__ __align__(16) short As[BM * BK];
  __shared__ __align__(16) short Bs[BN * BK];

  const int tid  = threadIdx.x;
  const int wid  = tid >> 6;
  const int lane = tid & 63;
  const int wr   = wid >> 1;
  const int wc   = wid & 1;
  const int m0   = blockIdx.y * BM;
  const int n0   = blockIdx.x * BN;

  f32x4 acc[4][NFRAG] = {};

  for (int k0 = 0; k0 < K; k0 += BK){
    #pragma unroll
    for (int s = 0; s < 2; s++){
      int q = s * 256 + tid;
      int row = q >> 2, kc = q & 3;
      const short* src = Ag + (size_t)(m0 + row) * K + k0 + kc * 8;
      gload_lds16(src, &As[(size_t)(s * 256 + wid * 64) * 8]);
    }
    #pragma unroll
    for (int s = 0; s < BN / 64; s++){
      int q = s * 256 + tid;
      int row = q >> 2, kc = q & 3;
      const short* src = Bg + (size_t)(n0 + row) * K + k0 + kc * 8;
      gload_lds16(src, &Bs[(size_t)(s * 256 + wid * 64) * 8]);
    }
    __syncthreads();

    s16x8 af[4], bf[NFRAG];
    #pragma unroll
    for (int m = 0; m < 4; m++)
      af[m] = *(const s16x8*)&As[(wr * 64 + m * 16 + (lane & 15)) * BK + (lane >> 4) * 8];
    #pragma unroll
    for (int n = 0; n < NFRAG; n++)
      bf[n] = *(const s16x8*)&Bs[(wc * (BN / 2) + n * 16 + (lane & 15)) * BK + (lane >> 4) * 8];
    #pragma unroll
    for (int m = 0; m < 4; m++)
      #pragma unroll
      for (int n = 0; n < NFRAG; n++)
        acc[m][n] = __builtin_amdgcn_mfma_f32_16x16x32_bf16(af[m], bf[n], acc[m][n], 0, 0, 0);
    __syncthreads();
  }

  #pragma unroll
  for (int m = 0; m < 4; m++){
    int row_base = m0 + wr * 64 + m * 16 + (lane >> 4) * 4;
    #pragma unroll
    for (int n = 0; n < NFRAG; n++){
      int col = n0 + wc * (BN / 2) + n * 16 + (lane & 15);
      float bi = bias[col];
      #pragma unroll
      for (int r = 0; r < 4; r++){
        int row = row_base + r;
        if (row >= M) continue;
        float v = acc[m][n][r] + bi;
        if (ACT) v = v > 0.f ? v : 0.01f * v;
        if (OUT_BF16) ((unsigned short*)Cout)[(size_t)row * ldc + col] = f2bf(v);
        else          ((float*)Cout)[(size_t)row * ldc + col] = v;
      }
    }
  }
}

// ================= atomic-free CSR build =================
__global__ __launch_bounds__(256) void histo_kernel(const int* __restrict__ ei,
                                                    int* __restrict__ hist){
  __shared__ int h[NBUCK];
  const int tid = threadIdx.x, c = blockIdx.x;
  for (int i = tid; i < NBUCK; i += 256) h[i] = 0;
  __syncthreads();
  int e0 = c * CHSZ, e1 = min(e0 + CHSZ, NE);
  for (int e = e0 + tid; e < e1; e += 256)
    atomicAdd(&h[ei[NE + e] >> 7], 1);
  __syncthreads();
  for (int i = tid; i < NBUCK; i += 256) hist[i * NCHUNK + c] = h[i];
}

__global__ __launch_bounds__(256) void scan_part(const int* __restrict__ a, int n,
                                                 int* __restrict__ bsum){
  __shared__ int ws4[4];
  int b = blockIdx.x, base = b * 1024;
  int v = 0;
  #pragma unroll
  for (int s = 0; s < 4; s++){
    int idx = base + s * 256 + threadIdx.x;
    if (idx < n) v += a[idx];
  }
  int lane = threadIdx.x & 63, w = threadIdx.x >> 6;
  #pragma unroll
  for (int o = 1; o < 64; o <<= 1) v += __shfl_xor(v, o);
  if (lane == 0) ws4[w] = v;
  __syncthreads();
  if (threadIdx.x == 0) bsum[b] = ws4[0] + ws4[1] + ws4[2] + ws4[3];
}

__global__ __launch_bounds__(1024) void scan_mid(const int* __restrict__ a, int np,
                                                 int* __restrict__ excl_out,
                                                 int* __restrict__ total_out){
  __shared__ int wsum[16];
  int tid = threadIdx.x;
  int v = (tid < np) ? a[tid] : 0;
  int lane = tid & 63, w = tid >> 6;
  int incl = v;
  #pragma unroll
  for (int o = 1; o < 64; o <<= 1){ int u = __shfl_up(incl, o); if (lane >= o) incl += u; }
  if (lane == 63) wsum[w] = incl;
  __syncthreads();
  int woff = 0;
  #pragma unroll
  for (int k = 0; k < 16; k++) if (k < w) woff += wsum[k];
  if (tid < np) excl_out[tid] = woff + incl - v;
  if (total_out && tid == 1023) *total_out = woff + incl;
}

__global__ __launch_bounds__(1024) void scan_apply(const int* __restrict__ a,
                                                   const int* __restrict__ boff,
                                                   int* __restrict__ sc, int n){
  __shared__ int wsum[16];
  int b = blockIdx.x, tid = threadIdx.x;
  int idx = b * 1024 + tid;
  int v = (idx < n) ? a[idx] : 0;
  int lane = tid & 63, w = tid >> 6;
  int incl = v;
  #pragma unroll
  for (int o = 1; o < 64; o <<= 1){ int u = __shfl_up(incl, o); if (lane >= o) incl += u; }
  if (lane == 63) wsum[w] = incl;
  __syncthreads();
  int woff = 0;
  #pragma unroll
  for (int k = 0; k < 16; k++) if (k < w) woff += wsum[k];
  if (idx < n) sc[idx] = boff[b] + woff + incl - v;
}

__global__ __launch_bounds__(256) void binscat_kernel(const int* __restrict__ ei,
                                                      const int* __restrict__ sc,
                                                      int* __restrict__ pairsv){
  __shared__ int cur[NBUCK];
  const int tid = threadIdx.x, c = blockIdx.x;
  for (int i = tid; i < NBUCK; i += 256) cur[i] = sc[i * NCHUNK + c];
  __syncthreads();
  int e0 = c * CHSZ, e1 = min(e0 + CHSZ, NE);
  for (int e = e0 + tid; e < e1; e += 256){
    int s = ei[e];
    int d = ei[NE + e];
    int pos = atomicAdd(&cur[d >> 7], 1);
    pairsv[pos] = ((d & 127) << 17) | s;
  }
}

__global__ __launch_bounds__(256) void bucket_count(const int* __restrict__ pairsv,
                                                    const int* __restrict__ sc,
                                                    int* __restrict__ lofs,
                                                    float* __restrict__ dinv,
                                                    int* __restrict__ btot){
  __shared__ int cnt[128];
  __shared__ int wtot;
  const int tid = threadIdx.x, b = blockIdx.x;
  if (tid < 128) cnt[tid] = 0;
  __syncthreads();
  int e0 = sc[b * NCHUNK];
  int e1 = (b == NBUCK - 1) ? NE : sc[(b + 1) * NCHUNK];
  for (int e = e0 + tid; e < e1; e += 256)
    atomicAdd(&cnt[(pairsv[e] >> 17) & 127], 1);
  __syncthreads();
  int lane = tid & 63;
  int incl = 0, pc = 0;
  if (tid < 128){
    pc = (cnt[tid] + 8) & ~7;        // deg + 1 self, padded to x8
    incl = pc;
    #pragma unroll
    for (int o = 1; o < 64; o <<= 1){ int u = __shfl_up(incl, o); if (lane >= o) incl += u; }
  }
  if (tid == 63) wtot = incl;
  __syncthreads();
  if (tid < 128){
    int excl = incl - pc + (tid >= 64 ? wtot : 0);
    int node = b * 128 + tid;
    lofs[node] = excl;
    dinv[node] = rsqrtf((float)(cnt[tid] + 1));
    if (tid == 127) btot[b] = excl + pc;
  }
}

__global__ __launch_bounds__(256) void bucket_fill(const int* __restrict__ pairsv,
                                                   const int* __restrict__ sc,
                                                   const int* __restrict__ lofs,
                                                   const int* __restrict__ bbase,
                                                   int* __restrict__ csr,
                                                   int* __restrict__ indptr){
  __shared__ int cur[128], l0[128];
  const int tid = threadIdx.x, b = blockIdx.x;
  const int base = bbase[b];
  if (tid < 128){
    int v = lofs[b * 128 + tid];
    cur[tid] = v; l0[tid] = v;
  }
  __syncthreads();
  int e0 = sc[b * NCHUNK];
  int e1 = (b == NBUCK - 1) ? NE : sc[(b + 1) * NCHUNK];
  for (int e = e0 + tid; e < e1; e += 256){
    int v = pairsv[e];
    int li = (v >> 17) & 127;
    int p = atomicAdd(&cur[li], 1);
    csr[base + p] = v & 0x1FFFF;
  }
  __syncthreads();
  if (tid < 128){
    int node = b * 128 + tid;
    int c = cur[tid];                 // l0 + deg
    int l = l0[tid];
    int end = l + ((c - l + 8) & ~7); // l + padded count (pad-to-8)
    csr[base + c] = node;             // self-loop
    for (int q = c + 1; q < end; q++) csr[base + q] = NN;   // pads -> zero row
    indptr[node] = base + l;
  }
}

// ---------------- normalize rows of x (users from pref, items from gemm2) ----------------
__global__ __launch_bounds__(256) void normalize_k(const float* __restrict__ pref,
                                                   float* __restrict__ x){
  int node = blockIdx.x * 4 + (threadIdx.x >> 6);
  int lane = threadIdx.x & 63;
  float v = (node < NUSER) ? pref[(size_t)node * DD + lane] : x[(size_t)node * DD + lane];
  float ss = v * v;
  #pragma unroll
  for (int o = 1; o < 64; o <<= 1) ss += __shfl_xor(ss, o);
  v = v / fmaxf(sqrtf(ss), 1e-12f);
  x[(size_t)node * DD + lane] = v;
}

// ---------------- lin via MFMA: hsb = bf16(dinv[row] * (src @ cwb^T)) ----------------
__global__ __launch_bounds__(256) void lin_mfma(const float* __restrict__ src,
                                                const short* __restrict__ cwb,
                                                const float* __restrict__ dinv,
                                                unsigned short* __restrict__ hsb){
  constexpr int AP = 72;                        // padded stride (elems)
  __shared__ __align__(16) short As[128 * AP];  // 18KB

  const int tid  = threadIdx.x;
  const int wid  = tid >> 6;
  const int lane = tid & 63;
  const int wr   = wid >> 1;
  const int wc   = wid & 1;
  const int m0   = blockIdx.x * 128;

  // stage A: 128x64 f32 = 2048 float4, 8/thread
  #pragma unroll
  for (int s = 0; s < 8; s++){
    int c = s * 256 + tid;
    int row = c >> 4, kc = c & 15;              // 16 float4 per 64-f32 row
    float4 v = *(const float4*)&src[(size_t)(m0 + row) * DD + kc * 4];
    ushort4 o = { f2bf(v.x), f2bf(v.y), f2bf(v.z), f2bf(v.w) };
    *(ushort4*)&As[row * AP + kc * 4] = o;
  }
  __syncthreads();

  f32x4 acc[4][2] = {};
  #pragma unroll
  for (int kk = 0; kk < DD; kk += 32){
    s16x8 af[4], bf[2];
    #pragma unroll
    for (int m = 0; m < 4; m++)
      af[m] = *(const s16x8*)&As[(wr * 64 + m * 16 + (lane & 15)) * AP + kk + (lane >> 4) * 8];
    #pragma unroll
    for (int n = 0; n < 2; n++)
      bf[n] = *(const s16x8*)&cwb[(size_t)(wc * 32 + n * 16 + (lane & 15)) * DD + kk + (lane >> 4) * 8];
    #pragma unroll
    for (int m = 0; m < 4; m++)
      #pragma unroll
      for (int n = 0; n < 2; n++)
        acc[m][n] = __builtin_amdgcn_mfma_f32_16x16x32_bf16(af[m], bf[n], acc[m][n], 0, 0, 0);
  }

  #pragma unroll
  for (int m = 0; m < 4; m++){
    int row_base = m0 + wr * 64 + m * 16 + (lane >> 4) * 4;
    #pragma unroll
    for (int n = 0; n < 2; n++){
      int col = wc * 32 + n * 16 + (lane & 15);
      #pragma unroll
      for (int r = 0; r < 4; r++){
        int row = row_base + r;
        hsb[(size_t)row * DD + col] = f2bf(dinv[row] * acc[m][n][r]);
      }
    }
  }
}

// ---------------- gather aggregation: 8 edges in flight, 8 lanes x s16x8 (bf16 rows) ----------------
template<int FINAL>
__global__ __launch_bounds__(256) void agg_kernel(const unsigned short* __restrict__ hsb,
                                                  const float* __restrict__ dinv,
                                                  const int* __restrict__ indptr,
                                                  const int* __restrict__ csr,
                                                  const float* __restrict__ bias,
                                                  const float* __restrict__ x,
                                                  const float* __restrict__ h,
                                                  float* __restrict__ out,
                                                  const float* __restrict__ pref,
                                                  float* __restrict__ out2){
  int b = blockIdx.x;
  if (FINAL && b >= NN / 4){
    long q = (long)(b - NN / 4) * 256 + threadIdx.x;
    if (q < (long)NUSER * DD / 4)
      ((float4*)out2)[q] = ((const float4*)pref)[q];
    return;
  }
  int node = b * 4 + (threadIdx.x >> 6);
  int lane = threadIdx.x & 63;
  int g  = lane >> 3;          // edge group 0..7
  int sl = lane & 7;           // 8 lanes x 8 bf16 (16B) = one 64-elem row
  int e0 = indptr[node];
  int nit = (indptr[node + 1] - e0) >> 3;
  float a0=0.f,a1=0.f,a2=0.f,a3=0.f,a4=0.f,a5=0.f,a6=0.f,a7=0.f;
  int k = e0 + g;
  for (int i = 0; i < nit; i++){
    int j = csr[k];
    k += 8;
    s16x8 v = *(const s16x8*)&hsb[(size_t)j * DD + sl * 8];
    a0 += bf2f((unsigned short)v[0]); a1 += bf2f((unsigned short)v[1]);
    a2 += bf2f((unsigned short)v[2]); a3 += bf2f((unsigned short)v[3]);
    a4 += bf2f((unsigned short)v[4]); a5 += bf2f((unsigned short)v[5]);
    a6 += bf2f((unsigned short)v[6]); a7 += bf2f((unsigned short)v[7]);
  }
  #pragma unroll
  for (int off = 8; off < 64; off <<= 1){
    a0 += __shfl_xor(a0, off); a1 += __shfl_xor(a1, off);
    a2 += __shfl_xor(a2, off); a3 += __shfl_xor(a3, off);
    a4 += __shfl_xor(a4, off); a5 += __shfl_xor(a5, off);
    a6 += __shfl_xor(a6, off); a7 += __shfl_xor(a7, off);
  }
  if (g == 0){
    float di = dinv[node];
    size_t rb = (size_t)node * DD + sl * 8;
    const float4 bi0 = *(const float4*)&bias[sl * 8];
    const float4 bi1 = *(const float4*)&bias[sl * 8 + 4];
    float4 r0, r1;
    r0.x = fmaf(di, a0, bi0.x); r0.y = fmaf(di, a1, bi0.y);
    r0.z = fmaf(di, a2, bi0.z); r0.w = fmaf(di, a3, bi0.w);
    r1.x = fmaf(di, a4, bi1.x); r1.y = fmaf(di, a5, bi1.y);
    r1.z = fmaf(di, a6, bi1.z); r1.w = fmaf(di, a7, bi1.w);
    if (FINAL){
      const float4 xv0 = *(const float4*)&x[rb];
      const float4 xv1 = *(const float4*)&x[rb + 4];
      const float4 hv0 = *(const float4*)&h[rb];
      const float4 hv1 = *(const float4*)&h[rb + 4];
      r0.x += xv0.x + hv0.x; r0.y += xv0.y + hv0.y;
      r0.z += xv0.z + hv0.z; r0.w += xv0.w + hv0.w;
      r1.x += xv1.x + hv1.x; r1.y += xv1.y + hv1.y;
      r1.z += xv1.z + hv1.z; r1.w += xv1.w + hv1.w;
    }
    *(float4*)&out[rb] = r0;
    *(float4*)&out[rb + 4] = r1;
  }
}

extern "C" void kernel_launch(void* const* d_in, const int* in_sizes, int n_in,
                              void* d_out, int out_size, void* d_ws, size_t ws_size,
                              hipStream_t stream){
  const int*   ei    = (const int*)  d_in[0];
  const float* feats = (const float*)d_in[1];
  const float* pref  = (const float*)d_in[2];
  const float* w1    = (const float*)d_in[3];
  const float* b1    = (const float*)d_in[4];
  const float* w2    = (const float*)d_in[5];
  const float* b2    = (const float*)d_in[6];
  const float* cw    = (const float*)d_in[7];
  const float* cb    = (const float*)d_in[8];
  float* out = (float*)d_out;

  // ---- workspace layout (lifetime-overlapped; peak ~77.2MB, proven) ----
  // [0, 51.25MB)  featsb bf16 [MPAD*512] (dead after gemm1), overlaid afterwards by:
  //    x    [0, 20.48MB)
  //    hbuf [20.48, 40.96MB)  -- CSR-build scratch overlays it
  //    [40.96, ~49.3MB) live graph: csr[CSRCAP] | indptr | dinv | lofs
  // [51.25, 76.9MB)  hiddenb bf16 [MPAD*256] (dead after gemm2), overlaid by hsb_a | hsb_b
  // [76.9MB, ...)    w1b, w2b, cwb bf16
  char* wsb = (char*)d_ws;
  short* featsb  = (short*)wsb;
  float* x       = (float*)wsb;
  float* hbuf    = (float*)(wsb + (size_t)NN * DD * 4);
  int*   pairsv  = (int*)hbuf;
  int*   hist    = pairsv + NE;
  int*   sc      = hist + NHIST;
  int*   bsum    = sc + NHIST;
  int*   boff    = bsum + NPART;
  int*   btot    = boff + NPART;
  int*   bbase   = btot + NBUCK;
  char*  graphb  = wsb + (size_t)NN * DD * 8;
  int*   csr     = (int*)graphb;
  int*   indptr  = csr + CSRCAP;
  float* dinv    = (float*)(indptr + NN + 1);
  int*   lofs    = (int*)(dinv + NN);
  unsigned short* hiddenb = (unsigned short*)(wsb + (size_t)MPAD * FEAT * 2);
  unsigned short* hsba = hiddenb;
  unsigned short* hsbb = hsba + (size_t)(NN + 1) * DD;
  short* w1b     = (short*)(wsb + (size_t)MPAD * FEAT * 2 + (size_t)(MPAD + 64) * HIDN * 2);
  short* w2b     = w1b + (size_t)HIDN * FEAT;
  short* cwb     = w2b + (size_t)DD * HIDN;

  // ---- bf16 conversions (one streaming launch: w1|w2|cw|feats) ----
  cvt_all<<<2048, 256, 0, stream>>>(w1, w2, cw, feats, (unsigned short*)w1b,
                                    (unsigned short*)w2b, (unsigned short*)cwb,
                                    (unsigned short*)featsb);

  // ---- MLP: gemm1 (bf16 A via global_load_lds) + gemm2 ----
  gemm_mfma<128, 1, 1><<<dim3(HIDN / 128, MPAD / 128), 256, 0, stream>>>(
      featsb, w1b, b1, hiddenb, NITEM, FEAT, HIDN);
  gemm_mfma<64, 0, 0><<<dim3(1, MPAD / 128), 256, 0, stream>>>(
      (const short*)hiddenb, w2b, b2, x + (size_t)NUSER * DD, NITEM, HIDN, DD);
  // pad rows (region overlays hiddenb: after gemm2)
  hipMemsetAsync(hsba + (size_t)NN * DD, 0, DD * sizeof(unsigned short), stream);
  hipMemsetAsync(hsbb + (size_t)NN * DD, 0, DD * sizeof(unsigned short), stream);

  // ---- atomic-free CSR build (regions overlay featsb: after gemm1) ----
  histo_kernel<<<NCHUNK, 256, 0, stream>>>(ei, hist);
  scan_part<<<NPART, 256, 0, stream>>>(hist, NHIST, bsum);
  scan_mid<<<1, 1024, 0, stream>>>(bsum, NPART, boff, nullptr);
  scan_apply<<<NPART, 1024, 0, stream>>>(hist, boff, sc, NHIST);
  binscat_kernel<<<NCHUNK, 256, 0, stream>>>(ei, sc, pairsv);
  bucket_count<<<NBUCK, 256, 0, stream>>>(pairsv, sc, lofs, dinv, btot);
  scan_mid<<<1, 1024, 0, stream>>>(btot, NBUCK, bbase, indptr + NN);
  bucket_fill<<<NBUCK, 256, 0, stream>>>(pairsv, sc, lofs, bbase, csr, indptr);

  // ---- normalize + conv1 lin ----
  normalize_k<<<NN / 4, 256, 0, stream>>>(pref, x);
  lin_mfma<<<NN / 128, 256, 0, stream>>>(x, cwb, dinv, hsba);
  // ---- conv1 gather ----
  agg_kernel<0><<<NN / 4, 256, 0, stream>>>(hsba, dinv, indptr, csr, cb,
                                            nullptr, nullptr, hbuf, nullptr, nullptr);
  // ---- conv2 lin + gather + residual + pref tail ----
  lin_mfma<<<NN / 128, 256, 0, stream>>>(hbuf, cwb, dinv, hsbb);
  agg_kernel<1><<<NN / 4 + (NUSER * DD / 4 + 255) / 256, 256, 0, stream>>>(
      hsbb, dinv, indptr, csr, cb, x, hbuf, out, pref, out + (size_t)NN * DD);
}

// Round 9
// 206.792 us; speedup vs baseline: 3.9645x; 1.1362x over previous
//
#include <hip/hip_runtime.h>

#define NUSER 30000
#define NITEM 50000
#define NN    80000
#define NE    1200000
#define DD    64
#define FEAT  512
#define HIDN  256
#define MPAD  50048           // NITEM rounded up to 128 (grid sizing)

#define NBUCK  625            // dst >> 7 ; 625*128 == 80000 exactly
#define NCHUNK 256            // edge chunks for histogram/binscat
#define CHSZ   ((NE + NCHUNK - 1) / NCHUNK)   // 4688
#define NHIST  (NBUCK * NCHUNK)               // 160000
#define NPART  ((NHIST + 1023) / 1024)        // 157
#define CSRCAP (NE + 1024 * NBUCK)            // fixed-capacity bucket layout (1.84M)

#define G1_BLOCKS  (2 * (MPAD / 128))         // 782 (bx in 0..1, by in 0..390)
#define G2_BLOCKS  (MPAD / 128)               // 391
#define CVTW_BLOCKS ((HIDN * FEAT / 4 + DD * HIDN / 4 + DD * DD / 4) / 256) // 148

using s16x8 = __attribute__((ext_vector_type(8))) short;
using f32x4 = __attribute__((ext_vector_type(4))) float;
using u32x4 = __attribute__((ext_vector_type(4))) unsigned int;

__device__ __forceinline__ unsigned short f2bf(float f){
  unsigned int u = __float_as_uint(f);
  unsigned int r = (u + 0x7fffu + ((u >> 16) & 1u)) >> 16;
  return (unsigned short)r;
}

__device__ __forceinline__ float bf2f(unsigned short s){
  unsigned int u = ((unsigned int)s) << 16;
  return __uint_as_float(u);
}

// packed f32x2 -> bf16x2 (RNE), gfx950 HW cvt [T12/m240]
__device__ __forceinline__ unsigned int cvtpk(float lo, float hi){
  unsigned int r;
  asm("v_cvt_pk_bf16_f32 %0, %1, %2" : "=v"(r) : "v"(lo), "v"(hi));
  return r;
}

__device__ __forceinline__ void gload_lds16(const void* g, void* l){
  __builtin_amdgcn_global_load_lds(
      (const __attribute__((address_space(1))) unsigned int*)g,
      (__attribute__((address_space(3))) unsigned int*)l, 16, 0, 0);
}

// ================= device bodies (packed kernels call these) =================

// ---- histo: per-chunk LDS histogram over 625 dst-buckets ----
__device__ __forceinline__ void dev_histo(int c, const int* __restrict__ ei,
                                          int* __restrict__ hist, int* h){
  const int tid = threadIdx.x;
  for (int i = tid; i < NBUCK; i += 256) h[i] = 0;
  __syncthreads();
  int e0 = c * CHSZ, e1 = min(e0 + CHSZ, NE);
  for (int e = e0 + tid; e < e1; e += 256)
    atomicAdd(&h[ei[NE + e] >> 7], 1);
  __syncthreads();
  for (int i = tid; i < NBUCK; i += 256) hist[i * NCHUNK + c] = h[i];
}

// ---- weights fp32 -> bf16 ----
__device__ __forceinline__ void dev_cvtw(int blk,
    const float* __restrict__ w1, const float* __restrict__ w2, const float* __restrict__ cw,
    unsigned short* __restrict__ w1b, unsigned short* __restrict__ w2b,
    unsigned short* __restrict__ cwb){
  const int n1 = HIDN * FEAT / 4, n2 = DD * HIDN / 4, n3 = DD * DD / 4;
  int q = blk * 256 + threadIdx.x;
  const float4* src; ushort4* dst; int i;
  if (q < n1){ src = (const float4*)w1; dst = (ushort4*)w1b; i = q; }
  else if (q < n1 + n2){ src = (const float4*)w2; dst = (ushort4*)w2b; i = q - n1; }
  else if (q < n1 + n2 + n3){ src = (const float4*)cw; dst = (ushort4*)cwb; i = q - n1 - n2; }
  else return;
  float4 v = src[i];
  ushort4 o = { f2bf(v.x), f2bf(v.y), f2bf(v.z), f2bf(v.w) };
  dst[i] = o;
}

// ---- GEMM1: hiddenb = bf16(leaky(feats_f32 @ w1b^T + b1)) ----
// A staged f32 via global_load_lds with XOR-swizzled SOURCE chunk (kc^(row&7)),
// linear LDS dest; un-XOR on read; cvt_pk to bf16 at fragment time.
__device__ __forceinline__ void dev_gemm1(int bx, int by,
    const float* __restrict__ feats, const short* __restrict__ w1b,
    const float* __restrict__ b1, unsigned short* __restrict__ hiddenb,
    float* Asf, short* Bs){
  const int tid  = threadIdx.x;
  const int wid  = tid >> 6;
  const int lane = tid & 63;
  const int wr   = wid >> 1;
  const int wc   = wid & 1;
  const int m0   = by * 128;
  const int n0   = bx * 128;

  f32x4 acc[4][4] = {};

  for (int k0 = 0; k0 < FEAT; k0 += 32){
    // A: 128 rows x 32 f32 = 1024 x 16B chunks, 4 issues; swizzled global source
    #pragma unroll
    for (int s = 0; s < 4; s++){
      int q = s * 256 + tid;
      int row = q >> 3, kc = q & 7;
      int gr = m0 + row; if (gr >= NITEM) gr = NITEM - 1;   // clamp tail (stores masked)
      int kcs = kc ^ (row & 7);
      const float* src = &feats[(size_t)gr * FEAT + k0 + kcs * 4];
      gload_lds16(src, Asf + (size_t)(s * 256 + wid * 64) * 4);
    }
    // B: w1 tile 128x32 bf16, 2 issues
    #pragma unroll
    for (int s = 0; s < 2; s++){
      int q = s * 256 + tid;
      int row = q >> 2, kc = q & 3;
      const short* src = w1b + (size_t)(n0 + row) * FEAT + k0 + kc * 8;
      gload_lds16(src, Bs + (size_t)(s * 256 + wid * 64) * 8);
    }
    __syncthreads();

    s16x8 af[4], bf[4];
    #pragma unroll
    for (int m = 0; m < 4; m++){
      int r  = wr * 64 + m * 16 + (lane & 15);
      int c0 = (lane >> 4) * 2;
      const float4 v0 = *(const float4*)&Asf[r * 32 + ((c0    ) ^ (r & 7)) * 4];
      const float4 v1 = *(const float4*)&Asf[r * 32 + ((c0 + 1) ^ (r & 7)) * 4];
      u32x4 t;
      t[0] = cvtpk(v0.x, v0.y); t[1] = cvtpk(v0.z, v0.w);
      t[2] = cvtpk(v1.x, v1.y); t[3] = cvtpk(v1.z, v1.w);
      af[m] = *(s16x8*)&t;
    }
    #pragma unroll
    for (int n = 0; n < 4; n++)
      bf[n] = *(const s16x8*)&Bs[(wc * 64 + n * 16 + (lane & 15)) * 32 + (lane >> 4) * 8];
    #pragma unroll
    for (int m = 0; m < 4; m++)
      #pragma unroll
      for (int n = 0; n < 4; n++)
        acc[m][n] = __builtin_amdgcn_mfma_f32_16x16x32_bf16(af[m], bf[n], acc[m][n], 0, 0, 0);
    __syncthreads();
  }

  #pragma unroll
  for (int m = 0; m < 4; m++){
    int row_base = m0 + wr * 64 + m * 16 + (lane >> 4) * 4;
    #pragma unroll
    for (int n = 0; n < 4; n++){
      int col = n0 + wc * 64 + n * 16 + (lane & 15);
      float bi = b1[col];
      #pragma unroll
      for (int r = 0; r < 4; r++){
        int row = row_base + r;
        if (row >= NITEM) continue;
        float v = acc[m][n][r] + bi;
        v = v > 0.f ? v : 0.01f * v;
        hiddenb[(size_t)row * HIDN + col] = f2bf(v);
      }
    }
  }
}

// ---- scan_apply, 256-thread version (4 elems/thread) ----
__device__ __forceinline__ void dev_scan_apply4(int blk, const int* __restrict__ a,
                                                const int* __restrict__ boff,
                                                int* __restrict__ sc, int* wsum4){
  int tid = threadIdx.x;
  int base = blk * 1024 + tid * 4;
  int v0 = (base + 0 < NHIST) ? a[base + 0] : 0;
  int v1 = (base + 1 < NHIST) ? a[base + 1] : 0;
  int v2 = (base + 2 < NHIST) ? a[base + 2] : 0;
  int v3 = (base + 3 < NHIST) ? a[base + 3] : 0;
  int s = v0 + v1 + v2 + v3;
  int lane = tid & 63, w = tid >> 6;
  int incl = s;
  #pragma unroll
  for (int o = 1; o < 64; o <<= 1){ int u = __shfl_up(incl, o); if (lane >= o) incl += u; }
  if (lane == 63) wsum4[w] = incl;
  __syncthreads();
  int woff = 0;
  #pragma unroll
  for (int k = 0; k < 4; k++) if (k < w) woff += wsum4[k];
  int excl = boff[blk] + woff + incl - s;
  if (base + 0 < NHIST) sc[base + 0] = excl; excl += v0;
  if (base + 1 < NHIST) sc[base + 1] = excl; excl += v1;
  if (base + 2 < NHIST) sc[base + 2] = excl; excl += v2;
  if (base + 3 < NHIST) sc[base + 3] = excl;
}

// ---- GEMM2: x items = hiddenb @ w2b^T + b2 (f32 out) ----
__device__ __forceinline__ void dev_gemm2(int by,
    const short* __restrict__ Ag, const short* __restrict__ Bg,
    const float* __restrict__ bias, float* __restrict__ Cout,
    short* As, short* Bs){
  const int tid  = threadIdx.x;
  const int wid  = tid >> 6;
  const int lane = tid & 63;
  const int wr   = wid >> 1;
  const int wc   = wid & 1;
  const int m0   = by * 128;

  f32x4 acc[4][2] = {};

  for (int k0 = 0; k0 < HIDN; k0 += 32){
    #pragma unroll
    for (int s = 0; s < 2; s++){
      int q = s * 256 + tid;
      int row = q >> 2, kc = q & 3;
      const short* src = Ag + (size_t)(m0 + row) * HIDN + k0 + kc * 8;
      gload_lds16(src, As + (size_t)(s * 256 + wid * 64) * 8);
    }
    {
      int row = tid >> 2, kc = tid & 3;
      const short* src = Bg + (size_t)row * HIDN + k0 + kc * 8;
      gload_lds16(src, Bs + (size_t)(wid * 64) * 8);
    }
    __syncthreads();

    s16x8 af[4], bf[2];
    #pragma unroll
    for (int m = 0; m < 4; m++)
      af[m] = *(const s16x8*)&As[(wr * 64 + m * 16 + (lane & 15)) * 32 + (lane >> 4) * 8];
    #pragma unroll
    for (int n = 0; n < 2; n++)
      bf[n] = *(const s16x8*)&Bs[(wc * 32 + n * 16 + (lane & 15)) * 32 + (lane >> 4) * 8];
    #pragma unroll
    for (int m = 0; m < 4; m++)
      #pragma unroll
      for (int n = 0; n < 2; n++)
        acc[m][n] = __builtin_amdgcn_mfma_f32_16x16x32_bf16(af[m], bf[n], acc[m][n], 0, 0, 0);
    __syncthreads();
  }

  #pragma unroll
  for (int m = 0; m < 4; m++){
    int row_base = m0 + wr * 64 + m * 16 + (lane >> 4) * 4;
    #pragma unroll
    for (int n = 0; n < 2; n++){
      int col = wc * 32 + n * 16 + (lane & 15);
      float bi = bias[col];
      #pragma unroll
      for (int r = 0; r < 4; r++){
        int row = row_base + r;
        if (row >= NITEM) continue;
        Cout[(size_t)row * DD + col] = acc[m][n][r] + bi;
      }
    }
  }
}

// ---- binscat: LDS-cursor scatter of packed (dst&127)<<17 | src ----
__device__ __forceinline__ void dev_binscat(int c, const int* __restrict__ ei,
                                            const int* __restrict__ sc,
                                            int* __restrict__ pairsv, int* cur){
  const int tid = threadIdx.x;
  for (int i = tid; i < NBUCK; i += 256) cur[i] = sc[i * NCHUNK + c];
  __syncthreads();
  int e0 = c * CHSZ, e1 = min(e0 + CHSZ, NE);
  for (int e = e0 + tid; e < e1; e += 256){
    int s = ei[e];
    int d = ei[NE + e];
    int pos = atomicAdd(&cur[d >> 7], 1);
    pairsv[pos] = ((d & 127) << 17) | s;
  }
}

// ---- bucketize (fused count + scan + fill): fixed base = sc[b*NCHUNK] + 1024*b ----
__device__ __forceinline__ void dev_bucketize(int b,
    const int* __restrict__ pairsv, const int* __restrict__ sc,
    float* __restrict__ dinv, int* __restrict__ csr,
    int* __restrict__ indptr, int* __restrict__ nitv,
    int* cnt, int* cur, int* l0, int* wtot){
  const int tid = threadIdx.x;
  if (tid < 128) cnt[tid] = 0;
  __syncthreads();
  int e0 = sc[b * NCHUNK];
  int e1 = (b == NBUCK - 1) ? NE : sc[(b + 1) * NCHUNK];
  for (int e = e0 + tid; e < e1; e += 256)
    atomicAdd(&cnt[(pairsv[e] >> 17) & 127], 1);
  __syncthreads();
  int lane = tid & 63;
  int incl = 0, pc = 0, cdeg = 0;
  if (tid < 128){
    cdeg = cnt[tid];
    pc = (cdeg + 8) & ~7;            // deg + 1 self, padded to x8
    incl = pc;
    #pragma unroll
    for (int o = 1; o < 64; o <<= 1){ int u = __shfl_up(incl, o); if (lane >= o) incl += u; }
  }
  if (tid == 63) *wtot = incl;
  __syncthreads();
  if (tid < 128){
    int excl = incl - pc + (tid >= 64 ? *wtot : 0);
    cur[tid] = excl; l0[tid] = excl;
    dinv[b * 128 + tid] = rsqrtf((float)(cdeg + 1));
  }
  __syncthreads();
  const int base = e0 + 1024 * b;
  for (int e = e0 + tid; e < e1; e += 256){
    int v = pairsv[e];
    int li = (v >> 17) & 127;
    int p = atomicAdd(&cur[li], 1);
    csr[base + p] = v & 0x1FFFF;
  }
  __syncthreads();
  if (tid < 128){
    int node = b * 128 + tid;
    int c = cur[tid];                 // l0 + deg
    int l = l0[tid];
    int end = l + ((c - l + 8) & ~7);
    csr[base + c] = node;             // self-loop
    for (int q = c + 1; q < end; q++) csr[base + q] = NN;   // pads -> zero row
    indptr[node] = base + l;
    nitv[node] = (end - l) >> 3;      // padded count / 8
  }
}

// ---- normalize one 4-node block ----
__device__ __forceinline__ void dev_normalize(int nb, const float* __restrict__ pref,
                                              float* __restrict__ x){
  int node = nb * 4 + (threadIdx.x >> 6);
  int lane = threadIdx.x & 63;
  float v = (node < NUSER) ? pref[(size_t)node * DD + lane] : x[(size_t)node * DD + lane];
  float ss = v * v;
  #pragma unroll
  for (int o = 1; o < 64; o <<= 1) ss += __shfl_xor(ss, o);
  v = v / fmaxf(sqrtf(ss), 1e-12f);
  x[(size_t)node * DD + lane] = v;
}

// ================= packed kernels =================
__global__ __launch_bounds__(256) void p1_histo_cvtw(const int* __restrict__ ei,
    int* __restrict__ hist, const float* __restrict__ w1, const float* __restrict__ w2,
    const float* __restrict__ cw, unsigned short* __restrict__ w1b,
    unsigned short* __restrict__ w2b, unsigned short* __restrict__ cwb){
  __shared__ int h[NBUCK];
  int b = blockIdx.x;
  if (b < NCHUNK) dev_histo(b, ei, hist, h);
  else            dev_cvtw(b - NCHUNK, w1, w2, cw, w1b, w2b, cwb);
}

__global__ __launch_bounds__(256) void scan_part(const int* __restrict__ a,
                                                 int* __restrict__ bsum){
  __shared__ int ws4[4];
  int b = blockIdx.x, base = b * 1024;
  int v = 0;
  #pragma unroll
  for (int s = 0; s < 4; s++){
    int idx = base + s * 256 + threadIdx.x;
    if (idx < NHIST) v += a[idx];
  }
  int lane = threadIdx.x & 63, w = threadIdx.x >> 6;
  #pragma unroll
  for (int o = 1; o < 64; o <<= 1) v += __shfl_xor(v, o);
  if (lane == 0) ws4[w] = v;
  __syncthreads();
  if (threadIdx.x == 0) bsum[b] = ws4[0] + ws4[1] + ws4[2] + ws4[3];
}

__global__ __launch_bounds__(1024) void scan_mid(const int* __restrict__ a,
                                                 int* __restrict__ excl_out){
  __shared__ int wsum[16];
  int tid = threadIdx.x;
  int v = (tid < NPART) ? a[tid] : 0;
  int lane = tid & 63, w = tid >> 6;
  int incl = v;
  #pragma unroll
  for (int o = 1; o < 64; o <<= 1){ int u = __shfl_up(incl, o); if (lane >= o) incl += u; }
  if (lane == 63) wsum[w] = incl;
  __syncthreads();
  int woff = 0;
  #pragma unroll
  for (int k = 0; k < 16; k++) if (k < w) woff += wsum[k];
  if (tid < NPART) excl_out[tid] = woff + incl - v;
}

__global__ __launch_bounds__(256) void p2_gemm1_scan(const float* __restrict__ feats,
    const short* __restrict__ w1b, const float* __restrict__ b1,
    unsigned short* __restrict__ hiddenb, const int* __restrict__ hist,
    const int* __restrict__ boff, int* __restrict__ sc){
  __shared__ __align__(16) float Asf[128 * 32];   // 16KB
  __shared__ __align__(16) short Bs[128 * 32];    // 8KB
  __shared__ int wsum4[4];
  int b = blockIdx.x;
  if (b < G1_BLOCKS) dev_gemm1(b & 1, b >> 1, feats, w1b, b1, hiddenb, Asf, Bs);
  else               dev_scan_apply4(b - G1_BLOCKS, hist, boff, sc, wsum4);
}

__global__ __launch_bounds__(256) void p3_gemm2_binscat(const unsigned short* __restrict__ hiddenb,
    const short* __restrict__ w2b, const float* __restrict__ b2, float* __restrict__ xitems,
    const int* __restrict__ ei, const int* __restrict__ sc, int* __restrict__ pairsv){
  __shared__ __align__(16) short As[128 * 32];    // 8KB
  __shared__ __align__(16) short Bs[64 * 32];     // 4KB
  __shared__ int cur[NBUCK];                      // 2.5KB
  int b = blockIdx.x;
  if (b < G2_BLOCKS) dev_gemm2(b, (const short*)hiddenb, w2b, b2, xitems, As, Bs);
  else               dev_binscat(b - G2_BLOCKS, ei, sc, pairsv, cur);
}

__global__ __launch_bounds__(256) void p4_bucketize_norm(const int* __restrict__ pairsv,
    const int* __restrict__ sc, float* __restrict__ dinv, int* __restrict__ csr,
    int* __restrict__ indptr, int* __restrict__ nitv,
    const float* __restrict__ pref, float* __restrict__ x){
  __shared__ int cnt[128], cur[128], l0[128];
  __shared__ int wtot;
  int b = blockIdx.x;
  if (b < NBUCK) dev_bucketize(b, pairsv, sc, dinv, csr, indptr, nitv, cnt, cur, l0, &wtot);
  else           dev_normalize(b - NBUCK, pref, x);
}

// ---------------- lin via MFMA: hsb = bf16(dinv[row] * (src @ cwb^T)) ----------------
__global__ __launch_bounds__(256) void lin_mfma(const float* __restrict__ src,
                                                const short* __restrict__ cwb,
                                                const float* __restrict__ dinv,
                                                unsigned short* __restrict__ hsb){
  constexpr int AP = 72;                        // padded stride (elems)
  __shared__ __align__(16) short As[128 * AP];  // 18KB

  const int tid  = threadIdx.x;
  const int wid  = tid >> 6;
  const int lane = tid & 63;
  const int wr   = wid >> 1;
  const int wc   = wid & 1;
  const int m0   = blockIdx.x * 128;

  #pragma unroll
  for (int s = 0; s < 8; s++){
    int c = s * 256 + tid;
    int row = c >> 4, kc = c & 15;
    float4 v = *(const float4*)&src[(size_t)(m0 + row) * DD + kc * 4];
    ushort4 o = { f2bf(v.x), f2bf(v.y), f2bf(v.z), f2bf(v.w) };
    *(ushort4*)&As[row * AP + kc * 4] = o;
  }
  __syncthreads();

  f32x4 acc[4][2] = {};
  #pragma unroll
  for (int kk = 0; kk < DD; kk += 32){
    s16x8 af[4], bf[2];
    #pragma unroll
    for (int m = 0; m < 4; m++)
      af[m] = *(const s16x8*)&As[(wr * 64 + m * 16 + (lane & 15)) * AP + kk + (lane >> 4) * 8];
    #pragma unroll
    for (int n = 0; n < 2; n++)
      bf[n] = *(const s16x8*)&cwb[(size_t)(wc * 32 + n * 16 + (lane & 15)) * DD + kk + (lane >> 4) * 8];
    #pragma unroll
    for (int m = 0; m < 4; m++)
      #pragma unroll
      for (int n = 0; n < 2; n++)
        acc[m][n] = __builtin_amdgcn_mfma_f32_16x16x32_bf16(af[m], bf[n], acc[m][n], 0, 0, 0);
  }

  #pragma unroll
  for (int m = 0; m < 4; m++){
    int row_base = m0 + wr * 64 + m * 16 + (lane >> 4) * 4;
    #pragma unroll
    for (int n = 0; n < 2; n++){
      int col = wc * 32 + n * 16 + (lane & 15);
      #pragma unroll
      for (int r = 0; r < 4; r++){
        int row = row_base + r;
        hsb[(size_t)row * DD + col] = f2bf(dinv[row] * acc[m][n][r]);
      }
    }
  }
}

// ---------------- gather aggregation: 8 edges in flight, 8 lanes x s16x8 ----------------
template<int FINAL>
__global__ __launch_bounds__(256) void agg_kernel(const unsigned short* __restrict__ hsb,
                                                  const float* __restrict__ dinv,
                                                  const int* __restrict__ indptr,
                                                  const int* __restrict__ nitv,
                                                  const int* __restrict__ csr,
                                                  const float* __restrict__ bias,
                                                  const float* __restrict__ x,
                                                  const float* __restrict__ h,
                                                  float* __restrict__ out,
                                                  const float* __restrict__ pref,
                                                  float* __restrict__ out2){
  int b = blockIdx.x;
  if (FINAL && b >= NN / 4){
    long q = (long)(b - NN / 4) * 256 + threadIdx.x;
    if (q < (long)NUSER * DD / 4)
      ((float4*)out2)[q] = ((const float4*)pref)[q];
    return;
  }
  int node = b * 4 + (threadIdx.x >> 6);
  int lane = threadIdx.x & 63;
  int g  = lane >> 3;
  int sl = lane & 7;
  int e0 = indptr[node];
  int nit = nitv[node];
  float a0=0.f,a1=0.f,a2=0.f,a3=0.f,a4=0.f,a5=0.f,a6=0.f,a7=0.f;
  int k = e0 + g;
  for (int i = 0; i < nit; i++){
    int j = csr[k];
    k += 8;
    s16x8 v = *(const s16x8*)&hsb[(size_t)j * DD + sl * 8];
    a0 += bf2f((unsigned short)v[0]); a1 += bf2f((unsigned short)v[1]);
    a2 += bf2f((unsigned short)v[2]); a3 += bf2f((unsigned short)v[3]);
    a4 += bf2f((unsigned short)v[4]); a5 += bf2f((unsigned short)v[5]);
    a6 += bf2f((unsigned short)v[6]); a7 += bf2f((unsigned short)v[7]);
  }
  #pragma unroll
  for (int off = 8; off < 64; off <<= 1){
    a0 += __shfl_xor(a0, off); a1 += __shfl_xor(a1, off);
    a2 += __shfl_xor(a2, off); a3 += __shfl_xor(a3, off);
    a4 += __shfl_xor(a4, off); a5 += __shfl_xor(a5, off);
    a6 += __shfl_xor(a6, off); a7 += __shfl_xor(a7, off);
  }
  if (g == 0){
    float di = dinv[node];
    size_t rb = (size_t)node * DD + sl * 8;
    const float4 bi0 = *(const float4*)&bias[sl * 8];
    const float4 bi1 = *(const float4*)&bias[sl * 8 + 4];
    float4 r0, r1;
    r0.x = fmaf(di, a0, bi0.x); r0.y = fmaf(di, a1, bi0.y);
    r0.z = fmaf(di, a2, bi0.z); r0.w = fmaf(di, a3, bi0.w);
    r1.x = fmaf(di, a4, bi1.x); r1.y = fmaf(di, a5, bi1.y);
    r1.z = fmaf(di, a6, bi1.z); r1.w = fmaf(di, a7, bi1.w);
    if (FINAL){
      const float4 xv0 = *(const float4*)&x[rb];
      const float4 xv1 = *(const float4*)&x[rb + 4];
      const float4 hv0 = *(const float4*)&h[rb];
      const float4 hv1 = *(const float4*)&h[rb + 4];
      r0.x += xv0.x + hv0.x; r0.y += xv0.y + hv0.y;
      r0.z += xv0.z + hv0.z; r0.w += xv0.w + hv0.w;
      r1.x += xv1.x + hv1.x; r1.y += xv1.y + hv1.y;
      r1.z += xv1.z + hv1.z; r1.w += xv1.w + hv1.w;
    }
    *(float4*)&out[rb] = r0;
    *(float4*)&out[rb + 4] = r1;
  }
}

extern "C" void kernel_launch(void* const* d_in, const int* in_sizes, int n_in,
                              void* d_out, int out_size, void* d_ws, size_t ws_size,
                              hipStream_t stream){
  const int*   ei    = (const int*)  d_in[0];
  const float* feats = (const float*)d_in[1];
  const float* pref  = (const float*)d_in[2];
  const float* w1    = (const float*)d_in[3];
  const float* b1    = (const float*)d_in[4];
  const float* w2    = (const float*)d_in[5];
  const float* b2    = (const float*)d_in[6];
  const float* cw    = (const float*)d_in[7];
  const float* cb    = (const float*)d_in[8];
  float* out = (float*)d_out;

  // ---- workspace layout (lifetime-overlapped; peak ~77.2MB, proven) ----
  // [0, 20.48MB)      x f32 [NN*64]
  // [20.48, 40.96MB)  hbuf f32 [NN*64] -- CSR scratch (pairsv|hist|sc|bsum|boff) overlays
  //                   it until bucketize; hbuf written by agg0 afterwards
  // [40.96, ~49.3MB)  live graph: csr[CSRCAP] | indptr[NN] | nitv[NN] | dinv[NN]
  // [51.25, 76.9MB)   hiddenb bf16 [MPAD*256] (dead after gemm2), overlaid by hsb_a | hsb_b
  // [76.9MB, ...)     w1b, w2b, cwb bf16
  char* wsb = (char*)d_ws;
  float* x       = (float*)wsb;
  float* hbuf    = (float*)(wsb + (size_t)NN * DD * 4);
  int*   pairsv  = (int*)hbuf;
  int*   hist    = pairsv + NE;
  int*   sc      = hist + NHIST;
  int*   bsum    = sc + NHIST;
  int*   boff    = bsum + NPART;
  char*  graphb  = wsb + (size_t)NN * DD * 8;
  int*   csr     = (int*)graphb;
  int*   indptr  = csr + CSRCAP;
  int*   nitv    = indptr + NN;
  float* dinv    = (float*)(nitv + NN);
  unsigned short* hiddenb = (unsigned short*)(wsb + (size_t)MPAD * FEAT * 2);
  unsigned short* hsba = hiddenb;
  unsigned short* hsbb = hsba + (size_t)(NN + 1) * DD;
  short* w1b     = (short*)(wsb + (size_t)MPAD * FEAT * 2 + (size_t)(MPAD + 64) * HIDN * 2);
  short* w2b     = w1b + (size_t)HIDN * FEAT;
  short* cwb     = w2b + (size_t)DD * HIDN;

  // ---- P1: edge histogram ∪ weight cvt ----
  p1_histo_cvtw<<<NCHUNK + CVTW_BLOCKS, 256, 0, stream>>>(
      ei, hist, w1, w2, cw, (unsigned short*)w1b, (unsigned short*)w2b,
      (unsigned short*)cwb);
  // ---- hist scan (part -> mid) ----
  scan_part<<<NPART, 256, 0, stream>>>(hist, bsum);
  scan_mid<<<1, 1024, 0, stream>>>(bsum, boff);
  // ---- P2: GEMM1 (f32 A direct) ∪ scan_apply ----
  p2_gemm1_scan<<<G1_BLOCKS + NPART, 256, 0, stream>>>(
      feats, w1b, b1, hiddenb, hist, boff, sc);
  // ---- P3: GEMM2 ∪ binscat ----
  p3_gemm2_binscat<<<G2_BLOCKS + NCHUNK, 256, 0, stream>>>(
      hiddenb, w2b, b2, x + (size_t)NUSER * DD, ei, sc, pairsv);
  // pad rows (hsb regions overlay hiddenb: after gemm2)
  hipMemsetAsync(hsba + (size_t)NN * DD, 0, DD * sizeof(unsigned short), stream);
  hipMemsetAsync(hsbb + (size_t)NN * DD, 0, DD * sizeof(unsigned short), stream);
  // ---- P4: bucketize (fused count+scan+fill) ∪ normalize ----
  p4_bucketize_norm<<<NBUCK + NN / 4, 256, 0, stream>>>(
      pairsv, sc, dinv, csr, indptr, nitv, pref, x);

  // ---- conv1: lin + gather ----
  lin_mfma<<<NN / 128, 256, 0, stream>>>(x, cwb, dinv, hsba);
  agg_kernel<0><<<NN / 4, 256, 0, stream>>>(hsba, dinv, indptr, nitv, csr, cb,
                                            nullptr, nullptr, hbuf, nullptr, nullptr);
  // ---- conv2: lin + gather + residual + pref tail ----
  lin_mfma<<<NN / 128, 256, 0, stream>>>(hbuf, cwb, dinv, hsbb);
  agg_kernel<1><<<NN / 4 + (NUSER * DD / 4) / 256, 256, 0, stream>>>(
      hsbb, dinv, indptr, nitv, csr, cb, x, hbuf, out, pref, out + (size_t)NN * DD);
}